// Round 1
// baseline (1073.984 us; speedup 1.0000x reference)
//
#include <hip/hip_runtime.h>

#define N_NODES 100000
#define P_PATHS 10000

// ---------------- Kernel 1: feat = x@fc_w, el/er attention scores ----------
__global__ __launch_bounds__(256) void k_feat(const float* __restrict__ x,
                                              const float* __restrict__ fc_w,
                                              const float* __restrict__ attn_l,
                                              const float* __restrict__ attn_r,
                                              float* __restrict__ feat,
                                              float* __restrict__ el,
                                              float* __restrict__ er) {
    __shared__ float s_w[64 * 64];
    __shared__ float s_al[64], s_ar[64];
    int tid = threadIdx.x;
    for (int i = tid; i < 64 * 64; i += 256) s_w[i] = fc_w[i];
    if (tid < 64) { s_al[tid] = attn_l[tid]; s_ar[tid] = attn_r[tid]; }
    __syncthreads();
    int wave = tid >> 6, lane = tid & 63;
    int n = blockIdx.x * 4 + wave;
    if (n >= N_NODES) return;
    float xv = x[n * 64 + lane];
    float acc = 0.f;
#pragma unroll
    for (int k = 0; k < 64; ++k) {
        acc += __shfl(xv, k) * s_w[k * 64 + lane];
    }
    feat[n * 64 + lane] = acc;
    int h = lane >> 4;
    float pl = acc * s_al[lane];
    float pr = acc * s_ar[lane];
#pragma unroll
    for (int off = 1; off < 16; off <<= 1) {
        pl += __shfl_xor(pl, off);
        pr += __shfl_xor(pr, off);
    }
    if ((lane & 15) == 0) {
        el[n * 4 + h] = pl;
        er[n * 4 + h] = pr;
    }
}

// ---------------- Kernel 2: per-edge exp scores -> denom (atomic) ----------
__global__ __launch_bounds__(256) void k_edge1(const int* __restrict__ src,
                                               const int* __restrict__ dst,
                                               const float* __restrict__ el,
                                               const float* __restrict__ er,
                                               float* __restrict__ denom, int E) {
    int i = blockIdx.x * blockDim.x + threadIdx.x;
    if (i >= E) return;
    int s = src[i], d = dst[i];
    float4 a = *(const float4*)(el + (size_t)s * 4);
    float4 b = *(const float4*)(er + (size_t)d * 4);
    float e0 = a.x + b.x, e1 = a.y + b.y, e2 = a.z + b.z, e3 = a.w + b.w;
    e0 = e0 > 0.f ? e0 : 0.2f * e0;
    e1 = e1 > 0.f ? e1 : 0.2f * e1;
    e2 = e2 > 0.f ? e2 : 0.2f * e2;
    e3 = e3 > 0.f ? e3 : 0.2f * e3;
    atomicAdd(denom + (size_t)d * 4 + 0, __expf(e0));
    atomicAdd(denom + (size_t)d * 4 + 1, __expf(e1));
    atomicAdd(denom + (size_t)d * 4 + 2, __expf(e2));
    atomicAdd(denom + (size_t)d * 4 + 3, __expf(e3));
}

// ---------------- Kernel 3: one wave per edge, alpha*feat[src] -> agg[dst] -
__global__ __launch_bounds__(256) void k_edge2(const int* __restrict__ src,
                                               const int* __restrict__ dst,
                                               const float* __restrict__ el,
                                               const float* __restrict__ er,
                                               const float* __restrict__ denom,
                                               const float* __restrict__ feat,
                                               float* __restrict__ agg, int E) {
    int gw = (int)((blockIdx.x * blockDim.x + threadIdx.x) >> 6);
    int nw = (int)((gridDim.x * blockDim.x) >> 6);
    int lane = threadIdx.x & 63;
    for (int e = gw; e < E; e += nw) {
        int s = src[e], d = dst[e];
        float a = 0.f;
        if (lane < 4) {
            float ev = el[(size_t)s * 4 + lane] + er[(size_t)d * 4 + lane];
            ev = ev > 0.f ? ev : 0.2f * ev;
            a = __expf(ev) / denom[(size_t)d * 4 + lane];
        }
        float alpha = __shfl(a, lane >> 4);
        float m = alpha * feat[(size_t)s * 64 + lane];
        atomicAdd(agg + (size_t)d * 64 + lane, m);
    }
}

// ---------------- Kernel 4: fused 7-layer MLP + skip linear ----------------
__device__ __forceinline__ void mlp_layer(const float* in, int sin, float* out, int sout,
                                          const float* __restrict__ w,
                                          const float* __restrict__ b,
                                          int din, int dout, int tid) {
    if (tid < dout) {
        float acc[16];
#pragma unroll
        for (int r = 0; r < 16; ++r) acc[r] = 0.f;
        for (int k = 0; k < din; ++k) {
            float wv = w[k * dout + tid];
#pragma unroll
            for (int r = 0; r < 16; ++r) acc[r] += in[r * sin + k] * wv;
        }
        float bb = b[tid];
#pragma unroll
        for (int r = 0; r < 16; ++r) {
            float v = acc[r] + bb;
            out[r * sout + tid] = v > 0.f ? v : 0.f;  // relu (layers 1..6)
        }
    }
}

__global__ __launch_bounds__(192) void k_mlp(const float* __restrict__ agg,
                                             const float* __restrict__ bias,
                                             const float* __restrict__ w1, const float* __restrict__ b1,
                                             const float* __restrict__ w2, const float* __restrict__ b2,
                                             const float* __restrict__ w3, const float* __restrict__ b3,
                                             const float* __restrict__ w4, const float* __restrict__ b4,
                                             const float* __restrict__ w5, const float* __restrict__ b5,
                                             const float* __restrict__ w6, const float* __restrict__ b6,
                                             const float* __restrict__ w7, const float* __restrict__ b7,
                                             const float* __restrict__ wt,
                                             float* __restrict__ outp) {
    __shared__ float g[16][640];
    __shared__ float buf0[16][184];
    __shared__ float buf1[16][184];
    __shared__ float wx[16];
    int tid = threadIdx.x;
    int p0 = blockIdx.x * 16;
    // load g tile: 16 paths x 640 (= contiguous 16*640 floats of agg) + bias
    for (int i = tid; i < 16 * 640; i += 192) {
        int r = i / 640, j = i % 640;
        g[r][j] = agg[(size_t)(p0 + r) * 640 + j] + bias[j & 63];
    }
    __syncthreads();
    // skip linear: wx[r] = g[r] . wt   (4 lanes per row, first wave)
    if (tid < 64) {
        int r = tid >> 2, sub = tid & 3;
        float acc = 0.f;
        for (int k = sub; k < 640; k += 4) acc += g[r][k] * wt[k];
        acc += __shfl_xor(acc, 1);
        acc += __shfl_xor(acc, 2);
        if (sub == 0) wx[r] = acc;
    }
    // layer 1 from g
    mlp_layer(&g[0][0], 640, &buf0[0][0], 184, w1, b1, 640, 180, tid);
    __syncthreads();
    mlp_layer(&buf0[0][0], 184, &buf1[0][0], 184, w2, b2, 180, 150, tid);
    __syncthreads();
    mlp_layer(&buf1[0][0], 184, &buf0[0][0], 184, w3, b3, 150, 128, tid);
    __syncthreads();
    mlp_layer(&buf0[0][0], 184, &buf1[0][0], 184, w4, b4, 128, 80, tid);
    __syncthreads();
    mlp_layer(&buf1[0][0], 184, &buf0[0][0], 184, w5, b5, 80, 64, tid);
    __syncthreads();
    mlp_layer(&buf0[0][0], 184, &buf1[0][0], 184, w6, b6, 64, 32, tid);
    __syncthreads();
    // layer 7 (32 -> 1, no relu) + wx
    if (tid < 16) {
        int r = tid;
        float acc = b7[0];
        for (int k = 0; k < 32; ++k) acc += buf1[r][k] * w7[k];
        outp[p0 + r] = acc + wx[r];
    }
}

extern "C" void kernel_launch(void* const* d_in, const int* in_sizes, int n_in,
                              void* d_out, int out_size, void* d_ws, size_t ws_size,
                              hipStream_t stream) {
    const float* x      = (const float*)d_in[0];
    const int*   src    = (const int*)d_in[1];
    const int*   dst    = (const int*)d_in[2];
    const float* fc_w   = (const float*)d_in[3];
    const float* bias   = (const float*)d_in[4];
    const float* attn_l = (const float*)d_in[5];
    const float* attn_r = (const float*)d_in[6];
    const float* w1 = (const float*)d_in[7];  const float* b1 = (const float*)d_in[8];
    const float* w2 = (const float*)d_in[9];  const float* b2 = (const float*)d_in[10];
    const float* w3 = (const float*)d_in[11]; const float* b3 = (const float*)d_in[12];
    const float* w4 = (const float*)d_in[13]; const float* b4 = (const float*)d_in[14];
    const float* w5 = (const float*)d_in[15]; const float* b5 = (const float*)d_in[16];
    const float* w6 = (const float*)d_in[17]; const float* b6 = (const float*)d_in[18];
    const float* w7 = (const float*)d_in[19]; const float* b7 = (const float*)d_in[20];
    const float* wt = (const float*)d_in[21];
    int E = in_sizes[1];

    float* ws    = (float*)d_ws;
    float* feat  = ws;                 // N*64   = 6,400,000 floats
    float* el    = ws + 6400000;       // N*4    =   400,000
    float* er    = ws + 6800000;       // N*4
    float* denom = ws + 7200000;       // N*4
    float* agg   = ws + 7600000;       // N*64

    hipMemsetAsync(denom, 0, (size_t)400000 * 4, stream);
    hipMemsetAsync(agg, 0, (size_t)6400000 * 4, stream);

    k_feat<<<N_NODES / 4, 256, 0, stream>>>(x, fc_w, attn_l, attn_r, feat, el, er);
    k_edge1<<<(E + 255) / 256, 256, 0, stream>>>(src, dst, el, er, denom, E);
    k_edge2<<<4096, 256, 0, stream>>>(src, dst, el, er, denom, feat, agg, E);
    k_mlp<<<P_PATHS / 16, 192, 0, stream>>>(agg, bias, w1, b1, w2, b2, w3, b3, w4, b4,
                                            w5, b5, w6, b6, w7, b7, wt, (float*)d_out);
}

// Round 2
// 623.184 us; speedup vs baseline: 1.7234x; 1.7234x over previous
//
#include <hip/hip_runtime.h>

#define N_NODES 100000
#define P_PATHS 10000
#define NCHUNK 98   // ceil(100000/1024)

// ---------------- Kernel 1: feat = x@fc_w, el/er attention scores ----------
__global__ __launch_bounds__(256) void k_feat(const float* __restrict__ x,
                                              const float* __restrict__ fc_w,
                                              const float* __restrict__ attn_l,
                                              const float* __restrict__ attn_r,
                                              float* __restrict__ feat,
                                              float* __restrict__ el,
                                              float* __restrict__ er) {
    __shared__ float s_w[64 * 64];
    __shared__ float s_al[64], s_ar[64];
    int tid = threadIdx.x;
    for (int i = tid; i < 64 * 64; i += 256) s_w[i] = fc_w[i];
    if (tid < 64) { s_al[tid] = attn_l[tid]; s_ar[tid] = attn_r[tid]; }
    __syncthreads();
    int wave = tid >> 6, lane = tid & 63;
    int n = blockIdx.x * 4 + wave;
    if (n >= N_NODES) return;
    float xv = x[n * 64 + lane];
    float acc = 0.f;
#pragma unroll
    for (int k = 0; k < 64; ++k) {
        acc += __shfl(xv, k) * s_w[k * 64 + lane];
    }
    feat[n * 64 + lane] = acc;
    int h = lane >> 4;
    float pl = acc * s_al[lane];
    float pr = acc * s_ar[lane];
#pragma unroll
    for (int off = 1; off < 16; off <<= 1) {
        pl += __shfl_xor(pl, off);
        pr += __shfl_xor(pr, off);
    }
    if ((lane & 15) == 0) {
        el[n * 4 + h] = pl;
        er[n * 4 + h] = pr;
    }
}

// ---------------- CSR build: histogram -> scan -> scatter ------------------
__global__ __launch_bounds__(256) void k_hist(const int* __restrict__ dst,
                                              int* __restrict__ deg, int E) {
    int i = blockIdx.x * 256 + threadIdx.x;
    if (i < E) atomicAdd(deg + dst[i], 1);
}

__global__ __launch_bounds__(256) void k_scan_a(const int* __restrict__ deg,
                                                int* __restrict__ excl,
                                                int* __restrict__ csum, int n) {
    __shared__ int s[256];
    int tid = threadIdx.x;
    int idx = blockIdx.x * 1024 + tid * 4;
    int v0 = 0, v1 = 0, v2 = 0, v3 = 0;
    if (idx + 0 < n) v0 = deg[idx + 0];
    if (idx + 1 < n) v1 = deg[idx + 1];
    if (idx + 2 < n) v2 = deg[idx + 2];
    if (idx + 3 < n) v3 = deg[idx + 3];
    int tsum = v0 + v1 + v2 + v3;
    s[tid] = tsum;
    __syncthreads();
    for (int off = 1; off < 256; off <<= 1) {
        int t = (tid >= off) ? s[tid - off] : 0;
        __syncthreads();
        s[tid] += t;
        __syncthreads();
    }
    int texcl = s[tid] - tsum;
    if (tid == 255) csum[blockIdx.x] = s[255];
    if (idx + 0 < n) excl[idx + 0] = texcl;
    if (idx + 1 < n) excl[idx + 1] = texcl + v0;
    if (idx + 2 < n) excl[idx + 2] = texcl + v0 + v1;
    if (idx + 3 < n) excl[idx + 3] = texcl + v0 + v1 + v2;
}

__global__ __launch_bounds__(128) void k_scan_b(int* __restrict__ csum, int nch) {
    __shared__ int s[128];
    int tid = threadIdx.x;
    int v = (tid < nch) ? csum[tid] : 0;
    s[tid] = v;
    __syncthreads();
    for (int off = 1; off < 128; off <<= 1) {
        int t = (tid >= off) ? s[tid - off] : 0;
        __syncthreads();
        s[tid] += t;
        __syncthreads();
    }
    if (tid < nch) csum[tid] = s[tid] - v;   // exclusive
}

__global__ __launch_bounds__(256) void k_scan_c(int* __restrict__ rowptr,
                                                const int* __restrict__ csum,
                                                int* __restrict__ wptr, int n, int E) {
    int i = blockIdx.x * 256 + threadIdx.x;
    if (i < n) {
        int v = rowptr[i] + csum[i >> 10];
        rowptr[i] = v;
        wptr[i] = v;
        if (i == 0) rowptr[n] = E;
    }
}

__global__ __launch_bounds__(256) void k_scatter(const int* __restrict__ src,
                                                 const int* __restrict__ dst,
                                                 int* __restrict__ wptr,
                                                 int* __restrict__ csr, int E) {
    int i = blockIdx.x * 256 + threadIdx.x;
    if (i < E) {
        int pos = atomicAdd(wptr + dst[i], 1);
        csr[pos] = src[i];
    }
}

// ---------------- Aggregation: one wave per node, no atomics ---------------
__global__ __launch_bounds__(256) void k_agg(const int* __restrict__ rowptr,
                                             const int* __restrict__ csr,
                                             const float* __restrict__ el,
                                             const float* __restrict__ er,
                                             const float* __restrict__ feat,
                                             const float* __restrict__ bias,
                                             float* __restrict__ agg) {
    int tid = threadIdx.x;
    int wave = tid >> 6, lane = tid & 63;
    int n = blockIdx.x * 4 + wave;
    if (n >= N_NODES) return;
    int h = lane >> 4;
    float ern = er[(size_t)n * 4 + h];
    int e0 = rowptr[n], e1 = rowptr[n + 1];
    float acc = 0.f, den = 0.f;
    int s_next = (e0 < e1) ? csr[e0] : 0;
    for (int e = e0; e < e1; ++e) {
        int s = s_next;
        if (e + 1 < e1) s_next = csr[e + 1];
        float ev = el[(size_t)s * 4 + h] + ern;
        ev = ev > 0.f ? ev : 0.2f * ev;
        float ez = __expf(ev);
        acc += ez * feat[(size_t)s * 64 + lane];
        den += ez;
    }
    agg[(size_t)n * 64 + lane] = acc / den + bias[lane];
}

// ---------------- Kernel 4: fused 7-layer MLP + skip linear ----------------
__device__ __forceinline__ void mlp_layer(const float* in, int sin, float* out, int sout,
                                          const float* __restrict__ w,
                                          const float* __restrict__ b,
                                          int din, int dout, int tid) {
    if (tid < dout) {
        float acc[16];
#pragma unroll
        for (int r = 0; r < 16; ++r) acc[r] = 0.f;
        int k = 0;
        for (; k + 4 <= din; k += 4) {
            float w0 = w[(k + 0) * dout + tid];
            float w1 = w[(k + 1) * dout + tid];
            float w2 = w[(k + 2) * dout + tid];
            float w3 = w[(k + 3) * dout + tid];
#pragma unroll
            for (int r = 0; r < 16; ++r) {
                float4 iv = *(const float4*)(in + r * sin + k);
                acc[r] += iv.x * w0 + iv.y * w1 + iv.z * w2 + iv.w * w3;
            }
        }
        for (; k < din; ++k) {
            float wv = w[k * dout + tid];
#pragma unroll
            for (int r = 0; r < 16; ++r) acc[r] += in[r * sin + k] * wv;
        }
        float bb = b[tid];
#pragma unroll
        for (int r = 0; r < 16; ++r) {
            float v = acc[r] + bb;
            out[r * sout + tid] = v > 0.f ? v : 0.f;  // relu (layers 1..6)
        }
    }
}

__global__ __launch_bounds__(192) void k_mlp(const float* __restrict__ agg,
                                             const float* __restrict__ w1, const float* __restrict__ b1,
                                             const float* __restrict__ w2, const float* __restrict__ b2,
                                             const float* __restrict__ w3, const float* __restrict__ b3,
                                             const float* __restrict__ w4, const float* __restrict__ b4,
                                             const float* __restrict__ w5, const float* __restrict__ b5,
                                             const float* __restrict__ w6, const float* __restrict__ b6,
                                             const float* __restrict__ w7, const float* __restrict__ b7,
                                             const float* __restrict__ wt,
                                             float* __restrict__ outp) {
    __shared__ float g[16][640];
    __shared__ float buf0[16][184];
    __shared__ float buf1[16][184];
    __shared__ float wx[16];
    int tid = threadIdx.x;
    int p0 = blockIdx.x * 16;
    // load g tile: 16 paths x 640 (= contiguous 16*640 floats of agg; bias already folded)
    for (int i = tid; i < 16 * 640; i += 192) {
        ((float*)g)[0 * 0 + 0] = ((float*)g)[0];  // no-op to keep layout simple
        int r = i / 640, j = i % 640;
        g[r][j] = agg[(size_t)(p0 + r) * 640 + j];
    }
    __syncthreads();
    // skip linear: wx[r] = g[r] . wt   (4 lanes per row, first wave)
    if (tid < 64) {
        int r = tid >> 2, sub = tid & 3;
        float acc = 0.f;
        for (int k = sub * 4; k < 640; k += 16) {
            float4 gv = *(const float4*)(&g[r][k]);
            float4 wv = *(const float4*)(wt + k);
            acc += gv.x * wv.x + gv.y * wv.y + gv.z * wv.z + gv.w * wv.w;
        }
        acc += __shfl_xor(acc, 1);
        acc += __shfl_xor(acc, 2);
        if (sub == 0) wx[r] = acc;
    }
    mlp_layer(&g[0][0], 640, &buf0[0][0], 184, w1, b1, 640, 180, tid);
    __syncthreads();
    mlp_layer(&buf0[0][0], 184, &buf1[0][0], 184, w2, b2, 180, 150, tid);
    __syncthreads();
    mlp_layer(&buf1[0][0], 184, &buf0[0][0], 184, w3, b3, 150, 128, tid);
    __syncthreads();
    mlp_layer(&buf0[0][0], 184, &buf1[0][0], 184, w4, b4, 128, 80, tid);
    __syncthreads();
    mlp_layer(&buf1[0][0], 184, &buf0[0][0], 184, w5, b5, 80, 64, tid);
    __syncthreads();
    mlp_layer(&buf0[0][0], 184, &buf1[0][0], 184, w6, b6, 64, 32, tid);
    __syncthreads();
    // layer 7 (32 -> 1, no relu) + wx
    if (tid < 16) {
        int r = tid;
        float acc = b7[0];
#pragma unroll
        for (int k = 0; k < 32; ++k) acc += buf1[r][k] * w7[k];
        outp[p0 + r] = acc + wx[r];
    }
}

extern "C" void kernel_launch(void* const* d_in, const int* in_sizes, int n_in,
                              void* d_out, int out_size, void* d_ws, size_t ws_size,
                              hipStream_t stream) {
    const float* x      = (const float*)d_in[0];
    const int*   src    = (const int*)d_in[1];
    const int*   dst    = (const int*)d_in[2];
    const float* fc_w   = (const float*)d_in[3];
    const float* bias   = (const float*)d_in[4];
    const float* attn_l = (const float*)d_in[5];
    const float* attn_r = (const float*)d_in[6];
    const float* w1 = (const float*)d_in[7];  const float* b1 = (const float*)d_in[8];
    const float* w2 = (const float*)d_in[9];  const float* b2 = (const float*)d_in[10];
    const float* w3 = (const float*)d_in[11]; const float* b3 = (const float*)d_in[12];
    const float* w4 = (const float*)d_in[13]; const float* b4 = (const float*)d_in[14];
    const float* w5 = (const float*)d_in[15]; const float* b5 = (const float*)d_in[16];
    const float* w6 = (const float*)d_in[17]; const float* b6 = (const float*)d_in[18];
    const float* w7 = (const float*)d_in[19]; const float* b7 = (const float*)d_in[20];
    const float* wt = (const float*)d_in[21];
    int E = in_sizes[1];

    float* ws     = (float*)d_ws;
    float* feat   = ws;                         // 6,400,000 f
    float* el     = ws + 6400000;               //   400,000 f
    float* er     = ws + 6800000;               //   400,000 f
    float* agg    = ws + 7200000;               // 6,400,000 f
    int*   deg    = (int*)(ws + 13600000);      //   100,000 i (reused as wptr)
    int*   rowptr = (int*)(ws + 13700000);      //   100,001 i (pad to 100,004)
    int*   csum   = (int*)(ws + 13800004);      //       128 i
    int*   csr    = (int*)(ws + 13800132);      //         E i

    int egrid = (E + 255) / 256;

    hipMemsetAsync(deg, 0, (size_t)N_NODES * 4, stream);

    k_feat<<<N_NODES / 4, 256, 0, stream>>>(x, fc_w, attn_l, attn_r, feat, el, er);
    k_hist<<<egrid, 256, 0, stream>>>(dst, deg, E);
    k_scan_a<<<NCHUNK, 256, 0, stream>>>(deg, rowptr, csum, N_NODES);
    k_scan_b<<<1, 128, 0, stream>>>(csum, NCHUNK);
    k_scan_c<<<(N_NODES + 255) / 256, 256, 0, stream>>>(rowptr, csum, deg /*wptr*/, N_NODES, E);
    k_scatter<<<egrid, 256, 0, stream>>>(src, dst, deg /*wptr*/, csr, E);
    k_agg<<<N_NODES / 4, 256, 0, stream>>>(rowptr, csr, el, er, feat, bias, agg);
    k_mlp<<<P_PATHS / 16, 192, 0, stream>>>(agg, w1, b1, w2, b2, w3, b3, w4, b4,
                                            w5, b5, w6, b6, w7, b7, wt, (float*)d_out);
}

// Round 3
// 541.373 us; speedup vs baseline: 1.9838x; 1.1511x over previous
//
#include <hip/hip_runtime.h>

#define N_NODES 100000
#define P_PATHS 10000
#define NCHUNK 98   // ceil(100000/1024)

// ---------------- Kernel 1: feat = x@fc_w, el/er attention scores ----------
__global__ __launch_bounds__(256) void k_feat(const float* __restrict__ x,
                                              const float* __restrict__ fc_w,
                                              const float* __restrict__ attn_l,
                                              const float* __restrict__ attn_r,
                                              float* __restrict__ feat,
                                              float* __restrict__ el,
                                              float* __restrict__ er) {
    __shared__ float s_w[64 * 64];
    __shared__ float s_al[64], s_ar[64];
    int tid = threadIdx.x;
    for (int i = tid; i < 64 * 64; i += 256) s_w[i] = fc_w[i];
    if (tid < 64) { s_al[tid] = attn_l[tid]; s_ar[tid] = attn_r[tid]; }
    __syncthreads();
    int wave = tid >> 6, lane = tid & 63;
    int n = blockIdx.x * 4 + wave;
    if (n >= N_NODES) return;
    float xv = x[n * 64 + lane];
    float acc = 0.f;
#pragma unroll
    for (int k = 0; k < 64; ++k) {
        acc += __shfl(xv, k) * s_w[k * 64 + lane];
    }
    feat[n * 64 + lane] = acc;
    int h = lane >> 4;
    float pl = acc * s_al[lane];
    float pr = acc * s_ar[lane];
#pragma unroll
    for (int off = 1; off < 16; off <<= 1) {
        pl += __shfl_xor(pl, off);
        pr += __shfl_xor(pr, off);
    }
    if ((lane & 15) == 0) {
        el[n * 4 + h] = pl;
        er[n * 4 + h] = pr;
    }
}

// ---------------- CSR build: histogram -> scan -> scatter ------------------
__global__ __launch_bounds__(256) void k_hist(const int* __restrict__ dst,
                                              int* __restrict__ deg, int E) {
    int i = blockIdx.x * 256 + threadIdx.x;
    if (i < E) atomicAdd(deg + dst[i], 1);
}

__global__ __launch_bounds__(256) void k_scan_a(const int* __restrict__ deg,
                                                int* __restrict__ excl,
                                                int* __restrict__ csum, int n) {
    __shared__ int s[256];
    int tid = threadIdx.x;
    int idx = blockIdx.x * 1024 + tid * 4;
    int v0 = 0, v1 = 0, v2 = 0, v3 = 0;
    if (idx + 0 < n) v0 = deg[idx + 0];
    if (idx + 1 < n) v1 = deg[idx + 1];
    if (idx + 2 < n) v2 = deg[idx + 2];
    if (idx + 3 < n) v3 = deg[idx + 3];
    int tsum = v0 + v1 + v2 + v3;
    s[tid] = tsum;
    __syncthreads();
    for (int off = 1; off < 256; off <<= 1) {
        int t = (tid >= off) ? s[tid - off] : 0;
        __syncthreads();
        s[tid] += t;
        __syncthreads();
    }
    int texcl = s[tid] - tsum;
    if (tid == 255) csum[blockIdx.x] = s[255];
    if (idx + 0 < n) excl[idx + 0] = texcl;
    if (idx + 1 < n) excl[idx + 1] = texcl + v0;
    if (idx + 2 < n) excl[idx + 2] = texcl + v0 + v1;
    if (idx + 3 < n) excl[idx + 3] = texcl + v0 + v1 + v2;
}

__global__ __launch_bounds__(128) void k_scan_b(int* __restrict__ csum, int nch) {
    __shared__ int s[128];
    int tid = threadIdx.x;
    int v = (tid < nch) ? csum[tid] : 0;
    s[tid] = v;
    __syncthreads();
    for (int off = 1; off < 128; off <<= 1) {
        int t = (tid >= off) ? s[tid - off] : 0;
        __syncthreads();
        s[tid] += t;
        __syncthreads();
    }
    if (tid < nch) csum[tid] = s[tid] - v;   // exclusive
}

__global__ __launch_bounds__(256) void k_scan_c(int* __restrict__ rowptr,
                                                const int* __restrict__ csum,
                                                int* __restrict__ wptr, int n, int E) {
    int i = blockIdx.x * 256 + threadIdx.x;
    if (i < n) {
        int v = rowptr[i] + csum[i >> 10];
        rowptr[i] = v;
        wptr[i] = v;
        if (i == 0) rowptr[n] = E;
    }
}

__global__ __launch_bounds__(256) void k_scatter(const int* __restrict__ src,
                                                 const int* __restrict__ dst,
                                                 int* __restrict__ wptr,
                                                 int* __restrict__ csr, int E) {
    int i = blockIdx.x * 256 + threadIdx.x;
    if (i < E) {
        int pos = atomicAdd(wptr + dst[i], 1);
        csr[pos] = src[i];
    }
}

// ---------------- Aggregation: one wave per node, no atomics ---------------
__global__ __launch_bounds__(256) void k_agg(const int* __restrict__ rowptr,
                                             const int* __restrict__ csr,
                                             const float* __restrict__ el,
                                             const float* __restrict__ er,
                                             const float* __restrict__ feat,
                                             const float* __restrict__ bias,
                                             float* __restrict__ agg) {
    int tid = threadIdx.x;
    int wave = tid >> 6, lane = tid & 63;
    int n = blockIdx.x * 4 + wave;
    if (n >= N_NODES) return;
    int h = lane >> 4;
    float ern = er[(size_t)n * 4 + h];
    int e0 = rowptr[n], e1 = rowptr[n + 1];
    float acc = 0.f, den = 0.f;
    int s_next = (e0 < e1) ? csr[e0] : 0;
    for (int e = e0; e < e1; ++e) {
        int s = s_next;
        if (e + 1 < e1) s_next = csr[e + 1];
        float ev = el[(size_t)s * 4 + h] + ern;
        ev = ev > 0.f ? ev : 0.2f * ev;
        float ez = __expf(ev);
        acc += ez * feat[(size_t)s * 64 + lane];
        den += ez;
    }
    agg[(size_t)n * 64 + lane] = acc / den + bias[lane];
}

// ---------------- Kernel 4: fused 7-layer MLP + skip linear ----------------
// 8 paths per block, 192 threads (thread = output column, 8 row-accumulators).
__device__ __forceinline__ void mlp_layer8(const float* in, int sin, float* out, int sout,
                                           const float* __restrict__ w,
                                           const float* __restrict__ b,
                                           int din, int dout, int tid) {
    if (tid < dout) {
        float acc[8];
#pragma unroll
        for (int r = 0; r < 8; ++r) acc[r] = 0.f;
        int k = 0;
        for (; k + 4 <= din; k += 4) {
            float w0 = w[(k + 0) * dout + tid];
            float w1 = w[(k + 1) * dout + tid];
            float w2 = w[(k + 2) * dout + tid];
            float w3 = w[(k + 3) * dout + tid];
#pragma unroll
            for (int r = 0; r < 8; ++r) {
                float4 iv = *(const float4*)(in + r * sin + k);
                acc[r] += iv.x * w0 + iv.y * w1 + iv.z * w2 + iv.w * w3;
            }
        }
        for (; k < din; ++k) {
            float wv = w[k * dout + tid];
#pragma unroll
            for (int r = 0; r < 8; ++r) acc[r] += in[r * sin + k] * wv;
        }
        float bb = b[tid];
#pragma unroll
        for (int r = 0; r < 8; ++r) {
            float v = acc[r] + bb;
            out[r * sout + tid] = v > 0.f ? v : 0.f;  // relu (layers 1..6)
        }
    }
}

__global__ __launch_bounds__(192) void k_mlp(const float* __restrict__ agg,
                                             const float* __restrict__ w1, const float* __restrict__ b1,
                                             const float* __restrict__ w2, const float* __restrict__ b2,
                                             const float* __restrict__ w3, const float* __restrict__ b3,
                                             const float* __restrict__ w4, const float* __restrict__ b4,
                                             const float* __restrict__ w5, const float* __restrict__ b5,
                                             const float* __restrict__ w6, const float* __restrict__ b6,
                                             const float* __restrict__ w7, const float* __restrict__ b7,
                                             const float* __restrict__ wt,
                                             float* __restrict__ outp) {
    __shared__ float buf0[8][184];
    __shared__ float buf1[8][184];
    __shared__ float wx[8];
    int tid = threadIdx.x;
    int p0 = blockIdx.x * 8;
    const float* gg = agg + (size_t)p0 * 640;   // 8x640 tile, L2/L3-resident

    // skip linear: wx[r] = g[r] . wt  (first wave: 8 lanes per row)
    if (tid < 64) {
        int r = tid >> 3, sub = tid & 7;
        float acc = 0.f;
        for (int k = sub * 4; k < 640; k += 32) {
            float4 gv = *(const float4*)(gg + r * 640 + k);
            float4 wv = *(const float4*)(wt + k);
            acc += gv.x * wv.x + gv.y * wv.y + gv.z * wv.z + gv.w * wv.w;
        }
        acc += __shfl_xor(acc, 1);
        acc += __shfl_xor(acc, 2);
        acc += __shfl_xor(acc, 4);
        if (sub == 0) wx[r] = acc;
    }

    // layer 1: activations from global (wave-uniform addresses -> scalar loads)
    if (tid < 180) {
        float acc[8];
#pragma unroll
        for (int r = 0; r < 8; ++r) acc[r] = 0.f;
        for (int k = 0; k < 640; k += 4) {
            float w0 = w1[(k + 0) * 180 + tid];
            float wv1 = w1[(k + 1) * 180 + tid];
            float w2v = w1[(k + 2) * 180 + tid];
            float w3v = w1[(k + 3) * 180 + tid];
#pragma unroll
            for (int r = 0; r < 8; ++r) {
                float4 iv = *(const float4*)(gg + r * 640 + k);
                acc[r] += iv.x * w0 + iv.y * wv1 + iv.z * w2v + iv.w * w3v;
            }
        }
        float bb = b1[tid];
#pragma unroll
        for (int r = 0; r < 8; ++r) {
            float v = acc[r] + bb;
            buf0[r][tid] = v > 0.f ? v : 0.f;
        }
    }
    __syncthreads();
    mlp_layer8(&buf0[0][0], 184, &buf1[0][0], 184, w2, b2, 180, 150, tid);
    __syncthreads();
    mlp_layer8(&buf1[0][0], 184, &buf0[0][0], 184, w3, b3, 150, 128, tid);
    __syncthreads();
    mlp_layer8(&buf0[0][0], 184, &buf1[0][0], 184, w4, b4, 128, 80, tid);
    __syncthreads();
    mlp_layer8(&buf1[0][0], 184, &buf0[0][0], 184, w5, b5, 80, 64, tid);
    __syncthreads();
    mlp_layer8(&buf0[0][0], 184, &buf1[0][0], 184, w6, b6, 64, 32, tid);
    __syncthreads();
    // layer 7 (32 -> 1, no relu) + wx
    if (tid < 8) {
        int r = tid;
        float acc = b7[0];
#pragma unroll
        for (int k = 0; k < 32; ++k) acc += buf1[r][k] * w7[k];
        outp[p0 + r] = acc + wx[r];
    }
}

extern "C" void kernel_launch(void* const* d_in, const int* in_sizes, int n_in,
                              void* d_out, int out_size, void* d_ws, size_t ws_size,
                              hipStream_t stream) {
    const float* x      = (const float*)d_in[0];
    const int*   src    = (const int*)d_in[1];
    const int*   dst    = (const int*)d_in[2];
    const float* fc_w   = (const float*)d_in[3];
    const float* bias   = (const float*)d_in[4];
    const float* attn_l = (const float*)d_in[5];
    const float* attn_r = (const float*)d_in[6];
    const float* w1 = (const float*)d_in[7];  const float* b1 = (const float*)d_in[8];
    const float* w2 = (const float*)d_in[9];  const float* b2 = (const float*)d_in[10];
    const float* w3 = (const float*)d_in[11]; const float* b3 = (const float*)d_in[12];
    const float* w4 = (const float*)d_in[13]; const float* b4 = (const float*)d_in[14];
    const float* w5 = (const float*)d_in[15]; const float* b5 = (const float*)d_in[16];
    const float* w6 = (const float*)d_in[17]; const float* b6 = (const float*)d_in[18];
    const float* w7 = (const float*)d_in[19]; const float* b7 = (const float*)d_in[20];
    const float* wt = (const float*)d_in[21];
    int E = in_sizes[1];

    float* ws     = (float*)d_ws;
    float* feat   = ws;                         // 6,400,000 f
    float* el     = ws + 6400000;               //   400,000 f
    float* er     = ws + 6800000;               //   400,000 f
    float* agg    = ws + 7200000;               // 6,400,000 f
    int*   deg    = (int*)(ws + 13600000);      //   100,000 i (reused as wptr)
    int*   rowptr = (int*)(ws + 13700000);      //   100,001 i (pad to 100,004)
    int*   csum   = (int*)(ws + 13800004);      //       128 i
    int*   csr    = (int*)(ws + 13800132);      //         E i

    int egrid = (E + 255) / 256;

    hipMemsetAsync(deg, 0, (size_t)N_NODES * 4, stream);

    k_feat<<<N_NODES / 4, 256, 0, stream>>>(x, fc_w, attn_l, attn_r, feat, el, er);
    k_hist<<<egrid, 256, 0, stream>>>(dst, deg, E);
    k_scan_a<<<NCHUNK, 256, 0, stream>>>(deg, rowptr, csum, N_NODES);
    k_scan_b<<<1, 128, 0, stream>>>(csum, NCHUNK);
    k_scan_c<<<(N_NODES + 255) / 256, 256, 0, stream>>>(rowptr, csum, deg /*wptr*/, N_NODES, E);
    k_scatter<<<egrid, 256, 0, stream>>>(src, dst, deg /*wptr*/, csr, E);
    k_agg<<<N_NODES / 4, 256, 0, stream>>>(rowptr, csr, el, er, feat, bias, agg);
    k_mlp<<<P_PATHS / 8, 192, 0, stream>>>(agg, w1, b1, w2, b2, w3, b3, w4, b4,
                                           w5, b5, w6, b6, w7, b7, wt, (float*)d_out);
}

// Round 4
// 518.305 us; speedup vs baseline: 2.0721x; 1.0445x over previous
//
#include <hip/hip_runtime.h>

#define N_NODES 100000
#define P_PATHS 10000
#define NCHUNK 98   // ceil(100000/1024)
#define NBUK 196    // ceil(100000/512)

// ---------------- Kernel 1: feat = x@fc_w, el/er attention scores ----------
__global__ __launch_bounds__(256) void k_feat(const float* __restrict__ x,
                                              const float* __restrict__ fc_w,
                                              const float* __restrict__ attn_l,
                                              const float* __restrict__ attn_r,
                                              float* __restrict__ feat,
                                              float* __restrict__ el,
                                              float* __restrict__ er) {
    __shared__ float s_w[64 * 64];
    __shared__ float s_al[64], s_ar[64];
    int tid = threadIdx.x;
    for (int i = tid; i < 64 * 64; i += 256) s_w[i] = fc_w[i];
    if (tid < 64) { s_al[tid] = attn_l[tid]; s_ar[tid] = attn_r[tid]; }
    __syncthreads();
    int wave = tid >> 6, lane = tid & 63;
    int n = blockIdx.x * 4 + wave;
    if (n >= N_NODES) return;
    float xv = x[n * 64 + lane];
    float acc = 0.f;
#pragma unroll
    for (int k = 0; k < 64; ++k) {
        acc += __shfl(xv, k) * s_w[k * 64 + lane];
    }
    feat[n * 64 + lane] = acc;
    int h = lane >> 4;
    float pl = acc * s_al[lane];
    float pr = acc * s_ar[lane];
#pragma unroll
    for (int off = 1; off < 16; off <<= 1) {
        pl += __shfl_xor(pl, off);
        pr += __shfl_xor(pr, off);
    }
    if ((lane & 15) == 0) {
        el[n * 4 + h] = pl;
        er[n * 4 + h] = pr;
    }
}

// ---------------- CSR build: histogram -> scan -> bucket sort --------------
__global__ __launch_bounds__(256) void k_hist(const int* __restrict__ dst,
                                              int* __restrict__ deg, int E) {
    int base = (blockIdx.x * 256 + threadIdx.x) * 4;
    if (base + 3 < E) {
        int4 d4 = *(const int4*)(dst + base);
        atomicAdd(deg + d4.x, 1);
        atomicAdd(deg + d4.y, 1);
        atomicAdd(deg + d4.z, 1);
        atomicAdd(deg + d4.w, 1);
    } else {
        for (int i = base; i < E; ++i) atomicAdd(deg + dst[i], 1);
    }
}

__global__ __launch_bounds__(256) void k_scan_a(const int* __restrict__ deg,
                                                int* __restrict__ excl,
                                                int* __restrict__ csum, int n) {
    __shared__ int s[256];
    int tid = threadIdx.x;
    int idx = blockIdx.x * 1024 + tid * 4;
    int v0 = 0, v1 = 0, v2 = 0, v3 = 0;
    if (idx + 0 < n) v0 = deg[idx + 0];
    if (idx + 1 < n) v1 = deg[idx + 1];
    if (idx + 2 < n) v2 = deg[idx + 2];
    if (idx + 3 < n) v3 = deg[idx + 3];
    int tsum = v0 + v1 + v2 + v3;
    s[tid] = tsum;
    __syncthreads();
    for (int off = 1; off < 256; off <<= 1) {
        int t = (tid >= off) ? s[tid - off] : 0;
        __syncthreads();
        s[tid] += t;
        __syncthreads();
    }
    int texcl = s[tid] - tsum;
    if (tid == 255) csum[blockIdx.x] = s[255];
    if (idx + 0 < n) excl[idx + 0] = texcl;
    if (idx + 1 < n) excl[idx + 1] = texcl + v0;
    if (idx + 2 < n) excl[idx + 2] = texcl + v0 + v1;
    if (idx + 3 < n) excl[idx + 3] = texcl + v0 + v1 + v2;
}

__global__ __launch_bounds__(128) void k_scan_b(int* __restrict__ csum, int nch) {
    __shared__ int s[128];
    int tid = threadIdx.x;
    int v = (tid < nch) ? csum[tid] : 0;
    s[tid] = v;
    __syncthreads();
    for (int off = 1; off < 128; off <<= 1) {
        int t = (tid >= off) ? s[tid - off] : 0;
        __syncthreads();
        s[tid] += t;
        __syncthreads();
    }
    if (tid < nch) csum[tid] = s[tid] - v;   // exclusive
}

__global__ __launch_bounds__(256) void k_scan_c(int* __restrict__ rowptr,
                                                const int* __restrict__ csum,
                                                int* __restrict__ wptr,
                                                int* __restrict__ bukptr, int n, int E) {
    int i = blockIdx.x * 256 + threadIdx.x;
    if (i < n) {
        int v = rowptr[i] + csum[i >> 10];
        rowptr[i] = v;
        wptr[i] = v;
        if ((i & 511) == 0) bukptr[i >> 9] = v;
        if (i == 0) rowptr[n] = E;
    }
}

// Pass A: bucket edges (bucket = dst>>9) into pair buffer, LDS-staged counts.
__global__ __launch_bounds__(256) void k_bucketA(const int* __restrict__ src,
                                                 const int* __restrict__ dst,
                                                 int* __restrict__ bukptr,
                                                 uint2* __restrict__ pair, int E) {
    __shared__ int cnt[NBUK];
    __shared__ int base[NBUK];
    int tid = threadIdx.x;
    if (tid < NBUK) cnt[tid] = 0;
    __syncthreads();
    int b0 = blockIdx.x * 2048;
    int s[8], d[8], off[8];
#pragma unroll
    for (int j = 0; j < 8; ++j) {
        int i = b0 + j * 256 + tid;
        if (i < E) {
            s[j] = src[i];
            d[j] = dst[i];
            off[j] = atomicAdd(&cnt[d[j] >> 9], 1);
        } else {
            d[j] = -1; s[j] = 0; off[j] = 0;
        }
    }
    __syncthreads();
    if (tid < NBUK) base[tid] = atomicAdd(bukptr + tid, cnt[tid]);
    __syncthreads();
#pragma unroll
    for (int j = 0; j < 8; ++j) {
        if (d[j] >= 0) {
            int pos = base[d[j] >> 9] + off[j];
            pair[pos] = make_uint2((unsigned)s[j], (unsigned)d[j]);
        }
    }
}

// Pass B: scatter within bucket windows; XCD-chunked block swizzle keeps each
// XCD's write window L2-resident.
__global__ __launch_bounds__(256) void k_bucketB(const uint2* __restrict__ pair,
                                                 int* __restrict__ wptr,
                                                 int* __restrict__ csr, int E, int nwg) {
    int orig = blockIdx.x;
    int q = nwg >> 3, r = nwg & 7;
    int xcd = orig & 7, j = orig >> 3;
    int bid = (xcd < r ? xcd * (q + 1) : r * (q + 1) + (xcd - r) * q) + j;
    int b0 = bid * 2048;
#pragma unroll
    for (int jj = 0; jj < 8; ++jj) {
        int i = b0 + jj * 256 + threadIdx.x;
        if (i < E) {
            uint2 p = pair[i];
            int pos = atomicAdd(wptr + (int)p.y, 1);
            csr[pos] = (int)p.x;
        }
    }
}

// ---------------- Aggregation: one wave per node, no atomics ---------------
__global__ __launch_bounds__(256) void k_agg(const int* __restrict__ rowptr,
                                             const int* __restrict__ csr,
                                             const float* __restrict__ el,
                                             const float* __restrict__ er,
                                             const float* __restrict__ feat,
                                             const float* __restrict__ bias,
                                             float* __restrict__ agg) {
    int tid = threadIdx.x;
    int wave = tid >> 6, lane = tid & 63;
    int n = blockIdx.x * 4 + wave;
    if (n >= N_NODES) return;
    int h = lane >> 4;
    float ern = er[(size_t)n * 4 + h];
    int e0 = rowptr[n], e1 = rowptr[n + 1];
    float acc = 0.f, den = 0.f;
    int s_next = (e0 < e1) ? csr[e0] : 0;
    for (int e = e0; e < e1; ++e) {
        int s = s_next;
        if (e + 1 < e1) s_next = csr[e + 1];
        float ev = el[(size_t)s * 4 + h] + ern;
        ev = ev > 0.f ? ev : 0.2f * ev;
        float ez = __expf(ev);
        acc += ez * feat[(size_t)s * 64 + lane];
        den += ez;
    }
    agg[(size_t)n * 64 + lane] = acc / den + bias[lane];
}

// ---------------- Kernel 4: fused 7-layer MLP + skip linear ----------------
// 8 paths/block, 192 threads; weight loads double-buffered (software pipeline).
__device__ __forceinline__ void mlp_layer8(const float* in, int sin, float* out, int sout,
                                           const float* __restrict__ w,
                                           const float* __restrict__ b,
                                           int din, int dout, int tid) {
    if (tid < dout) {
        float acc[8];
#pragma unroll
        for (int r = 0; r < 8; ++r) acc[r] = 0.f;
        int k = 0;
        float wa0 = w[0 * dout + tid], wa1 = w[1 * dout + tid],
              wa2 = w[2 * dout + tid], wa3 = w[3 * dout + tid];
        for (; k + 8 <= din; k += 4) {
            float wb0 = w[(k + 4) * dout + tid], wb1 = w[(k + 5) * dout + tid],
                  wb2 = w[(k + 6) * dout + tid], wb3 = w[(k + 7) * dout + tid];
#pragma unroll
            for (int r = 0; r < 8; ++r) {
                float4 iv = *(const float4*)(in + r * sin + k);
                acc[r] += iv.x * wa0 + iv.y * wa1 + iv.z * wa2 + iv.w * wa3;
            }
            wa0 = wb0; wa1 = wb1; wa2 = wb2; wa3 = wb3;
        }
        {
#pragma unroll
            for (int r = 0; r < 8; ++r) {
                float4 iv = *(const float4*)(in + r * sin + k);
                acc[r] += iv.x * wa0 + iv.y * wa1 + iv.z * wa2 + iv.w * wa3;
            }
            k += 4;
        }
        for (; k < din; ++k) {
            float wv = w[k * dout + tid];
#pragma unroll
            for (int r = 0; r < 8; ++r) acc[r] += in[r * sin + k] * wv;
        }
        float bb = b[tid];
#pragma unroll
        for (int r = 0; r < 8; ++r) {
            float v = acc[r] + bb;
            out[r * sout + tid] = v > 0.f ? v : 0.f;  // relu (layers 1..6)
        }
    }
}

__global__ __launch_bounds__(192) void k_mlp(const float* __restrict__ agg,
                                             const float* __restrict__ w1, const float* __restrict__ b1,
                                             const float* __restrict__ w2, const float* __restrict__ b2,
                                             const float* __restrict__ w3, const float* __restrict__ b3,
                                             const float* __restrict__ w4, const float* __restrict__ b4,
                                             const float* __restrict__ w5, const float* __restrict__ b5,
                                             const float* __restrict__ w6, const float* __restrict__ b6,
                                             const float* __restrict__ w7, const float* __restrict__ b7,
                                             const float* __restrict__ wt,
                                             float* __restrict__ outp) {
    __shared__ float buf0[8][184];
    __shared__ float buf1[8][184];
    __shared__ float wx[8];
    int tid = threadIdx.x;
    int p0 = blockIdx.x * 8;
    const float* gg = agg + (size_t)p0 * 640;   // 8x640 tile, L2/L3-resident

    // skip linear: wx[r] = g[r] . wt  (first wave: 8 lanes per row)
    if (tid < 64) {
        int r = tid >> 3, sub = tid & 7;
        float acc = 0.f;
        for (int k = sub * 4; k < 640; k += 32) {
            float4 gv = *(const float4*)(gg + r * 640 + k);
            float4 wv = *(const float4*)(wt + k);
            acc += gv.x * wv.x + gv.y * wv.y + gv.z * wv.z + gv.w * wv.w;
        }
        acc += __shfl_xor(acc, 1);
        acc += __shfl_xor(acc, 2);
        acc += __shfl_xor(acc, 4);
        if (sub == 0) wx[r] = acc;
    }

    // layer 1: activations straight from global (lane-uniform -> scalar loads),
    // weights software-pipelined
    if (tid < 180) {
        float acc[8];
#pragma unroll
        for (int r = 0; r < 8; ++r) acc[r] = 0.f;
        float wa0 = w1[0 * 180 + tid], wa1 = w1[1 * 180 + tid],
              wa2 = w1[2 * 180 + tid], wa3 = w1[3 * 180 + tid];
        int k = 0;
        for (; k + 8 <= 640; k += 4) {
            float wb0 = w1[(k + 4) * 180 + tid], wb1 = w1[(k + 5) * 180 + tid],
                  wb2 = w1[(k + 6) * 180 + tid], wb3 = w1[(k + 7) * 180 + tid];
#pragma unroll
            for (int r = 0; r < 8; ++r) {
                float4 iv = *(const float4*)(gg + r * 640 + k);
                acc[r] += iv.x * wa0 + iv.y * wa1 + iv.z * wa2 + iv.w * wa3;
            }
            wa0 = wb0; wa1 = wb1; wa2 = wb2; wa3 = wb3;
        }
#pragma unroll
        for (int r = 0; r < 8; ++r) {
            float4 iv = *(const float4*)(gg + r * 640 + k);
            acc[r] += iv.x * wa0 + iv.y * wa1 + iv.z * wa2 + iv.w * wa3;
        }
        float bb = b1[tid];
#pragma unroll
        for (int r = 0; r < 8; ++r) {
            float v = acc[r] + bb;
            buf0[r][tid] = v > 0.f ? v : 0.f;
        }
    }
    __syncthreads();
    mlp_layer8(&buf0[0][0], 184, &buf1[0][0], 184, w2, b2, 180, 150, tid);
    __syncthreads();
    mlp_layer8(&buf1[0][0], 184, &buf0[0][0], 184, w3, b3, 150, 128, tid);
    __syncthreads();
    mlp_layer8(&buf0[0][0], 184, &buf1[0][0], 184, w4, b4, 128, 80, tid);
    __syncthreads();
    mlp_layer8(&buf1[0][0], 184, &buf0[0][0], 184, w5, b5, 80, 64, tid);
    __syncthreads();
    mlp_layer8(&buf0[0][0], 184, &buf1[0][0], 184, w6, b6, 64, 32, tid);
    __syncthreads();
    // layer 7 (32 -> 1, no relu) + wx
    if (tid < 8) {
        int r = tid;
        float acc = b7[0];
#pragma unroll
        for (int k = 0; k < 32; ++k) acc += buf1[r][k] * w7[k];
        outp[p0 + r] = acc + wx[r];
    }
}

extern "C" void kernel_launch(void* const* d_in, const int* in_sizes, int n_in,
                              void* d_out, int out_size, void* d_ws, size_t ws_size,
                              hipStream_t stream) {
    const float* x      = (const float*)d_in[0];
    const int*   src    = (const int*)d_in[1];
    const int*   dst    = (const int*)d_in[2];
    const float* fc_w   = (const float*)d_in[3];
    const float* bias   = (const float*)d_in[4];
    const float* attn_l = (const float*)d_in[5];
    const float* attn_r = (const float*)d_in[6];
    const float* w1 = (const float*)d_in[7];  const float* b1 = (const float*)d_in[8];
    const float* w2 = (const float*)d_in[9];  const float* b2 = (const float*)d_in[10];
    const float* w3 = (const float*)d_in[11]; const float* b3 = (const float*)d_in[12];
    const float* w4 = (const float*)d_in[13]; const float* b4 = (const float*)d_in[14];
    const float* w5 = (const float*)d_in[15]; const float* b5 = (const float*)d_in[16];
    const float* w6 = (const float*)d_in[17]; const float* b6 = (const float*)d_in[18];
    const float* w7 = (const float*)d_in[19]; const float* b7 = (const float*)d_in[20];
    const float* wt = (const float*)d_in[21];
    int E = in_sizes[1];

    float* ws     = (float*)d_ws;
    float* feat   = ws;                         // 6,400,000 f
    float* el     = ws + 6400000;               //   400,000 f
    float* er     = ws + 6800000;               //   400,000 f
    float* agg    = ws + 7200000;               // 6,400,000 f
    uint2* pair   = (uint2*)(ws + 7200000);     // aliases agg (dead before k_agg)
    int*   deg    = (int*)(ws + 13600000);      //   100,000 i (reused as wptr)
    int*   rowptr = (int*)(ws + 13700000);      //   100,001 i (pad to 100,004)
    int*   csum   = (int*)(ws + 13800004);      //       128 i
    int*   csr    = (int*)(ws + 13800132);      //         E i
    int*   bukptr = csr + E;                    //       196 i

    int nwg = (E + 2047) / 2048;

    hipMemsetAsync(deg, 0, (size_t)N_NODES * 4, stream);

    k_feat<<<N_NODES / 4, 256, 0, stream>>>(x, fc_w, attn_l, attn_r, feat, el, er);
    k_hist<<<(E + 1023) / 1024, 256, 0, stream>>>(dst, deg, E);
    k_scan_a<<<NCHUNK, 256, 0, stream>>>(deg, rowptr, csum, N_NODES);
    k_scan_b<<<1, 128, 0, stream>>>(csum, NCHUNK);
    k_scan_c<<<(N_NODES + 255) / 256, 256, 0, stream>>>(rowptr, csum, deg /*wptr*/, bukptr, N_NODES, E);
    k_bucketA<<<nwg, 256, 0, stream>>>(src, dst, bukptr, pair, E);
    k_bucketB<<<nwg, 256, 0, stream>>>(pair, deg /*wptr*/, csr, E, nwg);
    k_agg<<<N_NODES / 4, 256, 0, stream>>>(rowptr, csr, el, er, feat, bias, agg);
    k_mlp<<<P_PATHS / 8, 192, 0, stream>>>(agg, w1, b1, w2, b2, w3, b3, w4, b4,
                                           w5, b5, w6, b6, w7, b7, wt, (float*)d_out);
}

// Round 5
// 508.237 us; speedup vs baseline: 2.1132x; 1.0198x over previous
//
#include <hip/hip_runtime.h>

#define N_NODES 100000
#define P_PATHS 10000
#define NCHUNK 98   // ceil(100000/1024)
#define NBUK 196    // ceil(100000/512)

// ---------------- Kernel 1: feat = x@fc_w, el/er attention scores ----------
__global__ __launch_bounds__(256) void k_feat(const float* __restrict__ x,
                                              const float* __restrict__ fc_w,
                                              const float* __restrict__ attn_l,
                                              const float* __restrict__ attn_r,
                                              float* __restrict__ feat,
                                              float* __restrict__ el,
                                              float* __restrict__ er) {
    __shared__ float s_w[64 * 64];
    __shared__ float s_al[64], s_ar[64];
    int tid = threadIdx.x;
    for (int i = tid; i < 64 * 64; i += 256) s_w[i] = fc_w[i];
    if (tid < 64) { s_al[tid] = attn_l[tid]; s_ar[tid] = attn_r[tid]; }
    __syncthreads();
    int wave = tid >> 6, lane = tid & 63;
    int n = blockIdx.x * 4 + wave;
    if (n >= N_NODES) return;
    float xv = x[n * 64 + lane];
    float acc = 0.f;
#pragma unroll
    for (int k = 0; k < 64; ++k) {
        acc += __shfl(xv, k) * s_w[k * 64 + lane];
    }
    feat[n * 64 + lane] = acc;
    int h = lane >> 4;
    float pl = acc * s_al[lane];
    float pr = acc * s_ar[lane];
#pragma unroll
    for (int off = 1; off < 16; off <<= 1) {
        pl += __shfl_xor(pl, off);
        pr += __shfl_xor(pr, off);
    }
    if ((lane & 15) == 0) {
        el[n * 4 + h] = pl;
        er[n * 4 + h] = pr;
    }
}

// ---------------- CSR build: histogram -> scan -> bucket sort --------------
__global__ __launch_bounds__(256) void k_hist(const int* __restrict__ dst,
                                              int* __restrict__ deg, int E) {
    int base = (blockIdx.x * 256 + threadIdx.x) * 4;
    if (base + 3 < E) {
        int4 d4 = *(const int4*)(dst + base);
        atomicAdd(deg + d4.x, 1);
        atomicAdd(deg + d4.y, 1);
        atomicAdd(deg + d4.z, 1);
        atomicAdd(deg + d4.w, 1);
    } else {
        for (int i = base; i < E; ++i) atomicAdd(deg + dst[i], 1);
    }
}

__global__ __launch_bounds__(256) void k_scan_a(const int* __restrict__ deg,
                                                int* __restrict__ excl,
                                                int* __restrict__ csum, int n) {
    __shared__ int s[256];
    int tid = threadIdx.x;
    int idx = blockIdx.x * 1024 + tid * 4;
    int v0 = 0, v1 = 0, v2 = 0, v3 = 0;
    if (idx + 0 < n) v0 = deg[idx + 0];
    if (idx + 1 < n) v1 = deg[idx + 1];
    if (idx + 2 < n) v2 = deg[idx + 2];
    if (idx + 3 < n) v3 = deg[idx + 3];
    int tsum = v0 + v1 + v2 + v3;
    s[tid] = tsum;
    __syncthreads();
    for (int off = 1; off < 256; off <<= 1) {
        int t = (tid >= off) ? s[tid - off] : 0;
        __syncthreads();
        s[tid] += t;
        __syncthreads();
    }
    int texcl = s[tid] - tsum;
    if (tid == 255) csum[blockIdx.x] = s[255];
    if (idx + 0 < n) excl[idx + 0] = texcl;
    if (idx + 1 < n) excl[idx + 1] = texcl + v0;
    if (idx + 2 < n) excl[idx + 2] = texcl + v0 + v1;
    if (idx + 3 < n) excl[idx + 3] = texcl + v0 + v1 + v2;
}

__global__ __launch_bounds__(128) void k_scan_b(int* __restrict__ csum, int nch) {
    __shared__ int s[128];
    int tid = threadIdx.x;
    int v = (tid < nch) ? csum[tid] : 0;
    s[tid] = v;
    __syncthreads();
    for (int off = 1; off < 128; off <<= 1) {
        int t = (tid >= off) ? s[tid - off] : 0;
        __syncthreads();
        s[tid] += t;
        __syncthreads();
    }
    if (tid < nch) csum[tid] = s[tid] - v;   // exclusive
}

__global__ __launch_bounds__(256) void k_scan_c(int* __restrict__ rowptr,
                                                const int* __restrict__ csum,
                                                int* __restrict__ wptr,
                                                int* __restrict__ bukptr, int n, int E) {
    int i = blockIdx.x * 256 + threadIdx.x;
    if (i < n) {
        int v = rowptr[i] + csum[i >> 10];
        rowptr[i] = v;
        wptr[i] = v;
        if ((i & 511) == 0) bukptr[i >> 9] = v;
        if (i == 0) rowptr[n] = E;
    }
}

// Pass A: bucket edges (bucket = dst>>9) into pair buffer, LDS-staged counts.
__global__ __launch_bounds__(256) void k_bucketA(const int* __restrict__ src,
                                                 const int* __restrict__ dst,
                                                 int* __restrict__ bukptr,
                                                 uint2* __restrict__ pair, int E) {
    __shared__ int cnt[NBUK];
    __shared__ int base[NBUK];
    int tid = threadIdx.x;
    if (tid < NBUK) cnt[tid] = 0;
    __syncthreads();
    int b0 = blockIdx.x * 2048;
    int s[8], d[8], off[8];
#pragma unroll
    for (int j = 0; j < 8; ++j) {
        int i = b0 + j * 256 + tid;
        if (i < E) {
            s[j] = src[i];
            d[j] = dst[i];
            off[j] = atomicAdd(&cnt[d[j] >> 9], 1);
        } else {
            d[j] = -1; s[j] = 0; off[j] = 0;
        }
    }
    __syncthreads();
    if (tid < NBUK) base[tid] = atomicAdd(bukptr + tid, cnt[tid]);
    __syncthreads();
#pragma unroll
    for (int j = 0; j < 8; ++j) {
        if (d[j] >= 0) {
            int pos = base[d[j] >> 9] + off[j];
            pair[pos] = make_uint2((unsigned)s[j], (unsigned)d[j]);
        }
    }
}

// Pass B: scatter within bucket windows; XCD-chunked block swizzle keeps each
// XCD's write window L2-resident.
__global__ __launch_bounds__(256) void k_bucketB(const uint2* __restrict__ pair,
                                                 int* __restrict__ wptr,
                                                 int* __restrict__ csr, int E, int nwg) {
    int orig = blockIdx.x;
    int q = nwg >> 3, r = nwg & 7;
    int xcd = orig & 7, j = orig >> 3;
    int bid = (xcd < r ? xcd * (q + 1) : r * (q + 1) + (xcd - r) * q) + j;
    int b0 = bid * 2048;
#pragma unroll
    for (int jj = 0; jj < 8; ++jj) {
        int i = b0 + jj * 256 + threadIdx.x;
        if (i < E) {
            uint2 p = pair[i];
            int pos = atomicAdd(wptr + (int)p.y, 1);
            csr[pos] = (int)p.x;
        }
    }
}

// ---------------- Aggregation: one wave per node, no atomics ---------------
__global__ __launch_bounds__(256) void k_agg(const int* __restrict__ rowptr,
                                             const int* __restrict__ csr,
                                             const float* __restrict__ el,
                                             const float* __restrict__ er,
                                             const float* __restrict__ feat,
                                             const float* __restrict__ bias,
                                             float* __restrict__ agg) {
    int tid = threadIdx.x;
    int wave = tid >> 6, lane = tid & 63;
    int n = blockIdx.x * 4 + wave;
    if (n >= N_NODES) return;
    int h = lane >> 4;
    float ern = er[(size_t)n * 4 + h];
    int e0 = rowptr[n], e1 = rowptr[n + 1];
    float acc = 0.f, den = 0.f;
    int s_next = (e0 < e1) ? csr[e0] : 0;
    for (int e = e0; e < e1; ++e) {
        int s = s_next;
        if (e + 1 < e1) s_next = csr[e + 1];
        float ev = el[(size_t)s * 4 + h] + ern;
        ev = ev > 0.f ? ev : 0.2f * ev;
        float ez = __expf(ev);
        acc += ez * feat[(size_t)s * 64 + lane];
        den += ez;
    }
    agg[(size_t)n * 64 + lane] = acc / den + bias[lane];
}

// ---------------- Kernel 4: fused 7-layer MLP + skip linear ----------------
// 4 paths/block (2500 blocks -> ~91% occupancy cap), 192 threads,
// weights software-pipelined, activations staged in LDS.
__device__ __forceinline__ void mlp_layer4(const float* in, int sin, float* out, int sout,
                                           const float* __restrict__ w,
                                           const float* __restrict__ b,
                                           int din, int dout, int tid) {
    if (tid < dout) {
        float acc[4];
#pragma unroll
        for (int r = 0; r < 4; ++r) acc[r] = 0.f;
        int k = 0;
        float wa0 = w[0 * dout + tid], wa1 = w[1 * dout + tid],
              wa2 = w[2 * dout + tid], wa3 = w[3 * dout + tid];
        for (; k + 8 <= din; k += 4) {
            float wb0 = w[(k + 4) * dout + tid], wb1 = w[(k + 5) * dout + tid],
                  wb2 = w[(k + 6) * dout + tid], wb3 = w[(k + 7) * dout + tid];
#pragma unroll
            for (int r = 0; r < 4; ++r) {
                float4 iv = *(const float4*)(in + r * sin + k);
                acc[r] += iv.x * wa0 + iv.y * wa1 + iv.z * wa2 + iv.w * wa3;
            }
            wa0 = wb0; wa1 = wb1; wa2 = wb2; wa3 = wb3;
        }
        {
#pragma unroll
            for (int r = 0; r < 4; ++r) {
                float4 iv = *(const float4*)(in + r * sin + k);
                acc[r] += iv.x * wa0 + iv.y * wa1 + iv.z * wa2 + iv.w * wa3;
            }
            k += 4;
        }
        for (; k < din; ++k) {
            float wv = w[k * dout + tid];
#pragma unroll
            for (int r = 0; r < 4; ++r) acc[r] += in[r * sin + k] * wv;
        }
        float bb = b[tid];
#pragma unroll
        for (int r = 0; r < 4; ++r) {
            float v = acc[r] + bb;
            out[r * sout + tid] = v > 0.f ? v : 0.f;  // relu (layers 1..6)
        }
    }
}

__global__ __launch_bounds__(192) void k_mlp(const float* __restrict__ agg,
                                             const float* __restrict__ w1, const float* __restrict__ b1,
                                             const float* __restrict__ w2, const float* __restrict__ b2,
                                             const float* __restrict__ w3, const float* __restrict__ b3,
                                             const float* __restrict__ w4, const float* __restrict__ b4,
                                             const float* __restrict__ w5, const float* __restrict__ b5,
                                             const float* __restrict__ w6, const float* __restrict__ b6,
                                             const float* __restrict__ w7, const float* __restrict__ b7,
                                             const float* __restrict__ wt,
                                             float* __restrict__ outp) {
    __shared__ float g[4][640];
    __shared__ float buf0[4][184];
    __shared__ float buf1[4][184];
    __shared__ float wx[4];
    int tid = threadIdx.x;
    int p0 = blockIdx.x * 4;
    const float* gg = agg + (size_t)p0 * 640;

    // stage 4x640 g-tile into LDS (coalesced)
    for (int i = tid; i < 4 * 640; i += 192) ((float*)g)[i] = gg[i];
    __syncthreads();

    // skip linear: wx[r] = g[r] . wt  (32 lanes: 8 per row)
    if (tid < 32) {
        int r = tid >> 3, sub = tid & 7;
        float acc = 0.f;
        for (int k = sub * 4; k < 640; k += 32) {
            float4 gv = *(const float4*)(&g[r][k]);
            float4 wv = *(const float4*)(wt + k);
            acc += gv.x * wv.x + gv.y * wv.y + gv.z * wv.z + gv.w * wv.w;
        }
        acc += __shfl_xor(acc, 1);
        acc += __shfl_xor(acc, 2);
        acc += __shfl_xor(acc, 4);
        if (sub == 0) wx[r] = acc;
    }

    // layer 1: activations from LDS (broadcast), weights software-pipelined
    if (tid < 180) {
        float acc[4];
#pragma unroll
        for (int r = 0; r < 4; ++r) acc[r] = 0.f;
        float wa0 = w1[0 * 180 + tid], wa1 = w1[1 * 180 + tid],
              wa2 = w1[2 * 180 + tid], wa3 = w1[3 * 180 + tid];
        int k = 0;
        for (; k + 8 <= 640; k += 4) {
            float wb0 = w1[(k + 4) * 180 + tid], wb1 = w1[(k + 5) * 180 + tid],
                  wb2 = w1[(k + 6) * 180 + tid], wb3 = w1[(k + 7) * 180 + tid];
#pragma unroll
            for (int r = 0; r < 4; ++r) {
                float4 iv = *(const float4*)(&g[r][k]);
                acc[r] += iv.x * wa0 + iv.y * wa1 + iv.z * wa2 + iv.w * wa3;
            }
            wa0 = wb0; wa1 = wb1; wa2 = wb2; wa3 = wb3;
        }
#pragma unroll
        for (int r = 0; r < 4; ++r) {
            float4 iv = *(const float4*)(&g[r][k]);
            acc[r] += iv.x * wa0 + iv.y * wa1 + iv.z * wa2 + iv.w * wa3;
        }
        float bb = b1[tid];
#pragma unroll
        for (int r = 0; r < 4; ++r) {
            float v = acc[r] + bb;
            buf0[r][tid] = v > 0.f ? v : 0.f;
        }
    }
    __syncthreads();
    mlp_layer4(&buf0[0][0], 184, &buf1[0][0], 184, w2, b2, 180, 150, tid);
    __syncthreads();
    mlp_layer4(&buf1[0][0], 184, &buf0[0][0], 184, w3, b3, 150, 128, tid);
    __syncthreads();
    mlp_layer4(&buf0[0][0], 184, &buf1[0][0], 184, w4, b4, 128, 80, tid);
    __syncthreads();
    mlp_layer4(&buf1[0][0], 184, &buf0[0][0], 184, w5, b5, 80, 64, tid);
    __syncthreads();
    mlp_layer4(&buf0[0][0], 184, &buf1[0][0], 184, w6, b6, 64, 32, tid);
    __syncthreads();
    // layer 7 (32 -> 1, no relu) + wx
    if (tid < 4) {
        int r = tid;
        float acc = b7[0];
#pragma unroll
        for (int k = 0; k < 32; ++k) acc += buf1[r][k] * w7[k];
        outp[p0 + r] = acc + wx[r];
    }
}

extern "C" void kernel_launch(void* const* d_in, const int* in_sizes, int n_in,
                              void* d_out, int out_size, void* d_ws, size_t ws_size,
                              hipStream_t stream) {
    const float* x      = (const float*)d_in[0];
    const int*   src    = (const int*)d_in[1];
    const int*   dst    = (const int*)d_in[2];
    const float* fc_w   = (const float*)d_in[3];
    const float* bias   = (const float*)d_in[4];
    const float* attn_l = (const float*)d_in[5];
    const float* attn_r = (const float*)d_in[6];
    const float* w1 = (const float*)d_in[7];  const float* b1 = (const float*)d_in[8];
    const float* w2 = (const float*)d_in[9];  const float* b2 = (const float*)d_in[10];
    const float* w3 = (const float*)d_in[11]; const float* b3 = (const float*)d_in[12];
    const float* w4 = (const float*)d_in[13]; const float* b4 = (const float*)d_in[14];
    const float* w5 = (const float*)d_in[15]; const float* b5 = (const float*)d_in[16];
    const float* w6 = (const float*)d_in[17]; const float* b6 = (const float*)d_in[18];
    const float* w7 = (const float*)d_in[19]; const float* b7 = (const float*)d_in[20];
    const float* wt = (const float*)d_in[21];
    int E = in_sizes[1];

    float* ws     = (float*)d_ws;
    float* feat   = ws;                         // 6,400,000 f
    float* el     = ws + 6400000;               //   400,000 f
    float* er     = ws + 6800000;               //   400,000 f
    float* agg    = ws + 7200000;               // 6,400,000 f
    uint2* pair   = (uint2*)(ws + 7200000);     // aliases agg (dead before k_agg)
    int*   deg    = (int*)(ws + 13600000);      //   100,000 i (reused as wptr)
    int*   rowptr = (int*)(ws + 13700000);      //   100,001 i (pad to 100,004)
    int*   csum   = (int*)(ws + 13800004);      //       128 i
    int*   csr    = (int*)(ws + 13800132);      //         E i
    int*   bukptr = csr + E;                    //       196 i

    int nwg = (E + 2047) / 2048;

    hipMemsetAsync(deg, 0, (size_t)N_NODES * 4, stream);

    k_feat<<<N_NODES / 4, 256, 0, stream>>>(x, fc_w, attn_l, attn_r, feat, el, er);
    k_hist<<<(E + 1023) / 1024, 256, 0, stream>>>(dst, deg, E);
    k_scan_a<<<NCHUNK, 256, 0, stream>>>(deg, rowptr, csum, N_NODES);
    k_scan_b<<<1, 128, 0, stream>>>(csum, NCHUNK);
    k_scan_c<<<(N_NODES + 255) / 256, 256, 0, stream>>>(rowptr, csum, deg /*wptr*/, bukptr, N_NODES, E);
    k_bucketA<<<nwg, 256, 0, stream>>>(src, dst, bukptr, pair, E);
    k_bucketB<<<nwg, 256, 0, stream>>>(pair, deg /*wptr*/, csr, E, nwg);
    k_agg<<<N_NODES / 4, 256, 0, stream>>>(rowptr, csr, el, er, feat, bias, agg);
    k_mlp<<<P_PATHS / 4, 192, 0, stream>>>(agg, w1, b1, w2, b2, w3, b3, w4, b4,
                                           w5, b5, w6, b6, w7, b7, wt, (float*)d_out);
}

// Round 6
// 442.965 us; speedup vs baseline: 2.4245x; 1.1474x over previous
//
#include <hip/hip_runtime.h>
#include <hip/hip_bf16.h>

#define N_NODES 100000
#define P_PATHS 10000
#define NCHUNK 98   // ceil(100000/1024)
#define NBUK 196    // ceil(100000/512)

typedef __attribute__((ext_vector_type(8))) short s16x8;
typedef __attribute__((ext_vector_type(4))) short s16x4;
typedef __attribute__((ext_vector_type(4))) float f32x4;

__device__ __forceinline__ short f2bf(float v) {
    return __builtin_bit_cast(short, __float2bfloat16(v));
}
__device__ __forceinline__ float bf2f(short s) {
    return __bfloat162float(__builtin_bit_cast(__hip_bfloat16, s));
}

// ---------------- Kernel 1: feat = x@fc_w, el/er attention scores ----------
__global__ __launch_bounds__(256) void k_feat(const float* __restrict__ x,
                                              const float* __restrict__ fc_w,
                                              const float* __restrict__ attn_l,
                                              const float* __restrict__ attn_r,
                                              float* __restrict__ feat,
                                              float* __restrict__ el,
                                              float* __restrict__ er) {
    __shared__ float s_w[64 * 64];
    __shared__ float s_al[64], s_ar[64];
    int tid = threadIdx.x;
    for (int i = tid; i < 64 * 64; i += 256) s_w[i] = fc_w[i];
    if (tid < 64) { s_al[tid] = attn_l[tid]; s_ar[tid] = attn_r[tid]; }
    __syncthreads();
    int wave = tid >> 6, lane = tid & 63;
    int n = blockIdx.x * 4 + wave;
    if (n >= N_NODES) return;
    float xv = x[n * 64 + lane];
    float acc = 0.f;
#pragma unroll
    for (int k = 0; k < 64; ++k) {
        acc += __shfl(xv, k) * s_w[k * 64 + lane];
    }
    feat[n * 64 + lane] = acc;
    int h = lane >> 4;
    float pl = acc * s_al[lane];
    float pr = acc * s_ar[lane];
#pragma unroll
    for (int off = 1; off < 16; off <<= 1) {
        pl += __shfl_xor(pl, off);
        pr += __shfl_xor(pr, off);
    }
    if ((lane & 15) == 0) {
        el[n * 4 + h] = pl;
        er[n * 4 + h] = pr;
    }
}

// ---------------- CSR build: histogram -> scan -> bucket sort --------------
__global__ __launch_bounds__(256) void k_hist(const int* __restrict__ dst,
                                              int* __restrict__ deg, int E) {
    int base = (blockIdx.x * 256 + threadIdx.x) * 4;
    if (base + 3 < E) {
        int4 d4 = *(const int4*)(dst + base);
        atomicAdd(deg + d4.x, 1);
        atomicAdd(deg + d4.y, 1);
        atomicAdd(deg + d4.z, 1);
        atomicAdd(deg + d4.w, 1);
    } else {
        for (int i = base; i < E; ++i) atomicAdd(deg + dst[i], 1);
    }
}

__global__ __launch_bounds__(256) void k_scan_a(const int* __restrict__ deg,
                                                int* __restrict__ excl,
                                                int* __restrict__ csum, int n) {
    __shared__ int s[256];
    int tid = threadIdx.x;
    int idx = blockIdx.x * 1024 + tid * 4;
    int v0 = 0, v1 = 0, v2 = 0, v3 = 0;
    if (idx + 0 < n) v0 = deg[idx + 0];
    if (idx + 1 < n) v1 = deg[idx + 1];
    if (idx + 2 < n) v2 = deg[idx + 2];
    if (idx + 3 < n) v3 = deg[idx + 3];
    int tsum = v0 + v1 + v2 + v3;
    s[tid] = tsum;
    __syncthreads();
    for (int off = 1; off < 256; off <<= 1) {
        int t = (tid >= off) ? s[tid - off] : 0;
        __syncthreads();
        s[tid] += t;
        __syncthreads();
    }
    int texcl = s[tid] - tsum;
    if (tid == 255) csum[blockIdx.x] = s[255];
    if (idx + 0 < n) excl[idx + 0] = texcl;
    if (idx + 1 < n) excl[idx + 1] = texcl + v0;
    if (idx + 2 < n) excl[idx + 2] = texcl + v0 + v1;
    if (idx + 3 < n) excl[idx + 3] = texcl + v0 + v1 + v2;
}

__global__ __launch_bounds__(128) void k_scan_b(int* __restrict__ csum, int nch) {
    __shared__ int s[128];
    int tid = threadIdx.x;
    int v = (tid < nch) ? csum[tid] : 0;
    s[tid] = v;
    __syncthreads();
    for (int off = 1; off < 128; off <<= 1) {
        int t = (tid >= off) ? s[tid - off] : 0;
        __syncthreads();
        s[tid] += t;
        __syncthreads();
    }
    if (tid < nch) csum[tid] = s[tid] - v;   // exclusive
}

__global__ __launch_bounds__(256) void k_scan_c(int* __restrict__ rowptr,
                                                const int* __restrict__ csum,
                                                int* __restrict__ wptr,
                                                int* __restrict__ bukptr, int n, int E) {
    int i = blockIdx.x * 256 + threadIdx.x;
    if (i < n) {
        int v = rowptr[i] + csum[i >> 10];
        rowptr[i] = v;
        wptr[i] = v;
        if ((i & 511) == 0) bukptr[i >> 9] = v;
        if (i == 0) rowptr[n] = E;
    }
}

// Pass A: bucket edges (bucket = dst>>9) into pair buffer, LDS-staged counts.
__global__ __launch_bounds__(256) void k_bucketA(const int* __restrict__ src,
                                                 const int* __restrict__ dst,
                                                 int* __restrict__ bukptr,
                                                 uint2* __restrict__ pair, int E) {
    __shared__ int cnt[NBUK];
    __shared__ int base[NBUK];
    int tid = threadIdx.x;
    if (tid < NBUK) cnt[tid] = 0;
    __syncthreads();
    int b0 = blockIdx.x * 2048;
    int s[8], d[8], off[8];
#pragma unroll
    for (int j = 0; j < 8; ++j) {
        int i = b0 + j * 256 + tid;
        if (i < E) {
            s[j] = src[i];
            d[j] = dst[i];
            off[j] = atomicAdd(&cnt[d[j] >> 9], 1);
        } else {
            d[j] = -1; s[j] = 0; off[j] = 0;
        }
    }
    __syncthreads();
    if (tid < NBUK) base[tid] = atomicAdd(bukptr + tid, cnt[tid]);
    __syncthreads();
#pragma unroll
    for (int j = 0; j < 8; ++j) {
        if (d[j] >= 0) {
            int pos = base[d[j] >> 9] + off[j];
            pair[pos] = make_uint2((unsigned)s[j], (unsigned)d[j]);
        }
    }
}

// Pass B: scatter within bucket windows; XCD-chunked block swizzle.
__global__ __launch_bounds__(256) void k_bucketB(const uint2* __restrict__ pair,
                                                 int* __restrict__ wptr,
                                                 int* __restrict__ csr, int E, int nwg) {
    int orig = blockIdx.x;
    int q = nwg >> 3, r = nwg & 7;
    int xcd = orig & 7, j = orig >> 3;
    int bid = (xcd < r ? xcd * (q + 1) : r * (q + 1) + (xcd - r) * q) + j;
    int b0 = bid * 2048;
#pragma unroll
    for (int jj = 0; jj < 8; ++jj) {
        int i = b0 + jj * 256 + threadIdx.x;
        if (i < E) {
            uint2 p = pair[i];
            int pos = atomicAdd(wptr + (int)p.y, 1);
            csr[pos] = (int)p.x;
        }
    }
}

// ---------------- Aggregation: one wave per node, no atomics ---------------
__global__ __launch_bounds__(256) void k_agg(const int* __restrict__ rowptr,
                                             const int* __restrict__ csr,
                                             const float* __restrict__ el,
                                             const float* __restrict__ er,
                                             const float* __restrict__ feat,
                                             const float* __restrict__ bias,
                                             float* __restrict__ agg) {
    int tid = threadIdx.x;
    int wave = tid >> 6, lane = tid & 63;
    int n = blockIdx.x * 4 + wave;
    if (n >= N_NODES) return;
    int h = lane >> 4;
    float ern = er[(size_t)n * 4 + h];
    int e0 = rowptr[n], e1 = rowptr[n + 1];
    float acc = 0.f, den = 0.f;
    int s_next = (e0 < e1) ? csr[e0] : 0;
    for (int e = e0; e < e1; ++e) {
        int s = s_next;
        if (e + 1 < e1) s_next = csr[e + 1];
        float ev = el[(size_t)s * 4 + h] + ern;
        ev = ev > 0.f ? ev : 0.2f * ev;
        float ez = __expf(ev);
        acc += ez * feat[(size_t)s * 64 + lane];
        den += ez;
    }
    agg[(size_t)n * 64 + lane] = acc / den + bias[lane];
}

// ---------------- Weight prep: f32 -> hi/lo bf16 B-fragments ---------------
// Fragment layout for v_mfma_f32_16x16x32_bf16 B operand (K=32 x N=16 tile):
// lane l, elem i -> k = 8*(l>>4)+i, col = l&15. Tile (ct,ks) stored at
// ((ct*KS+ks)*64 + l)*8. Out-of-range (k>=din || c>=dout) -> 0.
__global__ __launch_bounds__(64) void k_wprep(const float* __restrict__ w1,
                                              const float* __restrict__ w2,
                                              const float* __restrict__ w3,
                                              const float* __restrict__ w4,
                                              const float* __restrict__ w5,
                                              const float* __restrict__ w6,
                                              short* __restrict__ wfh,
                                              short* __restrict__ wfl) {
    const int nblk[6] = {240, 60, 40, 20, 12, 4};      // CT*KS
    const int din_[6] = {640, 180, 150, 128, 80, 64};
    const int dout_[6] = {180, 150, 128, 80, 64, 32};
    const int ks_[6]  = {20, 6, 5, 4, 3, 2};
    const int off_[6] = {0, 122880, 153600, 174080, 184320, 190464};
    const float* wp[6] = {w1, w2, w3, w4, w5, w6};

    int b = blockIdx.x, layer = 0;
    while (layer < 5 && b >= nblk[layer]) { b -= nblk[layer]; ++layer; }
    int KS = ks_[layer];
    int ct = b / KS, ks = b % KS;
    int l = threadIdx.x;
    int c = ct * 16 + (l & 15);
    int k0 = ks * 32 + ((l >> 4) * 8);
    int din = din_[layer], dout = dout_[layer];
    const float* w = wp[layer];
    s16x8 vh, vl;
#pragma unroll
    for (int i = 0; i < 8; ++i) {
        int k = k0 + i;
        float v = (k < din && c < dout) ? w[k * dout + c] : 0.f;
        short hi = f2bf(v);
        float r = v - bf2f(hi);
        vh[i] = hi;
        vl[i] = f2bf(r);
    }
    size_t o = (size_t)off_[layer] + ((size_t)(ct * KS + ks) * 64 + l) * 8;
    *(s16x8*)(wfh + o) = vh;
    *(s16x8*)(wfl + o) = vl;
}

// ---------------- Kernel 4: MFMA MLP, 32 paths/block, split-bf16 -----------
// D += Ah*Wh + Ah*Wl + Al*Wh  (compensated bf16: quantization error ~2^-18)
template <int KS, int CT>
__device__ __forceinline__ void mfma_layer(const short* sh, const short* sl, int sstride,
                                           short* dh, short* dl,
                                           const short* __restrict__ wfh,
                                           const short* __restrict__ wfl,
                                           const float* __restrict__ bias,
                                           int dout, int w, int l) {
    int mtile = w & 1;
    int lrow = mtile * 16 + (l & 15);
    int abase = lrow * sstride + ((l >> 4) * 8);
    int c_lane = l & 15;
    for (int ct = (w >> 1); ct < CT; ct += 4) {
        f32x4 acc = {0.f, 0.f, 0.f, 0.f};
        const s16x8* wph = (const s16x8*)wfh + (size_t)(ct * KS) * 64 + l;
        const s16x8* wpl = (const s16x8*)wfl + (size_t)(ct * KS) * 64 + l;
#pragma unroll 2
        for (int ks = 0; ks < KS; ++ks) {
            s16x8 ah = *(const s16x8*)(sh + abase + ks * 32);
            s16x8 al = *(const s16x8*)(sl + abase + ks * 32);
            s16x8 wh = wph[ks * 64];
            s16x8 wl = wpl[ks * 64];
            acc = __builtin_amdgcn_mfma_f32_16x16x32_bf16(ah, wh, acc, 0, 0, 0);
            acc = __builtin_amdgcn_mfma_f32_16x16x32_bf16(ah, wl, acc, 0, 0, 0);
            acc = __builtin_amdgcn_mfma_f32_16x16x32_bf16(al, wh, acc, 0, 0, 0);
        }
        int c = ct * 16 + c_lane;
        float bb = (c < dout) ? bias[c] : 0.f;
        int row0 = mtile * 16 + ((l >> 4) * 4);
#pragma unroll
        for (int j = 0; j < 4; ++j) {
            float v = acc[j] + bb;
            v = v > 0.f ? v : 0.f;   // relu (pad cols write 0)
            short hi = f2bf(v);
            float r = v - bf2f(hi);
            dh[(row0 + j) * 200 + c] = hi;
            dl[(row0 + j) * 200 + c] = f2bf(r);
        }
    }
}

__global__ __launch_bounds__(512) void k_mlp(const float* __restrict__ agg,
                                             const short* __restrict__ wfh,
                                             const short* __restrict__ wfl,
                                             const float* __restrict__ b1,
                                             const float* __restrict__ b2,
                                             const float* __restrict__ b3,
                                             const float* __restrict__ b4,
                                             const float* __restrict__ b5,
                                             const float* __restrict__ b6,
                                             const float* __restrict__ w7,
                                             const float* __restrict__ b7,
                                             const float* __restrict__ wt,
                                             float* __restrict__ outp) {
    __shared__ __align__(16) short smem[54272];   // 106KB
    __shared__ float wx[32];
    short* g_hi  = smem;           // 32 x 648
    short* g_lo  = smem + 20736;
    short* h0_hi = smem + 41472;   // 32 x 200
    short* h0_lo = smem + 47872;
    short* h1_hi = smem;           // overlays g (dead after L1)
    short* h1_lo = smem + 6400;

    int tid = threadIdx.x;
    int w = tid >> 6, l = tid & 63;
    int p0 = blockIdx.x * 32;

    // ---- stage g tile (32x640) as hi/lo bf16 into LDS ----
    const float4* a4 = (const float4*)(agg + (size_t)p0 * 640);
    for (int i = tid; i < 32 * 160; i += 512) {
        int r = i / 160, c4 = (i % 160) * 4;
        float4 v = (p0 + r < P_PATHS) ? a4[i] : make_float4(0.f, 0.f, 0.f, 0.f);
        float vs[4] = {v.x, v.y, v.z, v.w};
        s16x4 vh, vl;
#pragma unroll
        for (int t = 0; t < 4; ++t) {
            short hi = f2bf(vs[t]);
            vh[t] = hi;
            vl[t] = f2bf(vs[t] - bf2f(hi));
        }
        *(s16x4*)(g_hi + r * 648 + c4) = vh;
        *(s16x4*)(g_lo + r * 648 + c4) = vl;
    }

    // ---- skip linear wx = g . wt (f32 from global, 8 lanes/path) ----
    if (tid < 256) {
        int path = tid >> 3, sub = tid & 7;
        float acc = 0.f;
        if (p0 + path < P_PATHS) {
            const float* gr = agg + (size_t)(p0 + path) * 640;
            for (int k = sub * 4; k < 640; k += 32) {
                float4 gv = *(const float4*)(gr + k);
                float4 wv = *(const float4*)(wt + k);
                acc += gv.x * wv.x + gv.y * wv.y + gv.z * wv.z + gv.w * wv.w;
            }
        }
        acc += __shfl_xor(acc, 1);
        acc += __shfl_xor(acc, 2);
        acc += __shfl_xor(acc, 4);
        if (sub == 0) wx[path] = acc;
    }
    __syncthreads();

    mfma_layer<20, 12>(g_hi, g_lo, 648, h0_hi, h0_lo, wfh + 0,      wfl + 0,      b1, 180, w, l);
    __syncthreads();
    mfma_layer<6, 10>(h0_hi, h0_lo, 200, h1_hi, h1_lo, wfh + 122880, wfl + 122880, b2, 150, w, l);
    __syncthreads();
    mfma_layer<5, 8>(h1_hi, h1_lo, 200, h0_hi, h0_lo, wfh + 153600, wfl + 153600, b3, 128, w, l);
    __syncthreads();
    mfma_layer<4, 5>(h0_hi, h0_lo, 200, h1_hi, h1_lo, wfh + 174080, wfl + 174080, b4, 80, w, l);
    // L5 reads k<96 of h1 but L4 writes cols<80: zero cols [80,96) (avoid NaN*0)
    if (tid < 512) {
        int r = tid >> 4, c = 80 + (tid & 15);
        h1_hi[r * 200 + c] = 0;
        h1_lo[r * 200 + c] = 0;
    }
    __syncthreads();
    mfma_layer<3, 4>(h1_hi, h1_lo, 200, h0_hi, h0_lo, wfh + 184320, wfl + 184320, b5, 64, w, l);
    __syncthreads();
    mfma_layer<2, 2>(h0_hi, h0_lo, 200, h1_hi, h1_lo, wfh + 190464, wfl + 190464, b6, 32, w, l);
    __syncthreads();

    // ---- layer 7 (32->1) + skip ----
    if (tid < 32 && p0 + tid < P_PATHS) {
        float acc = b7[0];
#pragma unroll
        for (int k = 0; k < 32; ++k) {
            float v = bf2f(h1_hi[tid * 200 + k]) + bf2f(h1_lo[tid * 200 + k]);
            acc += v * w7[k];
        }
        outp[p0 + tid] = acc + wx[tid];
    }
}

extern "C" void kernel_launch(void* const* d_in, const int* in_sizes, int n_in,
                              void* d_out, int out_size, void* d_ws, size_t ws_size,
                              hipStream_t stream) {
    const float* x      = (const float*)d_in[0];
    const int*   src    = (const int*)d_in[1];
    const int*   dst    = (const int*)d_in[2];
    const float* fc_w   = (const float*)d_in[3];
    const float* bias   = (const float*)d_in[4];
    const float* attn_l = (const float*)d_in[5];
    const float* attn_r = (const float*)d_in[6];
    const float* w1 = (const float*)d_in[7];  const float* b1 = (const float*)d_in[8];
    const float* w2 = (const float*)d_in[9];  const float* b2 = (const float*)d_in[10];
    const float* w3 = (const float*)d_in[11]; const float* b3 = (const float*)d_in[12];
    const float* w4 = (const float*)d_in[13]; const float* b4 = (const float*)d_in[14];
    const float* w5 = (const float*)d_in[15]; const float* b5 = (const float*)d_in[16];
    const float* w6 = (const float*)d_in[17]; const float* b6 = (const float*)d_in[18];
    const float* w7 = (const float*)d_in[19]; const float* b7 = (const float*)d_in[20];
    const float* wt = (const float*)d_in[21];
    int E = in_sizes[1];

    float* ws     = (float*)d_ws;
    float* feat   = ws;                         // 6,400,000 f (dead after k_agg)
    float* el     = ws + 6400000;               //   400,000 f
    float* er     = ws + 6800000;               //   400,000 f
    float* agg    = ws + 7200000;               // 6,400,000 f
    uint2* pair   = (uint2*)(ws + 7200000);     // aliases agg (dead before k_agg)
    int*   deg    = (int*)(ws + 13600000);      //   100,000 i (reused as wptr)
    int*   rowptr = (int*)(ws + 13700000);      //   100,001 i
    int*   csum   = (int*)(ws + 13800004);      //       128 i
    int*   csr    = (int*)(ws + 13800132);      //         E i
    int*   bukptr = csr + E;                    //       196 i
    // weight fragments overlay feat (written after k_agg, read by k_mlp)
    short* wfh    = (short*)feat;               //   192,512 bf16
    short* wfl    = wfh + 192512;               //   192,512 bf16

    int nwg = (E + 2047) / 2048;

    hipMemsetAsync(deg, 0, (size_t)N_NODES * 4, stream);

    k_feat<<<N_NODES / 4, 256, 0, stream>>>(x, fc_w, attn_l, attn_r, feat, el, er);
    k_hist<<<(E + 1023) / 1024, 256, 0, stream>>>(dst, deg, E);
    k_scan_a<<<NCHUNK, 256, 0, stream>>>(deg, rowptr, csum, N_NODES);
    k_scan_b<<<1, 128, 0, stream>>>(csum, NCHUNK);
    k_scan_c<<<(N_NODES + 255) / 256, 256, 0, stream>>>(rowptr, csum, deg /*wptr*/, bukptr, N_NODES, E);
    k_bucketA<<<nwg, 256, 0, stream>>>(src, dst, bukptr, pair, E);
    k_bucketB<<<nwg, 256, 0, stream>>>(pair, deg /*wptr*/, csr, E, nwg);
    k_agg<<<N_NODES / 4, 256, 0, stream>>>(rowptr, csr, el, er, feat, bias, agg);
    k_wprep<<<376, 64, 0, stream>>>(w1, w2, w3, w4, w5, w6, wfh, wfl);
    k_mlp<<<(P_PATHS + 31) / 32, 512, 0, stream>>>(agg, wfh, wfl, b1, b2, b3, b4, b5, b6,
                                                   w7, b7, wt, (float*)d_out);
}

// Round 7
// 428.392 us; speedup vs baseline: 2.5070x; 1.0340x over previous
//
#include <hip/hip_runtime.h>
#include <hip/hip_bf16.h>
#include <hip/hip_fp16.h>

#define N_NODES 100000
#define P_PATHS 10000
#define NCHUNK 98   // ceil(100000/1024)
#define NBUK 196    // ceil(100000/512)

typedef __attribute__((ext_vector_type(8))) short s16x8;
typedef __attribute__((ext_vector_type(4))) short s16x4;
typedef __attribute__((ext_vector_type(4))) float f32x4;

__device__ __forceinline__ short f2bf(float v) {
    return __builtin_bit_cast(short, __float2bfloat16(v));
}
__device__ __forceinline__ float bf2f(short s) {
    return __bfloat162float(__builtin_bit_cast(__hip_bfloat16, s));
}

// ---------------- Kernel 1: feat = x@fc_w (fp16 out), el/er scores ---------
__global__ __launch_bounds__(256) void k_feat(const float* __restrict__ x,
                                              const float* __restrict__ fc_w,
                                              const float* __restrict__ attn_l,
                                              const float* __restrict__ attn_r,
                                              __half* __restrict__ feat,
                                              float* __restrict__ el,
                                              float* __restrict__ er) {
    __shared__ float s_w[64 * 64];
    __shared__ float s_al[64], s_ar[64];
    int tid = threadIdx.x;
    for (int i = tid; i < 64 * 64; i += 256) s_w[i] = fc_w[i];
    if (tid < 64) { s_al[tid] = attn_l[tid]; s_ar[tid] = attn_r[tid]; }
    __syncthreads();
    int wave = tid >> 6, lane = tid & 63;
    int n = blockIdx.x * 4 + wave;
    if (n >= N_NODES) return;
    float xv = x[n * 64 + lane];
    float acc = 0.f;
#pragma unroll
    for (int k = 0; k < 64; ++k) {
        acc += __shfl(xv, k) * s_w[k * 64 + lane];
    }
    feat[n * 64 + lane] = __float2half(acc);
    int h = lane >> 4;
    float pl = acc * s_al[lane];
    float pr = acc * s_ar[lane];
#pragma unroll
    for (int off = 1; off < 16; off <<= 1) {
        pl += __shfl_xor(pl, off);
        pr += __shfl_xor(pr, off);
    }
    if ((lane & 15) == 0) {
        el[n * 4 + h] = pl;
        er[n * 4 + h] = pr;
    }
}

// ---------------- CSR build: histogram -> scan -> bucket sort --------------
__global__ __launch_bounds__(256) void k_hist(const int* __restrict__ dst,
                                              int* __restrict__ deg, int E) {
    int base = (blockIdx.x * 256 + threadIdx.x) * 4;
    if (base + 3 < E) {
        int4 d4 = *(const int4*)(dst + base);
        atomicAdd(deg + d4.x, 1);
        atomicAdd(deg + d4.y, 1);
        atomicAdd(deg + d4.z, 1);
        atomicAdd(deg + d4.w, 1);
    } else {
        for (int i = base; i < E; ++i) atomicAdd(deg + dst[i], 1);
    }
}

__global__ __launch_bounds__(256) void k_scan_a(const int* __restrict__ deg,
                                                int* __restrict__ excl,
                                                int* __restrict__ csum, int n) {
    __shared__ int s[256];
    int tid = threadIdx.x;
    int idx = blockIdx.x * 1024 + tid * 4;
    int v0 = 0, v1 = 0, v2 = 0, v3 = 0;
    if (idx + 0 < n) v0 = deg[idx + 0];
    if (idx + 1 < n) v1 = deg[idx + 1];
    if (idx + 2 < n) v2 = deg[idx + 2];
    if (idx + 3 < n) v3 = deg[idx + 3];
    int tsum = v0 + v1 + v2 + v3;
    s[tid] = tsum;
    __syncthreads();
    for (int off = 1; off < 256; off <<= 1) {
        int t = (tid >= off) ? s[tid - off] : 0;
        __syncthreads();
        s[tid] += t;
        __syncthreads();
    }
    int texcl = s[tid] - tsum;
    if (tid == 255) csum[blockIdx.x] = s[255];
    if (idx + 0 < n) excl[idx + 0] = texcl;
    if (idx + 1 < n) excl[idx + 1] = texcl + v0;
    if (idx + 2 < n) excl[idx + 2] = texcl + v0 + v1;
    if (idx + 3 < n) excl[idx + 3] = texcl + v0 + v1 + v2;
}

__global__ __launch_bounds__(128) void k_scan_b(int* __restrict__ csum, int nch) {
    __shared__ int s[128];
    int tid = threadIdx.x;
    int v = (tid < nch) ? csum[tid] : 0;
    s[tid] = v;
    __syncthreads();
    for (int off = 1; off < 128; off <<= 1) {
        int t = (tid >= off) ? s[tid - off] : 0;
        __syncthreads();
        s[tid] += t;
        __syncthreads();
    }
    if (tid < nch) csum[tid] = s[tid] - v;   // exclusive
}

__global__ __launch_bounds__(256) void k_scan_c(int* __restrict__ rowptr,
                                                const int* __restrict__ csum,
                                                int* __restrict__ wptr,
                                                int* __restrict__ bukptr, int n, int E) {
    int i = blockIdx.x * 256 + threadIdx.x;
    if (i < n) {
        int v = rowptr[i] + csum[i >> 10];
        rowptr[i] = v;
        wptr[i] = v;
        if ((i & 511) == 0) bukptr[i >> 9] = v;
        if (i == 0) rowptr[n] = E;
    }
}

// Pass A: bucket edges (bucket = dst>>9) into pair buffer, LDS-staged counts.
__global__ __launch_bounds__(256) void k_bucketA(const int* __restrict__ src,
                                                 const int* __restrict__ dst,
                                                 int* __restrict__ bukptr,
                                                 uint2* __restrict__ pair, int E) {
    __shared__ int cnt[NBUK];
    __shared__ int base[NBUK];
    int tid = threadIdx.x;
    if (tid < NBUK) cnt[tid] = 0;
    __syncthreads();
    int b0 = blockIdx.x * 2048;
    int s[8], d[8], off[8];
#pragma unroll
    for (int j = 0; j < 8; ++j) {
        int i = b0 + j * 256 + tid;
        if (i < E) {
            s[j] = src[i];
            d[j] = dst[i];
            off[j] = atomicAdd(&cnt[d[j] >> 9], 1);
        } else {
            d[j] = -1; s[j] = 0; off[j] = 0;
        }
    }
    __syncthreads();
    if (tid < NBUK) base[tid] = atomicAdd(bukptr + tid, cnt[tid]);
    __syncthreads();
#pragma unroll
    for (int j = 0; j < 8; ++j) {
        if (d[j] >= 0) {
            int pos = base[d[j] >> 9] + off[j];
            pair[pos] = make_uint2((unsigned)s[j], (unsigned)d[j]);
        }
    }
}

// Pass B: scatter within bucket windows; XCD-chunked block swizzle.
__global__ __launch_bounds__(256) void k_bucketB(const uint2* __restrict__ pair,
                                                 int* __restrict__ wptr,
                                                 int* __restrict__ csr, int E, int nwg) {
    int orig = blockIdx.x;
    int q = nwg >> 3, r = nwg & 7;
    int xcd = orig & 7, j = orig >> 3;
    int bid = (xcd < r ? xcd * (q + 1) : r * (q + 1) + (xcd - r) * q) + j;
    int b0 = bid * 2048;
#pragma unroll
    for (int jj = 0; jj < 8; ++jj) {
        int i = b0 + jj * 256 + threadIdx.x;
        if (i < E) {
            uint2 p = pair[i];
            int pos = atomicAdd(wptr + (int)p.y, 1);
            csr[pos] = (int)p.x;
        }
    }
}

// ---------------- Aggregation: one wave per node, fp16 gather, unroll 2 ----
__global__ __launch_bounds__(256) void k_agg(const int* __restrict__ rowptr,
                                             const int* __restrict__ csr,
                                             const float* __restrict__ el,
                                             const float* __restrict__ er,
                                             const __half* __restrict__ feat,
                                             const float* __restrict__ bias,
                                             float* __restrict__ agg) {
    int tid = threadIdx.x;
    int wave = tid >> 6, lane = tid & 63;
    int n = blockIdx.x * 4 + wave;
    if (n >= N_NODES) return;
    int h = lane >> 4;
    float ern = er[(size_t)n * 4 + h];
    int e0 = rowptr[n], e1 = rowptr[n + 1];
    float acc0 = 0.f, den0 = 0.f, acc1 = 0.f, den1 = 0.f;
    int e = e0;
    for (; e + 2 <= e1; e += 2) {
        int s0 = csr[e], s1 = csr[e + 1];
        __half f0 = feat[(size_t)s0 * 64 + lane];
        __half f1 = feat[(size_t)s1 * 64 + lane];
        float ev0 = el[(size_t)s0 * 4 + h] + ern;
        float ev1 = el[(size_t)s1 * 4 + h] + ern;
        ev0 = ev0 > 0.f ? ev0 : 0.2f * ev0;
        ev1 = ev1 > 0.f ? ev1 : 0.2f * ev1;
        float ez0 = __expf(ev0);
        float ez1 = __expf(ev1);
        acc0 += ez0 * __half2float(f0);
        acc1 += ez1 * __half2float(f1);
        den0 += ez0;
        den1 += ez1;
    }
    if (e < e1) {
        int s0 = csr[e];
        __half f0 = feat[(size_t)s0 * 64 + lane];
        float ev0 = el[(size_t)s0 * 4 + h] + ern;
        ev0 = ev0 > 0.f ? ev0 : 0.2f * ev0;
        float ez0 = __expf(ev0);
        acc0 += ez0 * __half2float(f0);
        den0 += ez0;
    }
    agg[(size_t)n * 64 + lane] = (acc0 + acc1) / (den0 + den1) + bias[lane];
}

// ---------------- Weight prep: f32 -> hi/lo bf16 B-fragments ---------------
__global__ __launch_bounds__(64) void k_wprep(const float* __restrict__ w1,
                                              const float* __restrict__ w2,
                                              const float* __restrict__ w3,
                                              const float* __restrict__ w4,
                                              const float* __restrict__ w5,
                                              const float* __restrict__ w6,
                                              short* __restrict__ wfh,
                                              short* __restrict__ wfl) {
    const int nblk[6] = {240, 60, 40, 20, 12, 4};      // CT*KS
    const int din_[6] = {640, 180, 150, 128, 80, 64};
    const int dout_[6] = {180, 150, 128, 80, 64, 32};
    const int ks_[6]  = {20, 6, 5, 4, 3, 2};
    const int off_[6] = {0, 122880, 153600, 174080, 184320, 190464};
    const float* wp[6] = {w1, w2, w3, w4, w5, w6};

    int b = blockIdx.x, layer = 0;
    while (layer < 5 && b >= nblk[layer]) { b -= nblk[layer]; ++layer; }
    int KS = ks_[layer];
    int ct = b / KS, ks = b % KS;
    int l = threadIdx.x;
    int c = ct * 16 + (l & 15);
    int k0 = ks * 32 + ((l >> 4) * 8);
    int din = din_[layer], dout = dout_[layer];
    const float* w = wp[layer];
    s16x8 vh, vl;
#pragma unroll
    for (int i = 0; i < 8; ++i) {
        int k = k0 + i;
        float v = (k < din && c < dout) ? w[k * dout + c] : 0.f;
        short hi = f2bf(v);
        float r = v - bf2f(hi);
        vh[i] = hi;
        vl[i] = f2bf(r);
    }
    size_t o = (size_t)off_[layer] + ((size_t)(ct * KS + ks) * 64 + l) * 8;
    *(s16x8*)(wfh + o) = vh;
    *(s16x8*)(wfl + o) = vl;
}

// ---------------- Kernel 4: MFMA MLP, 32 paths/block, split-bf16 -----------
template <int KS, int CT>
__device__ __forceinline__ void mfma_layer(const short* sh, const short* sl, int sstride,
                                           short* dh, short* dl,
                                           const short* __restrict__ wfh,
                                           const short* __restrict__ wfl,
                                           const float* __restrict__ bias,
                                           int dout, int w, int l) {
    int mtile = w & 1;
    int lrow = mtile * 16 + (l & 15);
    int abase = lrow * sstride + ((l >> 4) * 8);
    int c_lane = l & 15;
    for (int ct = (w >> 1); ct < CT; ct += 4) {
        f32x4 acc = {0.f, 0.f, 0.f, 0.f};
        const s16x8* wph = (const s16x8*)wfh + (size_t)(ct * KS) * 64 + l;
        const s16x8* wpl = (const s16x8*)wfl + (size_t)(ct * KS) * 64 + l;
#pragma unroll 2
        for (int ks = 0; ks < KS; ++ks) {
            s16x8 ah = *(const s16x8*)(sh + abase + ks * 32);
            s16x8 al = *(const s16x8*)(sl + abase + ks * 32);
            s16x8 wh = wph[ks * 64];
            s16x8 wl = wpl[ks * 64];
            acc = __builtin_amdgcn_mfma_f32_16x16x32_bf16(ah, wh, acc, 0, 0, 0);
            acc = __builtin_amdgcn_mfma_f32_16x16x32_bf16(ah, wl, acc, 0, 0, 0);
            acc = __builtin_amdgcn_mfma_f32_16x16x32_bf16(al, wh, acc, 0, 0, 0);
        }
        int c = ct * 16 + c_lane;
        float bb = (c < dout) ? bias[c] : 0.f;
        int row0 = mtile * 16 + ((l >> 4) * 4);
#pragma unroll
        for (int j = 0; j < 4; ++j) {
            float v = acc[j] + bb;
            v = v > 0.f ? v : 0.f;   // relu (pad cols write 0)
            short hi = f2bf(v);
            float r = v - bf2f(hi);
            dh[(row0 + j) * 200 + c] = hi;
            dl[(row0 + j) * 200 + c] = f2bf(r);
        }
    }
}

__global__ __launch_bounds__(512) void k_mlp(const float* __restrict__ agg,
                                             const short* __restrict__ wfh,
                                             const short* __restrict__ wfl,
                                             const float* __restrict__ b1,
                                             const float* __restrict__ b2,
                                             const float* __restrict__ b3,
                                             const float* __restrict__ b4,
                                             const float* __restrict__ b5,
                                             const float* __restrict__ b6,
                                             const float* __restrict__ w7,
                                             const float* __restrict__ b7,
                                             const float* __restrict__ wt,
                                             float* __restrict__ outp) {
    __shared__ __align__(16) short smem[54272];   // 106KB
    __shared__ float wx[32];
    short* g_hi  = smem;           // 32 x 648
    short* g_lo  = smem + 20736;
    short* h0_hi = smem + 41472;   // 32 x 200
    short* h0_lo = smem + 47872;
    short* h1_hi = smem;           // overlays g (dead after L1)
    short* h1_lo = smem + 6400;

    int tid = threadIdx.x;
    int w = tid >> 6, l = tid & 63;
    int p0 = blockIdx.x * 32;

    // ---- stage g tile (32x640) as hi/lo bf16 into LDS ----
    const float4* a4 = (const float4*)(agg + (size_t)p0 * 640);
    for (int i = tid; i < 32 * 160; i += 512) {
        int r = i / 160, c4 = (i % 160) * 4;
        float4 v = (p0 + r < P_PATHS) ? a4[i] : make_float4(0.f, 0.f, 0.f, 0.f);
        float vs[4] = {v.x, v.y, v.z, v.w};
        s16x4 vh, vl;
#pragma unroll
        for (int t = 0; t < 4; ++t) {
            short hi = f2bf(vs[t]);
            vh[t] = hi;
            vl[t] = f2bf(vs[t] - bf2f(hi));
        }
        *(s16x4*)(g_hi + r * 648 + c4) = vh;
        *(s16x4*)(g_lo + r * 648 + c4) = vl;
    }

    // ---- skip linear wx = g . wt (f32 from global, 8 lanes/path) ----
    if (tid < 256) {
        int path = tid >> 3, sub = tid & 7;
        float acc = 0.f;
        if (p0 + path < P_PATHS) {
            const float* gr = agg + (size_t)(p0 + path) * 640;
            for (int k = sub * 4; k < 640; k += 32) {
                float4 gv = *(const float4*)(gr + k);
                float4 wv = *(const float4*)(wt + k);
                acc += gv.x * wv.x + gv.y * wv.y + gv.z * wv.z + gv.w * wv.w;
            }
        }
        acc += __shfl_xor(acc, 1);
        acc += __shfl_xor(acc, 2);
        acc += __shfl_xor(acc, 4);
        if (sub == 0) wx[path] = acc;
    }
    __syncthreads();

    mfma_layer<20, 12>(g_hi, g_lo, 648, h0_hi, h0_lo, wfh + 0,      wfl + 0,      b1, 180, w, l);
    __syncthreads();
    mfma_layer<6, 10>(h0_hi, h0_lo, 200, h1_hi, h1_lo, wfh + 122880, wfl + 122880, b2, 150, w, l);
    __syncthreads();
    mfma_layer<5, 8>(h1_hi, h1_lo, 200, h0_hi, h0_lo, wfh + 153600, wfl + 153600, b3, 128, w, l);
    __syncthreads();
    mfma_layer<4, 5>(h0_hi, h0_lo, 200, h1_hi, h1_lo, wfh + 174080, wfl + 174080, b4, 80, w, l);
    // L5 reads k<96 of h1 but L4 writes cols<80: zero cols [80,96)
    if (tid < 512) {
        int r = tid >> 4, c = 80 + (tid & 15);
        h1_hi[r * 200 + c] = 0;
        h1_lo[r * 200 + c] = 0;
    }
    __syncthreads();
    mfma_layer<3, 4>(h1_hi, h1_lo, 200, h0_hi, h0_lo, wfh + 184320, wfl + 184320, b5, 64, w, l);
    __syncthreads();
    mfma_layer<2, 2>(h0_hi, h0_lo, 200, h1_hi, h1_lo, wfh + 190464, wfl + 190464, b6, 32, w, l);
    __syncthreads();

    // ---- layer 7 (32->1) + skip ----
    if (tid < 32 && p0 + tid < P_PATHS) {
        float acc = b7[0];
#pragma unroll
        for (int k = 0; k < 32; ++k) {
            float v = bf2f(h1_hi[tid * 200 + k]) + bf2f(h1_lo[tid * 200 + k]);
            acc += v * w7[k];
        }
        outp[p0 + tid] = acc + wx[tid];
    }
}

extern "C" void kernel_launch(void* const* d_in, const int* in_sizes, int n_in,
                              void* d_out, int out_size, void* d_ws, size_t ws_size,
                              hipStream_t stream) {
    const float* x      = (const float*)d_in[0];
    const int*   src    = (const int*)d_in[1];
    const int*   dst    = (const int*)d_in[2];
    const float* fc_w   = (const float*)d_in[3];
    const float* bias   = (const float*)d_in[4];
    const float* attn_l = (const float*)d_in[5];
    const float* attn_r = (const float*)d_in[6];
    const float* w1 = (const float*)d_in[7];  const float* b1 = (const float*)d_in[8];
    const float* w2 = (const float*)d_in[9];  const float* b2 = (const float*)d_in[10];
    const float* w3 = (const float*)d_in[11]; const float* b3 = (const float*)d_in[12];
    const float* w4 = (const float*)d_in[13]; const float* b4 = (const float*)d_in[14];
    const float* w5 = (const float*)d_in[15]; const float* b5 = (const float*)d_in[16];
    const float* w6 = (const float*)d_in[17]; const float* b6 = (const float*)d_in[18];
    const float* w7 = (const float*)d_in[19]; const float* b7 = (const float*)d_in[20];
    const float* wt = (const float*)d_in[21];
    int E = in_sizes[1];

    float* ws     = (float*)d_ws;
    __half* feat  = (__half*)ws;                // 6,400,000 fp16 (dead after k_agg)
    float* el     = ws + 6400000;               //   400,000 f
    float* er     = ws + 6800000;               //   400,000 f
    float* agg    = ws + 7200000;               // 6,400,000 f
    uint2* pair   = (uint2*)(ws + 7200000);     // aliases agg (dead before k_agg)
    int*   deg    = (int*)(ws + 13600000);      //   100,000 i (reused as wptr)
    int*   rowptr = (int*)(ws + 13700000);      //   100,001 i
    int*   csum   = (int*)(ws + 13800004);      //       128 i
    int*   csr    = (int*)(ws + 13800132);      //         E i
    int*   bukptr = csr + E;                    //       196 i
    // weight fragments overlay feat region (written after k_agg, read by k_mlp)
    short* wfh    = (short*)ws;                 //   192,512 bf16
    short* wfl    = wfh + 192512;               //   192,512 bf16

    int nwg = (E + 2047) / 2048;

    hipMemsetAsync(deg, 0, (size_t)N_NODES * 4, stream);

    k_feat<<<N_NODES / 4, 256, 0, stream>>>(x, fc_w, attn_l, attn_r, feat, el, er);
    k_hist<<<(E + 1023) / 1024, 256, 0, stream>>>(dst, deg, E);
    k_scan_a<<<NCHUNK, 256, 0, stream>>>(deg, rowptr, csum, N_NODES);
    k_scan_b<<<1, 128, 0, stream>>>(csum, NCHUNK);
    k_scan_c<<<(N_NODES + 255) / 256, 256, 0, stream>>>(rowptr, csum, deg /*wptr*/, bukptr, N_NODES, E);
    k_bucketA<<<nwg, 256, 0, stream>>>(src, dst, bukptr, pair, E);
    k_bucketB<<<nwg, 256, 0, stream>>>(pair, deg /*wptr*/, csr, E, nwg);
    k_agg<<<N_NODES / 4, 256, 0, stream>>>(rowptr, csr, el, er, feat, bias, agg);
    k_wprep<<<376, 64, 0, stream>>>(w1, w2, w3, w4, w5, w6, wfh, wfl);
    k_mlp<<<(P_PATHS + 31) / 32, 512, 0, stream>>>(agg, wfh, wfl, b1, b2, b3, b4, b5, b6,
                                                   w7, b7, wt, (float*)d_out);
}

// Round 8
// 336.260 us; speedup vs baseline: 3.1939x; 1.2740x over previous
//
#include <hip/hip_runtime.h>
#include <hip/hip_bf16.h>
#include <hip/hip_fp16.h>

#define N_NODES 100000
#define P_PATHS 10000
#define NCHUNK 98   // ceil(100000/1024)
#define NBUK 196    // ceil(100000/512)

typedef __attribute__((ext_vector_type(8))) short s16x8;
typedef __attribute__((ext_vector_type(4))) short s16x4;
typedef __attribute__((ext_vector_type(4))) float f32x4;

__device__ __forceinline__ short f2bf(float v) {
    return __builtin_bit_cast(short, __float2bfloat16(v));
}
__device__ __forceinline__ float bf2f(short s) {
    return __bfloat162float(__builtin_bit_cast(__hip_bfloat16, s));
}

// ---------------- Kernel 1: feat = x@fc_w via MFMA (split-bf16) ------------
// el/er folded in as a 5th N-tile: el = x@(W.al), er = x@(W.ar).
__global__ __launch_bounds__(256) void k_feat(const float* __restrict__ x,
                                              const float* __restrict__ fc_w,
                                              const float* __restrict__ attn_l,
                                              const float* __restrict__ attn_r,
                                              __half* __restrict__ feat,
                                              float* __restrict__ el,
                                              float* __restrict__ er) {
    __shared__ float s_w[64 * 64];
    __shared__ float s_wx[64 * 16];   // cols 0..3: W.al (head), 4..7: W.ar, 8..15: 0
    int tid = threadIdx.x;
    for (int i = tid; i < 4096; i += 256) s_w[i] = fc_w[i];
    __syncthreads();
    for (int i = tid; i < 1024; i += 256) {
        int k = i >> 4, c = i & 15;
        float v = 0.f;
        if (c < 8) {
            int h = c & 3;
            const float* av = (c < 4) ? attn_l : attn_r;
            for (int f = 0; f < 16; ++f) v += s_w[k * 64 + h * 16 + f] * av[h * 16 + f];
        }
        s_wx[i] = v;
    }
    __syncthreads();

    int w = tid >> 6, l = tid & 63;
    int c_lane = l & 15, kg = l >> 4;

    // B fragments (hi/lo split), 5 N-tiles x 2 K-steps
    s16x8 wh[5][2], wlo[5][2];
#pragma unroll
    for (int ct = 0; ct < 5; ++ct)
#pragma unroll
        for (int ks = 0; ks < 2; ++ks) {
            s16x8 h8, l8;
#pragma unroll
            for (int i = 0; i < 8; ++i) {
                int k = ks * 32 + kg * 8 + i;
                float v = (ct < 4) ? s_w[k * 64 + ct * 16 + c_lane]
                                   : s_wx[k * 16 + c_lane];
                short hi = f2bf(v);
                h8[i] = hi;
                l8[i] = f2bf(v - bf2f(hi));
            }
            wh[ct][ks] = h8;
            wlo[ct][ks] = l8;
        }

    int nbase = blockIdx.x * 256 + w * 64;
#pragma unroll 1
    for (int mt = 0; mt < 4; ++mt) {
        int m0 = nbase + mt * 16;
        if (m0 >= N_NODES) break;
        int arow = m0 + c_lane;
        size_t axoff = (size_t)(arow < N_NODES ? arow : N_NODES - 1) * 64;
        s16x8 ah[2], alo[2];
#pragma unroll
        for (int ks = 0; ks < 2; ++ks) {
            const float* xp = x + axoff + ks * 32 + kg * 8;
            float4 v0 = *(const float4*)xp;
            float4 v1 = *(const float4*)(xp + 4);
            float vv[8] = {v0.x, v0.y, v0.z, v0.w, v1.x, v1.y, v1.z, v1.w};
            s16x8 h8, l8;
#pragma unroll
            for (int i = 0; i < 8; ++i) {
                short hi = f2bf(vv[i]);
                h8[i] = hi;
                l8[i] = f2bf(vv[i] - bf2f(hi));
            }
            ah[ks] = h8;
            alo[ks] = l8;
        }
        int r0 = m0 + kg * 4;
#pragma unroll
        for (int ct = 0; ct < 5; ++ct) {
            f32x4 acc = {0.f, 0.f, 0.f, 0.f};
#pragma unroll
            for (int ks = 0; ks < 2; ++ks) {
                acc = __builtin_amdgcn_mfma_f32_16x16x32_bf16(ah[ks], wh[ct][ks], acc, 0, 0, 0);
                acc = __builtin_amdgcn_mfma_f32_16x16x32_bf16(ah[ks], wlo[ct][ks], acc, 0, 0, 0);
                acc = __builtin_amdgcn_mfma_f32_16x16x32_bf16(alo[ks], wh[ct][ks], acc, 0, 0, 0);
            }
            if (ct < 4) {
#pragma unroll
                for (int j = 0; j < 4; ++j) {
                    int r = r0 + j;
                    if (r < N_NODES)
                        feat[(size_t)r * 64 + ct * 16 + c_lane] = __float2half(acc[j]);
                }
            } else {
                if (c_lane < 4) {
#pragma unroll
                    for (int j = 0; j < 4; ++j) {
                        int r = r0 + j;
                        if (r < N_NODES) el[r * 4 + c_lane] = acc[j];
                    }
                } else if (c_lane < 8) {
#pragma unroll
                    for (int j = 0; j < 4; ++j) {
                        int r = r0 + j;
                        if (r < N_NODES) er[r * 4 + (c_lane - 4)] = acc[j];
                    }
                }
            }
        }
    }
}

// ---------------- CSR build: histogram -> scan -> bucket sort --------------
__global__ __launch_bounds__(256) void k_hist(const int* __restrict__ dst,
                                              int* __restrict__ deg, int E) {
    int base = (blockIdx.x * 256 + threadIdx.x) * 4;
    if (base + 3 < E) {
        int4 d4 = *(const int4*)(dst + base);
        atomicAdd(deg + d4.x, 1);
        atomicAdd(deg + d4.y, 1);
        atomicAdd(deg + d4.z, 1);
        atomicAdd(deg + d4.w, 1);
    } else {
        for (int i = base; i < E; ++i) atomicAdd(deg + dst[i], 1);
    }
}

__global__ __launch_bounds__(256) void k_scan_a(const int* __restrict__ deg,
                                                int* __restrict__ excl,
                                                int* __restrict__ csum, int n) {
    __shared__ int s[256];
    int tid = threadIdx.x;
    int idx = blockIdx.x * 1024 + tid * 4;
    int v0 = 0, v1 = 0, v2 = 0, v3 = 0;
    if (idx + 0 < n) v0 = deg[idx + 0];
    if (idx + 1 < n) v1 = deg[idx + 1];
    if (idx + 2 < n) v2 = deg[idx + 2];
    if (idx + 3 < n) v3 = deg[idx + 3];
    int tsum = v0 + v1 + v2 + v3;
    s[tid] = tsum;
    __syncthreads();
    for (int off = 1; off < 256; off <<= 1) {
        int t = (tid >= off) ? s[tid - off] : 0;
        __syncthreads();
        s[tid] += t;
        __syncthreads();
    }
    int texcl = s[tid] - tsum;
    if (tid == 255) csum[blockIdx.x] = s[255];
    if (idx + 0 < n) excl[idx + 0] = texcl;
    if (idx + 1 < n) excl[idx + 1] = texcl + v0;
    if (idx + 2 < n) excl[idx + 2] = texcl + v0 + v1;
    if (idx + 3 < n) excl[idx + 3] = texcl + v0 + v1 + v2;
}

__global__ __launch_bounds__(128) void k_scan_b(int* __restrict__ csum, int nch) {
    __shared__ int s[128];
    int tid = threadIdx.x;
    int v = (tid < nch) ? csum[tid] : 0;
    s[tid] = v;
    __syncthreads();
    for (int off = 1; off < 128; off <<= 1) {
        int t = (tid >= off) ? s[tid - off] : 0;
        __syncthreads();
        s[tid] += t;
        __syncthreads();
    }
    if (tid < nch) csum[tid] = s[tid] - v;   // exclusive
}

__global__ __launch_bounds__(256) void k_scan_c(int* __restrict__ rowptr,
                                                const int* __restrict__ csum,
                                                int* __restrict__ wptr,
                                                int* __restrict__ bukptr, int n, int E) {
    int i = blockIdx.x * 256 + threadIdx.x;
    if (i < n) {
        int v = rowptr[i] + csum[i >> 10];
        rowptr[i] = v;
        wptr[i] = v;
        if ((i & 511) == 0) bukptr[i >> 9] = v;
        if (i == 0) rowptr[n] = E;
    }
}

// Pass A: bucket edges (bucket = dst>>9) into pair buffer, LDS-staged counts.
__global__ __launch_bounds__(256) void k_bucketA(const int* __restrict__ src,
                                                 const int* __restrict__ dst,
                                                 int* __restrict__ bukptr,
                                                 uint2* __restrict__ pair, int E) {
    __shared__ int cnt[NBUK];
    __shared__ int base[NBUK];
    int tid = threadIdx.x;
    if (tid < NBUK) cnt[tid] = 0;
    __syncthreads();
    int b0 = blockIdx.x * 2048;
    int s[8], d[8], off[8];
#pragma unroll
    for (int j = 0; j < 8; ++j) {
        int i = b0 + j * 256 + tid;
        if (i < E) {
            s[j] = src[i];
            d[j] = dst[i];
            off[j] = atomicAdd(&cnt[d[j] >> 9], 1);
        } else {
            d[j] = -1; s[j] = 0; off[j] = 0;
        }
    }
    __syncthreads();
    if (tid < NBUK) base[tid] = atomicAdd(bukptr + tid, cnt[tid]);
    __syncthreads();
#pragma unroll
    for (int j = 0; j < 8; ++j) {
        if (d[j] >= 0) {
            int pos = base[d[j] >> 9] + off[j];
            pair[pos] = make_uint2((unsigned)s[j], (unsigned)d[j]);
        }
    }
}

// Pass B: scatter within bucket windows; XCD-chunked block swizzle.
__global__ __launch_bounds__(256) void k_bucketB(const uint2* __restrict__ pair,
                                                 int* __restrict__ wptr,
                                                 int* __restrict__ csr, int E, int nwg) {
    int orig = blockIdx.x;
    int q = nwg >> 3, r = nwg & 7;
    int xcd = orig & 7, j = orig >> 3;
    int bid = (xcd < r ? xcd * (q + 1) : r * (q + 1) + (xcd - r) * q) + j;
    int b0 = bid * 2048;
#pragma unroll
    for (int jj = 0; jj < 8; ++jj) {
        int i = b0 + jj * 256 + threadIdx.x;
        if (i < E) {
            uint2 p = pair[i];
            int pos = atomicAdd(wptr + (int)p.y, 1);
            csr[pos] = (int)p.x;
        }
    }
}

// ---------------- Aggregation: one wave per node, fp16 gather, unroll 2 ----
__global__ __launch_bounds__(256) void k_agg(const int* __restrict__ rowptr,
                                             const int* __restrict__ csr,
                                             const float* __restrict__ el,
                                             const float* __restrict__ er,
                                             const __half* __restrict__ feat,
                                             const float* __restrict__ bias,
                                             float* __restrict__ agg) {
    int tid = threadIdx.x;
    int wave = tid >> 6, lane = tid & 63;
    int n = blockIdx.x * 4 + wave;
    if (n >= N_NODES) return;
    int h = lane >> 4;
    float ern = er[(size_t)n * 4 + h];
    int e0 = rowptr[n], e1 = rowptr[n + 1];
    float acc0 = 0.f, den0 = 0.f, acc1 = 0.f, den1 = 0.f;
    int e = e0;
    for (; e + 2 <= e1; e += 2) {
        int s0 = csr[e], s1 = csr[e + 1];
        __half f0 = feat[(size_t)s0 * 64 + lane];
        __half f1 = feat[(size_t)s1 * 64 + lane];
        float ev0 = el[(size_t)s0 * 4 + h] + ern;
        float ev1 = el[(size_t)s1 * 4 + h] + ern;
        ev0 = ev0 > 0.f ? ev0 : 0.2f * ev0;
        ev1 = ev1 > 0.f ? ev1 : 0.2f * ev1;
        float ez0 = __expf(ev0);
        float ez1 = __expf(ev1);
        acc0 += ez0 * __half2float(f0);
        acc1 += ez1 * __half2float(f1);
        den0 += ez0;
        den1 += ez1;
    }
    if (e < e1) {
        int s0 = csr[e];
        __half f0 = feat[(size_t)s0 * 64 + lane];
        float ev0 = el[(size_t)s0 * 4 + h] + ern;
        ev0 = ev0 > 0.f ? ev0 : 0.2f * ev0;
        float ez0 = __expf(ev0);
        acc0 += ez0 * __half2float(f0);
        den0 += ez0;
    }
    agg[(size_t)n * 64 + lane] = (acc0 + acc1) / (den0 + den1) + bias[lane];
}

// ---------------- Weight prep: f32 -> hi/lo bf16 B-fragments ---------------
__global__ __launch_bounds__(64) void k_wprep(const float* __restrict__ w1,
                                              const float* __restrict__ w2,
                                              const float* __restrict__ w3,
                                              const float* __restrict__ w4,
                                              const float* __restrict__ w5,
                                              const float* __restrict__ w6,
                                              short* __restrict__ wfh,
                                              short* __restrict__ wfl) {
    const int nblk[6] = {240, 60, 40, 20, 12, 4};      // CT*KS
    const int din_[6] = {640, 180, 150, 128, 80, 64};
    const int dout_[6] = {180, 150, 128, 80, 64, 32};
    const int ks_[6]  = {20, 6, 5, 4, 3, 2};
    const int off_[6] = {0, 122880, 153600, 174080, 184320, 190464};
    const float* wp[6] = {w1, w2, w3, w4, w5, w6};

    int b = blockIdx.x, layer = 0;
    while (layer < 5 && b >= nblk[layer]) { b -= nblk[layer]; ++layer; }
    int KS = ks_[layer];
    int ct = b / KS, ks = b % KS;
    int l = threadIdx.x;
    int c = ct * 16 + (l & 15);
    int k0 = ks * 32 + ((l >> 4) * 8);
    int din = din_[layer], dout = dout_[layer];
    const float* w = wp[layer];
    s16x8 vh, vl;
#pragma unroll
    for (int i = 0; i < 8; ++i) {
        int k = k0 + i;
        float v = (k < din && c < dout) ? w[k * dout + c] : 0.f;
        short hi = f2bf(v);
        float r = v - bf2f(hi);
        vh[i] = hi;
        vl[i] = f2bf(r);
    }
    size_t o = (size_t)off_[layer] + ((size_t)(ct * KS + ks) * 64 + l) * 8;
    *(s16x8*)(wfh + o) = vh;
    *(s16x8*)(wfl + o) = vl;
}

// ---------------- Kernel 4: MFMA MLP, 32 paths/block, split-bf16 -----------
template <int KS, int CT>
__device__ __forceinline__ void mfma_layer(const short* sh, const short* sl, int sstride,
                                           short* dh, short* dl,
                                           const short* __restrict__ wfh,
                                           const short* __restrict__ wfl,
                                           const float* __restrict__ bias,
                                           int dout, int w, int l) {
    int mtile = w & 1;
    int lrow = mtile * 16 + (l & 15);
    int abase = lrow * sstride + ((l >> 4) * 8);
    int c_lane = l & 15;
    for (int ct = (w >> 1); ct < CT; ct += 4) {
        f32x4 acc = {0.f, 0.f, 0.f, 0.f};
        const s16x8* wph = (const s16x8*)wfh + (size_t)(ct * KS) * 64 + l;
        const s16x8* wpl = (const s16x8*)wfl + (size_t)(ct * KS) * 64 + l;
#pragma unroll 2
        for (int ks = 0; ks < KS; ++ks) {
            s16x8 ah = *(const s16x8*)(sh + abase + ks * 32);
            s16x8 al = *(const s16x8*)(sl + abase + ks * 32);
            s16x8 wh = wph[ks * 64];
            s16x8 wl = wpl[ks * 64];
            acc = __builtin_amdgcn_mfma_f32_16x16x32_bf16(ah, wh, acc, 0, 0, 0);
            acc = __builtin_amdgcn_mfma_f32_16x16x32_bf16(ah, wl, acc, 0, 0, 0);
            acc = __builtin_amdgcn_mfma_f32_16x16x32_bf16(al, wh, acc, 0, 0, 0);
        }
        int c = ct * 16 + c_lane;
        float bb = (c < dout) ? bias[c] : 0.f;
        int row0 = mtile * 16 + ((l >> 4) * 4);
#pragma unroll
        for (int j = 0; j < 4; ++j) {
            float v = acc[j] + bb;
            v = v > 0.f ? v : 0.f;   // relu (pad cols write 0)
            short hi = f2bf(v);
            float r = v - bf2f(hi);
            dh[(row0 + j) * 200 + c] = hi;
            dl[(row0 + j) * 200 + c] = f2bf(r);
        }
    }
}

__global__ __launch_bounds__(512) void k_mlp(const float* __restrict__ agg,
                                             const short* __restrict__ wfh,
                                             const short* __restrict__ wfl,
                                             const float* __restrict__ b1,
                                             const float* __restrict__ b2,
                                             const float* __restrict__ b3,
                                             const float* __restrict__ b4,
                                             const float* __restrict__ b5,
                                             const float* __restrict__ b6,
                                             const float* __restrict__ w7,
                                             const float* __restrict__ b7,
                                             const float* __restrict__ wt,
                                             float* __restrict__ outp) {
    __shared__ __align__(16) short smem[54272];   // 106KB
    __shared__ float wx[32];
    short* g_hi  = smem;           // 32 x 648
    short* g_lo  = smem + 20736;
    short* h0_hi = smem + 41472;   // 32 x 200
    short* h0_lo = smem + 47872;
    short* h1_hi = smem;           // overlays g (dead after L1)
    short* h1_lo = smem + 6400;

    int tid = threadIdx.x;
    int w = tid >> 6, l = tid & 63;
    int p0 = blockIdx.x * 32;

    // ---- stage g tile (32x640) as hi/lo bf16 into LDS ----
    const float4* a4 = (const float4*)(agg + (size_t)p0 * 640);
    for (int i = tid; i < 32 * 160; i += 512) {
        int r = i / 160, c4 = (i % 160) * 4;
        float4 v = (p0 + r < P_PATHS) ? a4[i] : make_float4(0.f, 0.f, 0.f, 0.f);
        float vs[4] = {v.x, v.y, v.z, v.w};
        s16x4 vh, vl;
#pragma unroll
        for (int t = 0; t < 4; ++t) {
            short hi = f2bf(vs[t]);
            vh[t] = hi;
            vl[t] = f2bf(vs[t] - bf2f(hi));
        }
        *(s16x4*)(g_hi + r * 648 + c4) = vh;
        *(s16x4*)(g_lo + r * 648 + c4) = vl;
    }

    // ---- skip linear wx = g . wt (f32 from global, 8 lanes/path) ----
    if (tid < 256) {
        int path = tid >> 3, sub = tid & 7;
        float acc = 0.f;
        if (p0 + path < P_PATHS) {
            const float* gr = agg + (size_t)(p0 + path) * 640;
            for (int k = sub * 4; k < 640; k += 32) {
                float4 gv = *(const float4*)(gr + k);
                float4 wv = *(const float4*)(wt + k);
                acc += gv.x * wv.x + gv.y * wv.y + gv.z * wv.z + gv.w * wv.w;
            }
        }
        acc += __shfl_xor(acc, 1);
        acc += __shfl_xor(acc, 2);
        acc += __shfl_xor(acc, 4);
        if (sub == 0) wx[path] = acc;
    }
    __syncthreads();

    mfma_layer<20, 12>(g_hi, g_lo, 648, h0_hi, h0_lo, wfh + 0,      wfl + 0,      b1, 180, w, l);
    __syncthreads();
    mfma_layer<6, 10>(h0_hi, h0_lo, 200, h1_hi, h1_lo, wfh + 122880, wfl + 122880, b2, 150, w, l);
    __syncthreads();
    mfma_layer<5, 8>(h1_hi, h1_lo, 200, h0_hi, h0_lo, wfh + 153600, wfl + 153600, b3, 128, w, l);
    __syncthreads();
    mfma_layer<4, 5>(h0_hi, h0_lo, 200, h1_hi, h1_lo, wfh + 174080, wfl + 174080, b4, 80, w, l);
    // L5 reads k<96 of h1 but L4 writes cols<80: zero cols [80,96)
    if (tid < 512) {
        int r = tid >> 4, c = 80 + (tid & 15);
        h1_hi[r * 200 + c] = 0;
        h1_lo[r * 200 + c] = 0;
    }
    __syncthreads();
    mfma_layer<3, 4>(h1_hi, h1_lo, 200, h0_hi, h0_lo, wfh + 184320, wfl + 184320, b5, 64, w, l);
    __syncthreads();
    mfma_layer<2, 2>(h0_hi, h0_lo, 200, h1_hi, h1_lo, wfh + 190464, wfl + 190464, b6, 32, w, l);
    __syncthreads();

    // ---- layer 7 (32->1) + skip ----
    if (tid < 32 && p0 + tid < P_PATHS) {
        float acc = b7[0];
#pragma unroll
        for (int k = 0; k < 32; ++k) {
            float v = bf2f(h1_hi[tid * 200 + k]) + bf2f(h1_lo[tid * 200 + k]);
            acc += v * w7[k];
        }
        outp[p0 + tid] = acc + wx[tid];
    }
}

extern "C" void kernel_launch(void* const* d_in, const int* in_sizes, int n_in,
                              void* d_out, int out_size, void* d_ws, size_t ws_size,
                              hipStream_t stream) {
    const float* x      = (const float*)d_in[0];
    const int*   src    = (const int*)d_in[1];
    const int*   dst    = (const int*)d_in[2];
    const float* fc_w   = (const float*)d_in[3];
    const float* bias   = (const float*)d_in[4];
    const float* attn_l = (const float*)d_in[5];
    const float* attn_r = (const float*)d_in[6];
    const float* w1 = (const float*)d_in[7];  const float* b1 = (const float*)d_in[8];
    const float* w2 = (const float*)d_in[9];  const float* b2 = (const float*)d_in[10];
    const float* w3 = (const float*)d_in[11]; const float* b3 = (const float*)d_in[12];
    const float* w4 = (const float*)d_in[13]; const float* b4 = (const float*)d_in[14];
    const float* w5 = (const float*)d_in[15]; const float* b5 = (const float*)d_in[16];
    const float* w6 = (const float*)d_in[17]; const float* b6 = (const float*)d_in[18];
    const float* w7 = (const float*)d_in[19]; const float* b7 = (const float*)d_in[20];
    const float* wt = (const float*)d_in[21];
    int E = in_sizes[1];

    float* ws     = (float*)d_ws;
    __half* feat  = (__half*)ws;                // 6,400,000 fp16 (dead after k_agg)
    float* el     = ws + 6400000;               //   400,000 f
    float* er     = ws + 6800000;               //   400,000 f
    float* agg    = ws + 7200000;               // 6,400,000 f
    uint2* pair   = (uint2*)(ws + 7200000);     // aliases agg (dead before k_agg)
    int*   deg    = (int*)(ws + 13600000);      //   100,000 i (reused as wptr)
    int*   rowptr = (int*)(ws + 13700000);      //   100,001 i
    int*   csum   = (int*)(ws + 13800004);      //       128 i
    int*   csr    = (int*)(ws + 13800132);      //         E i
    int*   bukptr = csr + E;                    //       196 i
    // weight fragments overlay feat region (written after k_agg, read by k_mlp)
    short* wfh    = (short*)ws;                 //   192,512 bf16
    short* wfl    = wfh + 192512;               //   192,512 bf16

    int nwg = (E + 2047) / 2048;

    hipMemsetAsync(deg, 0, (size_t)N_NODES * 4, stream);

    k_feat<<<(N_NODES + 255) / 256, 256, 0, stream>>>(x, fc_w, attn_l, attn_r, feat, el, er);
    k_hist<<<(E + 1023) / 1024, 256, 0, stream>>>(dst, deg, E);
    k_scan_a<<<NCHUNK, 256, 0, stream>>>(deg, rowptr, csum, N_NODES);
    k_scan_b<<<1, 128, 0, stream>>>(csum, NCHUNK);
    k_scan_c<<<(N_NODES + 255) / 256, 256, 0, stream>>>(rowptr, csum, deg /*wptr*/, bukptr, N_NODES, E);
    k_bucketA<<<nwg, 256, 0, stream>>>(src, dst, bukptr, pair, E);
    k_bucketB<<<nwg, 256, 0, stream>>>(pair, deg /*wptr*/, csr, E, nwg);
    k_agg<<<N_NODES / 4, 256, 0, stream>>>(rowptr, csr, el, er, feat, bias, agg);
    k_wprep<<<376, 64, 0, stream>>>(w1, w2, w3, w4, w5, w6, wfh, wfl);
    k_mlp<<<(P_PATHS + 31) / 32, 512, 0, stream>>>(agg, wfh, wfl, b1, b2, b3, b4, b5, b6,
                                                   w7, b7, wt, (float*)d_out);
}

// Round 9
// 302.684 us; speedup vs baseline: 3.5482x; 1.1109x over previous
//
#include <hip/hip_runtime.h>
#include <hip/hip_bf16.h>
#include <hip/hip_fp16.h>

#define N_NODES 100000
#define P_PATHS 10000
#define NCHUNK 98   // ceil(100000/1024)
#define NBUK 196    // ceil(100000/512)

typedef __attribute__((ext_vector_type(8))) short s16x8;
typedef __attribute__((ext_vector_type(4))) short s16x4;
typedef __attribute__((ext_vector_type(4))) float f32x4;

__device__ __forceinline__ short f2bf(float v) {
    return __builtin_bit_cast(short, __float2bfloat16(v));
}
__device__ __forceinline__ float bf2f(short s) {
    return __bfloat162float(__builtin_bit_cast(__hip_bfloat16, s));
}

// ---------------- Kernel 1: feat = x@fc_w via MFMA (split-bf16) ------------
// el/er folded in as a 5th N-tile: el = x@(W.al), er = x@(W.ar).
__global__ __launch_bounds__(256) void k_feat(const float* __restrict__ x,
                                              const float* __restrict__ fc_w,
                                              const float* __restrict__ attn_l,
                                              const float* __restrict__ attn_r,
                                              __half* __restrict__ feat,
                                              float* __restrict__ el,
                                              float* __restrict__ er) {
    __shared__ float s_w[64 * 64];
    __shared__ float s_wx[64 * 16];   // cols 0..3: W.al (head), 4..7: W.ar, 8..15: 0
    int tid = threadIdx.x;
    for (int i = tid; i < 4096; i += 256) s_w[i] = fc_w[i];
    __syncthreads();
    for (int i = tid; i < 1024; i += 256) {
        int k = i >> 4, c = i & 15;
        float v = 0.f;
        if (c < 8) {
            int h = c & 3;
            const float* av = (c < 4) ? attn_l : attn_r;
            for (int f = 0; f < 16; ++f) v += s_w[k * 64 + h * 16 + f] * av[h * 16 + f];
        }
        s_wx[i] = v;
    }
    __syncthreads();

    int w = tid >> 6, l = tid & 63;
    int c_lane = l & 15, kg = l >> 4;

    // B fragments (hi/lo split), 5 N-tiles x 2 K-steps
    s16x8 wh[5][2], wlo[5][2];
#pragma unroll
    for (int ct = 0; ct < 5; ++ct)
#pragma unroll
        for (int ks = 0; ks < 2; ++ks) {
            s16x8 h8, l8;
#pragma unroll
            for (int i = 0; i < 8; ++i) {
                int k = ks * 32 + kg * 8 + i;
                float v = (ct < 4) ? s_w[k * 64 + ct * 16 + c_lane]
                                   : s_wx[k * 16 + c_lane];
                short hi = f2bf(v);
                h8[i] = hi;
                l8[i] = f2bf(v - bf2f(hi));
            }
            wh[ct][ks] = h8;
            wlo[ct][ks] = l8;
        }

    int nbase = blockIdx.x * 256 + w * 64;
#pragma unroll 1
    for (int mt = 0; mt < 4; ++mt) {
        int m0 = nbase + mt * 16;
        if (m0 >= N_NODES) break;
        int arow = m0 + c_lane;
        size_t axoff = (size_t)(arow < N_NODES ? arow : N_NODES - 1) * 64;
        s16x8 ah[2], alo[2];
#pragma unroll
        for (int ks = 0; ks < 2; ++ks) {
            const float* xp = x + axoff + ks * 32 + kg * 8;
            float4 v0 = *(const float4*)xp;
            float4 v1 = *(const float4*)(xp + 4);
            float vv[8] = {v0.x, v0.y, v0.z, v0.w, v1.x, v1.y, v1.z, v1.w};
            s16x8 h8, l8;
#pragma unroll
            for (int i = 0; i < 8; ++i) {
                short hi = f2bf(vv[i]);
                h8[i] = hi;
                l8[i] = f2bf(vv[i] - bf2f(hi));
            }
            ah[ks] = h8;
            alo[ks] = l8;
        }
        int r0 = m0 + kg * 4;
#pragma unroll
        for (int ct = 0; ct < 5; ++ct) {
            f32x4 acc = {0.f, 0.f, 0.f, 0.f};
#pragma unroll
            for (int ks = 0; ks < 2; ++ks) {
                acc = __builtin_amdgcn_mfma_f32_16x16x32_bf16(ah[ks], wh[ct][ks], acc, 0, 0, 0);
                acc = __builtin_amdgcn_mfma_f32_16x16x32_bf16(ah[ks], wlo[ct][ks], acc, 0, 0, 0);
                acc = __builtin_amdgcn_mfma_f32_16x16x32_bf16(alo[ks], wh[ct][ks], acc, 0, 0, 0);
            }
            if (ct < 4) {
#pragma unroll
                for (int j = 0; j < 4; ++j) {
                    int r = r0 + j;
                    if (r < N_NODES)
                        feat[(size_t)r * 64 + ct * 16 + c_lane] = __float2half(acc[j]);
                }
            } else {
                if (c_lane < 4) {
#pragma unroll
                    for (int j = 0; j < 4; ++j) {
                        int r = r0 + j;
                        if (r < N_NODES) el[r * 4 + c_lane] = acc[j];
                    }
                } else if (c_lane < 8) {
#pragma unroll
                    for (int j = 0; j < 4; ++j) {
                        int r = r0 + j;
                        if (r < N_NODES) er[r * 4 + (c_lane - 4)] = acc[j];
                    }
                }
            }
        }
    }
}

// ---------------- CSR build: histogram -> scan -> bucket sort --------------
__global__ __launch_bounds__(256) void k_hist(const int* __restrict__ dst,
                                              int* __restrict__ deg, int E) {
    int base = (blockIdx.x * 256 + threadIdx.x) * 4;
    if (base + 3 < E) {
        int4 d4 = *(const int4*)(dst + base);
        atomicAdd(deg + d4.x, 1);
        atomicAdd(deg + d4.y, 1);
        atomicAdd(deg + d4.z, 1);
        atomicAdd(deg + d4.w, 1);
    } else {
        for (int i = base; i < E; ++i) atomicAdd(deg + dst[i], 1);
    }
}

__global__ __launch_bounds__(256) void k_scan_a(const int* __restrict__ deg,
                                                int* __restrict__ excl,
                                                int* __restrict__ csum, int n) {
    __shared__ int s[256];
    int tid = threadIdx.x;
    int idx = blockIdx.x * 1024 + tid * 4;
    int v0 = 0, v1 = 0, v2 = 0, v3 = 0;
    if (idx + 0 < n) v0 = deg[idx + 0];
    if (idx + 1 < n) v1 = deg[idx + 1];
    if (idx + 2 < n) v2 = deg[idx + 2];
    if (idx + 3 < n) v3 = deg[idx + 3];
    int tsum = v0 + v1 + v2 + v3;
    s[tid] = tsum;
    __syncthreads();
    for (int off = 1; off < 256; off <<= 1) {
        int t = (tid >= off) ? s[tid - off] : 0;
        __syncthreads();
        s[tid] += t;
        __syncthreads();
    }
    int texcl = s[tid] - tsum;
    if (tid == 255) csum[blockIdx.x] = s[255];
    if (idx + 0 < n) excl[idx + 0] = texcl;
    if (idx + 1 < n) excl[idx + 1] = texcl + v0;
    if (idx + 2 < n) excl[idx + 2] = texcl + v0 + v1;
    if (idx + 3 < n) excl[idx + 3] = texcl + v0 + v1 + v2;
}

__global__ __launch_bounds__(128) void k_scan_b(int* __restrict__ csum, int nch) {
    __shared__ int s[128];
    int tid = threadIdx.x;
    int v = (tid < nch) ? csum[tid] : 0;
    s[tid] = v;
    __syncthreads();
    for (int off = 1; off < 128; off <<= 1) {
        int t = (tid >= off) ? s[tid - off] : 0;
        __syncthreads();
        s[tid] += t;
        __syncthreads();
    }
    if (tid < nch) csum[tid] = s[tid] - v;   // exclusive
}

__global__ __launch_bounds__(256) void k_scan_c(int* __restrict__ rowptr,
                                                const int* __restrict__ csum,
                                                int* __restrict__ wptr,
                                                int* __restrict__ bukptr, int n, int E) {
    int i = blockIdx.x * 256 + threadIdx.x;
    if (i < n) {
        int v = rowptr[i] + csum[i >> 10];
        rowptr[i] = v;
        wptr[i] = v;
        if ((i & 511) == 0) bukptr[i >> 9] = v;
        if (i == 0) rowptr[n] = E;
    }
}

// Pass A: bucket edges (bucket = dst>>9) into pair buffer, LDS-staged counts.
__global__ __launch_bounds__(256) void k_bucketA(const int* __restrict__ src,
                                                 const int* __restrict__ dst,
                                                 int* __restrict__ bukptr,
                                                 uint2* __restrict__ pair, int E) {
    __shared__ int cnt[NBUK];
    __shared__ int base[NBUK];
    int tid = threadIdx.x;
    if (tid < NBUK) cnt[tid] = 0;
    __syncthreads();
    int b0 = blockIdx.x * 2048;
    int s[8], d[8], off[8];
#pragma unroll
    for (int j = 0; j < 8; ++j) {
        int i = b0 + j * 256 + tid;
        if (i < E) {
            s[j] = src[i];
            d[j] = dst[i];
            off[j] = atomicAdd(&cnt[d[j] >> 9], 1);
        } else {
            d[j] = -1; s[j] = 0; off[j] = 0;
        }
    }
    __syncthreads();
    if (tid < NBUK) base[tid] = atomicAdd(bukptr + tid, cnt[tid]);
    __syncthreads();
#pragma unroll
    for (int j = 0; j < 8; ++j) {
        if (d[j] >= 0) {
            int pos = base[d[j] >> 9] + off[j];
            pair[pos] = make_uint2((unsigned)s[j], (unsigned)d[j]);
        }
    }
}

// Pass B: scatter within bucket windows; XCD-chunked block swizzle.
__global__ __launch_bounds__(256) void k_bucketB(const uint2* __restrict__ pair,
                                                 int* __restrict__ wptr,
                                                 int* __restrict__ csr, int E, int nwg) {
    int orig = blockIdx.x;
    int q = nwg >> 3, r = nwg & 7;
    int xcd = orig & 7, j = orig >> 3;
    int bid = (xcd < r ? xcd * (q + 1) : r * (q + 1) + (xcd - r) * q) + j;
    int b0 = bid * 2048;
#pragma unroll
    for (int jj = 0; jj < 8; ++jj) {
        int i = b0 + jj * 256 + threadIdx.x;
        if (i < E) {
            uint2 p = pair[i];
            int pos = atomicAdd(wptr + (int)p.y, 1);
            csr[pos] = (int)p.x;
        }
    }
}

// ---------------- Aggregation: 2 edges/wave (half2 lanes), unroll 2 --------
// Lanes 0..31 process even-offset edges, 32..63 odd-offset; each lane loads a
// half2 (features 2*fl, 2*fl+1). Final __shfl_xor(32) merges the two streams.
__global__ __launch_bounds__(256) void k_agg(const int* __restrict__ rowptr,
                                             const int* __restrict__ csr,
                                             const float* __restrict__ el,
                                             const float* __restrict__ er,
                                             const __half* __restrict__ feat,
                                             const float* __restrict__ bias,
                                             float* __restrict__ agg) {
    int tid = threadIdx.x;
    int wave = tid >> 6, lane = tid & 63;
    int half = lane >> 5;          // which edge of the pair
    int fl = lane & 31;            // feature pair index: features 2fl, 2fl+1
    int n = blockIdx.x * 4 + wave;
    if (n >= N_NODES) return;
    int h = fl >> 3;               // head = (2*fl)>>4
    float ern = er[(size_t)n * 4 + h];
    int e0 = rowptr[n], e1 = rowptr[n + 1];
    float ax0 = 0.f, ay0 = 0.f, den0 = 0.f;
    float ax1 = 0.f, ay1 = 0.f, den1 = 0.f;
    int e = e0 + half;
    for (; e + 2 < e1; e += 4) {
        int s0 = csr[e], s1 = csr[e + 2];
        unsigned v0 = *(const unsigned*)(feat + (size_t)s0 * 64 + fl * 2);
        unsigned v1 = *(const unsigned*)(feat + (size_t)s1 * 64 + fl * 2);
        float ev0 = el[(size_t)s0 * 4 + h] + ern;
        float ev1 = el[(size_t)s1 * 4 + h] + ern;
        ev0 = ev0 > 0.f ? ev0 : 0.2f * ev0;
        ev1 = ev1 > 0.f ? ev1 : 0.2f * ev1;
        float ez0 = __expf(ev0);
        float ez1 = __expf(ev1);
        float2 f0 = __half22float2(__builtin_bit_cast(__half2, v0));
        float2 f1 = __half22float2(__builtin_bit_cast(__half2, v1));
        ax0 += ez0 * f0.x; ay0 += ez0 * f0.y; den0 += ez0;
        ax1 += ez1 * f1.x; ay1 += ez1 * f1.y; den1 += ez1;
    }
    for (; e < e1; e += 2) {
        int s0 = csr[e];
        unsigned v0 = *(const unsigned*)(feat + (size_t)s0 * 64 + fl * 2);
        float ev0 = el[(size_t)s0 * 4 + h] + ern;
        ev0 = ev0 > 0.f ? ev0 : 0.2f * ev0;
        float ez0 = __expf(ev0);
        float2 f0 = __half22float2(__builtin_bit_cast(__half2, v0));
        ax0 += ez0 * f0.x; ay0 += ez0 * f0.y; den0 += ez0;
    }
    float ax = ax0 + ax1, ay = ay0 + ay1, den = den0 + den1;
    ax += __shfl_xor(ax, 32);
    ay += __shfl_xor(ay, 32);
    den += __shfl_xor(den, 32);
    if (half == 0) {
        float2 o;
        o.x = ax / den + bias[fl * 2];
        o.y = ay / den + bias[fl * 2 + 1];
        *(float2*)(agg + (size_t)n * 64 + fl * 2) = o;
    }
}

// ---------------- Weight prep: f32 -> hi/lo bf16 B-fragments ---------------
__global__ __launch_bounds__(64) void k_wprep(const float* __restrict__ w1,
                                              const float* __restrict__ w2,
                                              const float* __restrict__ w3,
                                              const float* __restrict__ w4,
                                              const float* __restrict__ w5,
                                              const float* __restrict__ w6,
                                              short* __restrict__ wfh,
                                              short* __restrict__ wfl) {
    const int nblk[6] = {240, 60, 40, 20, 12, 4};      // CT*KS
    const int din_[6] = {640, 180, 150, 128, 80, 64};
    const int dout_[6] = {180, 150, 128, 80, 64, 32};
    const int ks_[6]  = {20, 6, 5, 4, 3, 2};
    const int off_[6] = {0, 122880, 153600, 174080, 184320, 190464};
    const float* wp[6] = {w1, w2, w3, w4, w5, w6};

    int b = blockIdx.x, layer = 0;
    while (layer < 5 && b >= nblk[layer]) { b -= nblk[layer]; ++layer; }
    int KS = ks_[layer];
    int ct = b / KS, ks = b % KS;
    int l = threadIdx.x;
    int c = ct * 16 + (l & 15);
    int k0 = ks * 32 + ((l >> 4) * 8);
    int din = din_[layer], dout = dout_[layer];
    const float* w = wp[layer];
    s16x8 vh, vl;
#pragma unroll
    for (int i = 0; i < 8; ++i) {
        int k = k0 + i;
        float v = (k < din && c < dout) ? w[k * dout + c] : 0.f;
        short hi = f2bf(v);
        float r = v - bf2f(hi);
        vh[i] = hi;
        vl[i] = f2bf(r);
    }
    size_t o = (size_t)off_[layer] + ((size_t)(ct * KS + ks) * 64 + l) * 8;
    *(s16x8*)(wfh + o) = vh;
    *(s16x8*)(wfl + o) = vl;
}

// ---------------- Kernel 4: MFMA MLP, 32 paths/block, split-bf16 -----------
template <int KS, int CT>
__device__ __forceinline__ void mfma_layer(const short* sh, const short* sl, int sstride,
                                           short* dh, short* dl,
                                           const short* __restrict__ wfh,
                                           const short* __restrict__ wfl,
                                           const float* __restrict__ bias,
                                           int dout, int w, int l) {
    int mtile = w & 1;
    int lrow = mtile * 16 + (l & 15);
    int abase = lrow * sstride + ((l >> 4) * 8);
    int c_lane = l & 15;
    for (int ct = (w >> 1); ct < CT; ct += 4) {
        f32x4 acc = {0.f, 0.f, 0.f, 0.f};
        const s16x8* wph = (const s16x8*)wfh + (size_t)(ct * KS) * 64 + l;
        const s16x8* wpl = (const s16x8*)wfl + (size_t)(ct * KS) * 64 + l;
#pragma unroll 2
        for (int ks = 0; ks < KS; ++ks) {
            s16x8 ah = *(const s16x8*)(sh + abase + ks * 32);
            s16x8 al = *(const s16x8*)(sl + abase + ks * 32);
            s16x8 wh = wph[ks * 64];
            s16x8 wl = wpl[ks * 64];
            acc = __builtin_amdgcn_mfma_f32_16x16x32_bf16(ah, wh, acc, 0, 0, 0);
            acc = __builtin_amdgcn_mfma_f32_16x16x32_bf16(ah, wl, acc, 0, 0, 0);
            acc = __builtin_amdgcn_mfma_f32_16x16x32_bf16(al, wh, acc, 0, 0, 0);
        }
        int c = ct * 16 + c_lane;
        float bb = (c < dout) ? bias[c] : 0.f;
        int row0 = mtile * 16 + ((l >> 4) * 4);
#pragma unroll
        for (int j = 0; j < 4; ++j) {
            float v = acc[j] + bb;
            v = v > 0.f ? v : 0.f;   // relu (pad cols write 0)
            short hi = f2bf(v);
            float r = v - bf2f(hi);
            dh[(row0 + j) * 200 + c] = hi;
            dl[(row0 + j) * 200 + c] = f2bf(r);
        }
    }
}

__global__ __launch_bounds__(512) void k_mlp(const float* __restrict__ agg,
                                             const short* __restrict__ wfh,
                                             const short* __restrict__ wfl,
                                             const float* __restrict__ b1,
                                             const float* __restrict__ b2,
                                             const float* __restrict__ b3,
                                             const float* __restrict__ b4,
                                             const float* __restrict__ b5,
                                             const float* __restrict__ b6,
                                             const float* __restrict__ w7,
                                             const float* __restrict__ b7,
                                             const float* __restrict__ wt,
                                             float* __restrict__ outp) {
    __shared__ __align__(16) short smem[54272];   // 106KB
    __shared__ float wx[32];
    short* g_hi  = smem;           // 32 x 648
    short* g_lo  = smem + 20736;
    short* h0_hi = smem + 41472;   // 32 x 200
    short* h0_lo = smem + 47872;
    short* h1_hi = smem;           // overlays g (dead after L1)
    short* h1_lo = smem + 6400;

    int tid = threadIdx.x;
    int w = tid >> 6, l = tid & 63;
    int p0 = blockIdx.x * 32;

    // ---- stage g tile (32x640) as hi/lo bf16 into LDS ----
    const float4* a4 = (const float4*)(agg + (size_t)p0 * 640);
    for (int i = tid; i < 32 * 160; i += 512) {
        int r = i / 160, c4 = (i % 160) * 4;
        float4 v = (p0 + r < P_PATHS) ? a4[i] : make_float4(0.f, 0.f, 0.f, 0.f);
        float vs[4] = {v.x, v.y, v.z, v.w};
        s16x4 vh, vl;
#pragma unroll
        for (int t = 0; t < 4; ++t) {
            short hi = f2bf(vs[t]);
            vh[t] = hi;
            vl[t] = f2bf(vs[t] - bf2f(hi));
        }
        *(s16x4*)(g_hi + r * 648 + c4) = vh;
        *(s16x4*)(g_lo + r * 648 + c4) = vl;
    }

    // ---- skip linear wx = g . wt (f32 from global, 8 lanes/path) ----
    if (tid < 256) {
        int path = tid >> 3, sub = tid & 7;
        float acc = 0.f;
        if (p0 + path < P_PATHS) {
            const float* gr = agg + (size_t)(p0 + path) * 640;
            for (int k = sub * 4; k < 640; k += 32) {
                float4 gv = *(const float4*)(gr + k);
                float4 wv = *(const float4*)(wt + k);
                acc += gv.x * wv.x + gv.y * wv.y + gv.z * wv.z + gv.w * wv.w;
            }
        }
        acc += __shfl_xor(acc, 1);
        acc += __shfl_xor(acc, 2);
        acc += __shfl_xor(acc, 4);
        if (sub == 0) wx[path] = acc;
    }
    __syncthreads();

    mfma_layer<20, 12>(g_hi, g_lo, 648, h0_hi, h0_lo, wfh + 0,      wfl + 0,      b1, 180, w, l);
    __syncthreads();
    mfma_layer<6, 10>(h0_hi, h0_lo, 200, h1_hi, h1_lo, wfh + 122880, wfl + 122880, b2, 150, w, l);
    __syncthreads();
    mfma_layer<5, 8>(h1_hi, h1_lo, 200, h0_hi, h0_lo, wfh + 153600, wfl + 153600, b3, 128, w, l);
    __syncthreads();
    mfma_layer<4, 5>(h0_hi, h0_lo, 200, h1_hi, h1_lo, wfh + 174080, wfl + 174080, b4, 80, w, l);
    // L5 reads k<96 of h1 but L4 writes cols<80: zero cols [80,96)
    if (tid < 512) {
        int r = tid >> 4, c = 80 + (tid & 15);
        h1_hi[r * 200 + c] = 0;
        h1_lo[r * 200 + c] = 0;
    }
    __syncthreads();
    mfma_layer<3, 4>(h1_hi, h1_lo, 200, h0_hi, h0_lo, wfh + 184320, wfl + 184320, b5, 64, w, l);
    __syncthreads();
    mfma_layer<2, 2>(h0_hi, h0_lo, 200, h1_hi, h1_lo, wfh + 190464, wfl + 190464, b6, 32, w, l);
    __syncthreads();

    // ---- layer 7 (32->1) + skip ----
    if (tid < 32 && p0 + tid < P_PATHS) {
        float acc = b7[0];
#pragma unroll
        for (int k = 0; k < 32; ++k) {
            float v = bf2f(h1_hi[tid * 200 + k]) + bf2f(h1_lo[tid * 200 + k]);
            acc += v * w7[k];
        }
        outp[p0 + tid] = acc + wx[tid];
    }
}

extern "C" void kernel_launch(void* const* d_in, const int* in_sizes, int n_in,
                              void* d_out, int out_size, void* d_ws, size_t ws_size,
                              hipStream_t stream) {
    const float* x      = (const float*)d_in[0];
    const int*   src    = (const int*)d_in[1];
    const int*   dst    = (const int*)d_in[2];
    const float* fc_w   = (const float*)d_in[3];
    const float* bias   = (const float*)d_in[4];
    const float* attn_l = (const float*)d_in[5];
    const float* attn_r = (const float*)d_in[6];
    const float* w1 = (const float*)d_in[7];  const float* b1 = (const float*)d_in[8];
    const float* w2 = (const float*)d_in[9];  const float* b2 = (const float*)d_in[10];
    const float* w3 = (const float*)d_in[11]; const float* b3 = (const float*)d_in[12];
    const float* w4 = (const float*)d_in[13]; const float* b4 = (const float*)d_in[14];
    const float* w5 = (const float*)d_in[15]; const float* b5 = (const float*)d_in[16];
    const float* w6 = (const float*)d_in[17]; const float* b6 = (const float*)d_in[18];
    const float* w7 = (const float*)d_in[19]; const float* b7 = (const float*)d_in[20];
    const float* wt = (const float*)d_in[21];
    int E = in_sizes[1];

    float* ws     = (float*)d_ws;
    __half* feat  = (__half*)ws;                // 6,400,000 fp16 (dead after k_agg)
    float* el     = ws + 6400000;               //   400,000 f
    float* er     = ws + 6800000;               //   400,000 f
    float* agg    = ws + 7200000;               // 6,400,000 f
    uint2* pair   = (uint2*)(ws + 7200000);     // aliases agg (dead before k_agg)
    int*   deg    = (int*)(ws + 13600000);      //   100,000 i (reused as wptr)
    int*   rowptr = (int*)(ws + 13700000);      //   100,001 i
    int*   csum   = (int*)(ws + 13800004);      //       128 i
    int*   csr    = (int*)(ws + 13800132);      //         E i
    int*   bukptr = csr + E;                    //       196 i
    // weight fragments overlay feat region (written after k_agg, read by k_mlp)
    short* wfh    = (short*)ws;                 //   192,512 bf16
    short* wfl    = wfh + 192512;               //   192,512 bf16

    int nwg = (E + 2047) / 2048;

    hipMemsetAsync(deg, 0, (size_t)N_NODES * 4, stream);

    k_feat<<<(N_NODES + 255) / 256, 256, 0, stream>>>(x, fc_w, attn_l, attn_r, feat, el, er);
    k_hist<<<(E + 1023) / 1024, 256, 0, stream>>>(dst, deg, E);
    k_scan_a<<<NCHUNK, 256, 0, stream>>>(deg, rowptr, csum, N_NODES);
    k_scan_b<<<1, 128, 0, stream>>>(csum, NCHUNK);
    k_scan_c<<<(N_NODES + 255) / 256, 256, 0, stream>>>(rowptr, csum, deg /*wptr*/, bukptr, N_NODES, E);
    k_bucketA<<<nwg, 256, 0, stream>>>(src, dst, bukptr, pair, E);
    k_bucketB<<<nwg, 256, 0, stream>>>(pair, deg /*wptr*/, csr, E, nwg);
    k_agg<<<N_NODES / 4, 256, 0, stream>>>(rowptr, csr, el, er, feat, bias, agg);
    k_wprep<<<376, 64, 0, stream>>>(w1, w2, w3, w4, w5, w6, wfh, wfl);
    k_mlp<<<(P_PATHS + 31) / 32, 512, 0, stream>>>(agg, wfh, wfl, b1, b2, b3, b4, b5, b6,
                                                   w7, b7, wt, (float*)d_out);
}

// Round 10
// 293.135 us; speedup vs baseline: 3.6638x; 1.0326x over previous
//
#include <hip/hip_runtime.h>
#include <hip/hip_bf16.h>
#include <hip/hip_fp16.h>

#define N_NODES 100000
#define P_PATHS 10000
#define NCHUNK 98   // ceil(100000/1024)
#define NBUK 196    // ceil(100000/512)

typedef __attribute__((ext_vector_type(8))) short s16x8;
typedef __attribute__((ext_vector_type(4))) short s16x4;
typedef __attribute__((ext_vector_type(4))) float f32x4;

__device__ __forceinline__ short f2bf(float v) {
    return __builtin_bit_cast(short, __float2bfloat16(v));
}
__device__ __forceinline__ float bf2f(short s) {
    return __bfloat162float(__builtin_bit_cast(__hip_bfloat16, s));
}

// ---------------- Kernel 1: feat = x@fc_w via MFMA (split-bf16) ------------
// el/er folded in as a 5th N-tile: el = x@(W.al), er = x@(W.ar).
__global__ __launch_bounds__(256) void k_feat(const float* __restrict__ x,
                                              const float* __restrict__ fc_w,
                                              const float* __restrict__ attn_l,
                                              const float* __restrict__ attn_r,
                                              __half* __restrict__ feat,
                                              float* __restrict__ el,
                                              float* __restrict__ er) {
    __shared__ float s_w[64 * 64];
    __shared__ float s_wx[64 * 16];   // cols 0..3: W.al (head), 4..7: W.ar, 8..15: 0
    int tid = threadIdx.x;
    for (int i = tid; i < 4096; i += 256) s_w[i] = fc_w[i];
    __syncthreads();
    for (int i = tid; i < 1024; i += 256) {
        int k = i >> 4, c = i & 15;
        float v = 0.f;
        if (c < 8) {
            int h = c & 3;
            const float* av = (c < 4) ? attn_l : attn_r;
            for (int f = 0; f < 16; ++f) v += s_w[k * 64 + h * 16 + f] * av[h * 16 + f];
        }
        s_wx[i] = v;
    }
    __syncthreads();

    int w = tid >> 6, l = tid & 63;
    int c_lane = l & 15, kg = l >> 4;

    // B fragments (hi/lo split), 5 N-tiles x 2 K-steps
    s16x8 wh[5][2], wlo[5][2];
#pragma unroll
    for (int ct = 0; ct < 5; ++ct)
#pragma unroll
        for (int ks = 0; ks < 2; ++ks) {
            s16x8 h8, l8;
#pragma unroll
            for (int i = 0; i < 8; ++i) {
                int k = ks * 32 + kg * 8 + i;
                float v = (ct < 4) ? s_w[k * 64 + ct * 16 + c_lane]
                                   : s_wx[k * 16 + c_lane];
                short hi = f2bf(v);
                h8[i] = hi;
                l8[i] = f2bf(v - bf2f(hi));
            }
            wh[ct][ks] = h8;
            wlo[ct][ks] = l8;
        }

    int nbase = blockIdx.x * 256 + w * 64;
#pragma unroll 1
    for (int mt = 0; mt < 4; ++mt) {
        int m0 = nbase + mt * 16;
        if (m0 >= N_NODES) break;
        int arow = m0 + c_lane;
        size_t axoff = (size_t)(arow < N_NODES ? arow : N_NODES - 1) * 64;
        s16x8 ah[2], alo[2];
#pragma unroll
        for (int ks = 0; ks < 2; ++ks) {
            const float* xp = x + axoff + ks * 32 + kg * 8;
            float4 v0 = *(const float4*)xp;
            float4 v1 = *(const float4*)(xp + 4);
            float vv[8] = {v0.x, v0.y, v0.z, v0.w, v1.x, v1.y, v1.z, v1.w};
            s16x8 h8, l8;
#pragma unroll
            for (int i = 0; i < 8; ++i) {
                short hi = f2bf(vv[i]);
                h8[i] = hi;
                l8[i] = f2bf(vv[i] - bf2f(hi));
            }
            ah[ks] = h8;
            alo[ks] = l8;
        }
        int r0 = m0 + kg * 4;
#pragma unroll
        for (int ct = 0; ct < 5; ++ct) {
            f32x4 acc = {0.f, 0.f, 0.f, 0.f};
#pragma unroll
            for (int ks = 0; ks < 2; ++ks) {
                acc = __builtin_amdgcn_mfma_f32_16x16x32_bf16(ah[ks], wh[ct][ks], acc, 0, 0, 0);
                acc = __builtin_amdgcn_mfma_f32_16x16x32_bf16(ah[ks], wlo[ct][ks], acc, 0, 0, 0);
                acc = __builtin_amdgcn_mfma_f32_16x16x32_bf16(alo[ks], wh[ct][ks], acc, 0, 0, 0);
            }
            if (ct < 4) {
#pragma unroll
                for (int j = 0; j < 4; ++j) {
                    int r = r0 + j;
                    if (r < N_NODES)
                        feat[(size_t)r * 64 + ct * 16 + c_lane] = __float2half(acc[j]);
                }
            } else {
                if (c_lane < 4) {
#pragma unroll
                    for (int j = 0; j < 4; ++j) {
                        int r = r0 + j;
                        if (r < N_NODES) el[r * 4 + c_lane] = acc[j];
                    }
                } else if (c_lane < 8) {
#pragma unroll
                    for (int j = 0; j < 4; ++j) {
                        int r = r0 + j;
                        if (r < N_NODES) er[r * 4 + (c_lane - 4)] = acc[j];
                    }
                }
            }
        }
    }
}

// ---------------- CSR build: histogram -> scan -> bucket sort --------------
__global__ __launch_bounds__(256) void k_hist(const int* __restrict__ dst,
                                              int* __restrict__ deg, int E) {
    int base = (blockIdx.x * 256 + threadIdx.x) * 4;
    if (base + 3 < E) {
        int4 d4 = *(const int4*)(dst + base);
        atomicAdd(deg + d4.x, 1);
        atomicAdd(deg + d4.y, 1);
        atomicAdd(deg + d4.z, 1);
        atomicAdd(deg + d4.w, 1);
    } else {
        for (int i = base; i < E; ++i) atomicAdd(deg + dst[i], 1);
    }
}

__global__ __launch_bounds__(256) void k_scan_a(const int* __restrict__ deg,
                                                int* __restrict__ excl,
                                                int* __restrict__ csum, int n) {
    __shared__ int s[256];
    int tid = threadIdx.x;
    int idx = blockIdx.x * 1024 + tid * 4;
    int v0 = 0, v1 = 0, v2 = 0, v3 = 0;
    if (idx + 0 < n) v0 = deg[idx + 0];
    if (idx + 1 < n) v1 = deg[idx + 1];
    if (idx + 2 < n) v2 = deg[idx + 2];
    if (idx + 3 < n) v3 = deg[idx + 3];
    int tsum = v0 + v1 + v2 + v3;
    s[tid] = tsum;
    __syncthreads();
    for (int off = 1; off < 256; off <<= 1) {
        int t = (tid >= off) ? s[tid - off] : 0;
        __syncthreads();
        s[tid] += t;
        __syncthreads();
    }
    int texcl = s[tid] - tsum;
    if (tid == 255) csum[blockIdx.x] = s[255];
    if (idx + 0 < n) excl[idx + 0] = texcl;
    if (idx + 1 < n) excl[idx + 1] = texcl + v0;
    if (idx + 2 < n) excl[idx + 2] = texcl + v0 + v1;
    if (idx + 3 < n) excl[idx + 3] = texcl + v0 + v1 + v2;
}

__global__ __launch_bounds__(128) void k_scan_b(int* __restrict__ csum, int nch) {
    __shared__ int s[128];
    int tid = threadIdx.x;
    int v = (tid < nch) ? csum[tid] : 0;
    s[tid] = v;
    __syncthreads();
    for (int off = 1; off < 128; off <<= 1) {
        int t = (tid >= off) ? s[tid - off] : 0;
        __syncthreads();
        s[tid] += t;
        __syncthreads();
    }
    if (tid < nch) csum[tid] = s[tid] - v;   // exclusive
}

__global__ __launch_bounds__(256) void k_scan_c(int* __restrict__ rowptr,
                                                const int* __restrict__ csum,
                                                int* __restrict__ wptr,
                                                int* __restrict__ bukptr, int n, int E) {
    int i = blockIdx.x * 256 + threadIdx.x;
    if (i < n) {
        int v = rowptr[i] + csum[i >> 10];
        rowptr[i] = v;
        wptr[i] = v;
        if ((i & 511) == 0) bukptr[i >> 9] = v;
        if (i == 0) rowptr[n] = E;
    }
}

// Pass A: bucket edges (bucket = dst>>9) into pair buffer, LDS-staged counts.
__global__ __launch_bounds__(256) void k_bucketA(const int* __restrict__ src,
                                                 const int* __restrict__ dst,
                                                 int* __restrict__ bukptr,
                                                 uint2* __restrict__ pair, int E) {
    __shared__ int cnt[NBUK];
    __shared__ int base[NBUK];
    int tid = threadIdx.x;
    if (tid < NBUK) cnt[tid] = 0;
    __syncthreads();
    int b0 = blockIdx.x * 2048;
    int s[8], d[8], off[8];
#pragma unroll
    for (int j = 0; j < 8; ++j) {
        int i = b0 + j * 256 + tid;
        if (i < E) {
            s[j] = src[i];
            d[j] = dst[i];
            off[j] = atomicAdd(&cnt[d[j] >> 9], 1);
        } else {
            d[j] = -1; s[j] = 0; off[j] = 0;
        }
    }
    __syncthreads();
    if (tid < NBUK) base[tid] = atomicAdd(bukptr + tid, cnt[tid]);
    __syncthreads();
#pragma unroll
    for (int j = 0; j < 8; ++j) {
        if (d[j] >= 0) {
            int pos = base[d[j] >> 9] + off[j];
            pair[pos] = make_uint2((unsigned)s[j], (unsigned)d[j]);
        }
    }
}

// Pass B: scatter within bucket windows; XCD-chunked block swizzle.
__global__ __launch_bounds__(256) void k_bucketB(const uint2* __restrict__ pair,
                                                 int* __restrict__ wptr,
                                                 int* __restrict__ csr, int E, int nwg) {
    int orig = blockIdx.x;
    int q = nwg >> 3, r = nwg & 7;
    int xcd = orig & 7, j = orig >> 3;
    int bid = (xcd < r ? xcd * (q + 1) : r * (q + 1) + (xcd - r) * q) + j;
    int b0 = bid * 2048;
#pragma unroll
    for (int jj = 0; jj < 8; ++jj) {
        int i = b0 + jj * 256 + threadIdx.x;
        if (i < E) {
            uint2 p = pair[i];
            int pos = atomicAdd(wptr + (int)p.y, 1);
            csr[pos] = (int)p.x;
        }
    }
}

// ---------------- Aggregation: 4 edges/wave (s16x4 lanes), unroll 2 --------
// 16-lane row segments: lane = 16*slot + fl; lane loads 4 fp16 features
// (4fl..4fl+3) of edge (e0 + slot + 4k). 8 gathers in flight per wave.
// Reduction over slots via __shfl_xor(32), __shfl_xor(16).
__global__ __launch_bounds__(256) void k_agg(const int* __restrict__ rowptr,
                                             const int* __restrict__ csr,
                                             const float* __restrict__ el,
                                             const float* __restrict__ er,
                                             const __half* __restrict__ feat,
                                             const float* __restrict__ bias,
                                             float* __restrict__ agg) {
    int tid = threadIdx.x;
    int wave = tid >> 6, lane = tid & 63;
    int slot = lane >> 4;          // edge slot 0..3
    int fl = lane & 15;            // feature quad: features 4fl..4fl+3
    int n = blockIdx.x * 4 + wave;
    if (n >= N_NODES) return;
    int h = fl >> 2;               // head (16 features per head)
    float ern = er[(size_t)n * 4 + h];
    int e0 = rowptr[n], e1 = rowptr[n + 1];
    f32x4 a0 = {0.f, 0.f, 0.f, 0.f}, a1 = {0.f, 0.f, 0.f, 0.f};
    float den0 = 0.f, den1 = 0.f;
    int e = e0 + slot;
    for (; e + 4 < e1; e += 8) {
        int s0 = csr[e], s1 = csr[e + 4];
        s16x4 v0 = *(const s16x4*)(feat + (size_t)s0 * 64 + fl * 4);
        s16x4 v1 = *(const s16x4*)(feat + (size_t)s1 * 64 + fl * 4);
        float ev0 = el[(size_t)s0 * 4 + h] + ern;
        float ev1 = el[(size_t)s1 * 4 + h] + ern;
        ev0 = ev0 > 0.f ? ev0 : 0.2f * ev0;
        ev1 = ev1 > 0.f ? ev1 : 0.2f * ev1;
        float ez0 = __expf(ev0);
        float ez1 = __expf(ev1);
#pragma unroll
        for (int t = 0; t < 4; ++t) {
            a0[t] += ez0 * __half2float(__builtin_bit_cast(__half, (short)v0[t]));
            a1[t] += ez1 * __half2float(__builtin_bit_cast(__half, (short)v1[t]));
        }
        den0 += ez0;
        den1 += ez1;
    }
    for (; e < e1; e += 4) {
        int s0 = csr[e];
        s16x4 v0 = *(const s16x4*)(feat + (size_t)s0 * 64 + fl * 4);
        float ev0 = el[(size_t)s0 * 4 + h] + ern;
        ev0 = ev0 > 0.f ? ev0 : 0.2f * ev0;
        float ez0 = __expf(ev0);
#pragma unroll
        for (int t = 0; t < 4; ++t)
            a0[t] += ez0 * __half2float(__builtin_bit_cast(__half, (short)v0[t]));
        den0 += ez0;
    }
    f32x4 a;
    float den = den0 + den1;
#pragma unroll
    for (int t = 0; t < 4; ++t) a[t] = a0[t] + a1[t];
#pragma unroll
    for (int t = 0; t < 4; ++t) {
        a[t] += __shfl_xor(a[t], 32);
        a[t] += __shfl_xor(a[t], 16);
    }
    den += __shfl_xor(den, 32);
    den += __shfl_xor(den, 16);
    if (slot == 0) {
        float4 o;
        float inv = 1.f / den;
        o.x = a[0] * inv + bias[fl * 4 + 0];
        o.y = a[1] * inv + bias[fl * 4 + 1];
        o.z = a[2] * inv + bias[fl * 4 + 2];
        o.w = a[3] * inv + bias[fl * 4 + 3];
        *(float4*)(agg + (size_t)n * 64 + fl * 4) = o;
    }
}

// ---------------- Weight prep: f32 -> hi/lo bf16 B-fragments ---------------
__global__ __launch_bounds__(64) void k_wprep(const float* __restrict__ w1,
                                              const float* __restrict__ w2,
                                              const float* __restrict__ w3,
                                              const float* __restrict__ w4,
                                              const float* __restrict__ w5,
                                              const float* __restrict__ w6,
                                              short* __restrict__ wfh,
                                              short* __restrict__ wfl) {
    const int nblk[6] = {240, 60, 40, 20, 12, 4};      // CT*KS
    const int din_[6] = {640, 180, 150, 128, 80, 64};
    const int dout_[6] = {180, 150, 128, 80, 64, 32};
    const int ks_[6]  = {20, 6, 5, 4, 3, 2};
    const int off_[6] = {0, 122880, 153600, 174080, 184320, 190464};
    const float* wp[6] = {w1, w2, w3, w4, w5, w6};

    int b = blockIdx.x, layer = 0;
    while (layer < 5 && b >= nblk[layer]) { b -= nblk[layer]; ++layer; }
    int KS = ks_[layer];
    int ct = b / KS, ks = b % KS;
    int l = threadIdx.x;
    int c = ct * 16 + (l & 15);
    int k0 = ks * 32 + ((l >> 4) * 8);
    int din = din_[layer], dout = dout_[layer];
    const float* w = wp[layer];
    s16x8 vh, vl;
#pragma unroll
    for (int i = 0; i < 8; ++i) {
        int k = k0 + i;
        float v = (k < din && c < dout) ? w[k * dout + c] : 0.f;
        short hi = f2bf(v);
        float r = v - bf2f(hi);
        vh[i] = hi;
        vl[i] = f2bf(r);
    }
    size_t o = (size_t)off_[layer] + ((size_t)(ct * KS + ks) * 64 + l) * 8;
    *(s16x8*)(wfh + o) = vh;
    *(s16x8*)(wfl + o) = vl;
}

// ---------------- Kernel 4: MFMA MLP, 32 paths/block, split-bf16 -----------
template <int KS, int CT>
__device__ __forceinline__ void mfma_layer(const short* sh, const short* sl, int sstride,
                                           short* dh, short* dl,
                                           const short* __restrict__ wfh,
                                           const short* __restrict__ wfl,
                                           const float* __restrict__ bias,
                                           int dout, int w, int l) {
    int mtile = w & 1;
    int lrow = mtile * 16 + (l & 15);
    int abase = lrow * sstride + ((l >> 4) * 8);
    int c_lane = l & 15;
    for (int ct = (w >> 1); ct < CT; ct += 4) {
        f32x4 acc = {0.f, 0.f, 0.f, 0.f};
        const s16x8* wph = (const s16x8*)wfh + (size_t)(ct * KS) * 64 + l;
        const s16x8* wpl = (const s16x8*)wfl + (size_t)(ct * KS) * 64 + l;
#pragma unroll 2
        for (int ks = 0; ks < KS; ++ks) {
            s16x8 ah = *(const s16x8*)(sh + abase + ks * 32);
            s16x8 al = *(const s16x8*)(sl + abase + ks * 32);
            s16x8 wh = wph[ks * 64];
            s16x8 wl = wpl[ks * 64];
            acc = __builtin_amdgcn_mfma_f32_16x16x32_bf16(ah, wh, acc, 0, 0, 0);
            acc = __builtin_amdgcn_mfma_f32_16x16x32_bf16(ah, wl, acc, 0, 0, 0);
            acc = __builtin_amdgcn_mfma_f32_16x16x32_bf16(al, wh, acc, 0, 0, 0);
        }
        int c = ct * 16 + c_lane;
        float bb = (c < dout) ? bias[c] : 0.f;
        int row0 = mtile * 16 + ((l >> 4) * 4);
#pragma unroll
        for (int j = 0; j < 4; ++j) {
            float v = acc[j] + bb;
            v = v > 0.f ? v : 0.f;   // relu (pad cols write 0)
            short hi = f2bf(v);
            float r = v - bf2f(hi);
            dh[(row0 + j) * 200 + c] = hi;
            dl[(row0 + j) * 200 + c] = f2bf(r);
        }
    }
}

__global__ __launch_bounds__(512) void k_mlp(const float* __restrict__ agg,
                                             const short* __restrict__ wfh,
                                             const short* __restrict__ wfl,
                                             const float* __restrict__ b1,
                                             const float* __restrict__ b2,
                                             const float* __restrict__ b3,
                                             const float* __restrict__ b4,
                                             const float* __restrict__ b5,
                                             const float* __restrict__ b6,
                                             const float* __restrict__ w7,
                                             const float* __restrict__ b7,
                                             const float* __restrict__ wt,
                                             float* __restrict__ outp) {
    __shared__ __align__(16) short smem[54272];   // 106KB
    __shared__ float wx[32];
    short* g_hi  = smem;           // 32 x 648
    short* g_lo  = smem + 20736;
    short* h0_hi = smem + 41472;   // 32 x 200
    short* h0_lo = smem + 47872;
    short* h1_hi = smem;           // overlays g (dead after L1)
    short* h1_lo = smem + 6400;

    int tid = threadIdx.x;
    int w = tid >> 6, l = tid & 63;
    int p0 = blockIdx.x * 32;

    // ---- stage g tile (32x640) as hi/lo bf16 into LDS ----
    const float4* a4 = (const float4*)(agg + (size_t)p0 * 640);
    for (int i = tid; i < 32 * 160; i += 512) {
        int r = i / 160, c4 = (i % 160) * 4;
        float4 v = (p0 + r < P_PATHS) ? a4[i] : make_float4(0.f, 0.f, 0.f, 0.f);
        float vs[4] = {v.x, v.y, v.z, v.w};
        s16x4 vh, vl;
#pragma unroll
        for (int t = 0; t < 4; ++t) {
            short hi = f2bf(vs[t]);
            vh[t] = hi;
            vl[t] = f2bf(vs[t] - bf2f(hi));
        }
        *(s16x4*)(g_hi + r * 648 + c4) = vh;
        *(s16x4*)(g_lo + r * 648 + c4) = vl;
    }

    // ---- skip linear wx = g . wt (f32 from global, 8 lanes/path) ----
    if (tid < 256) {
        int path = tid >> 3, sub = tid & 7;
        float acc = 0.f;
        if (p0 + path < P_PATHS) {
            const float* gr = agg + (size_t)(p0 + path) * 640;
            for (int k = sub * 4; k < 640; k += 32) {
                float4 gv = *(const float4*)(gr + k);
                float4 wv = *(const float4*)(wt + k);
                acc += gv.x * wv.x + gv.y * wv.y + gv.z * wv.z + gv.w * wv.w;
            }
        }
        acc += __shfl_xor(acc, 1);
        acc += __shfl_xor(acc, 2);
        acc += __shfl_xor(acc, 4);
        if (sub == 0) wx[path] = acc;
    }
    __syncthreads();

    mfma_layer<20, 12>(g_hi, g_lo, 648, h0_hi, h0_lo, wfh + 0,      wfl + 0,      b1, 180, w, l);
    __syncthreads();
    mfma_layer<6, 10>(h0_hi, h0_lo, 200, h1_hi, h1_lo, wfh + 122880, wfl + 122880, b2, 150, w, l);
    __syncthreads();
    mfma_layer<5, 8>(h1_hi, h1_lo, 200, h0_hi, h0_lo, wfh + 153600, wfl + 153600, b3, 128, w, l);
    __syncthreads();
    mfma_layer<4, 5>(h0_hi, h0_lo, 200, h1_hi, h1_lo, wfh + 174080, wfl + 174080, b4, 80, w, l);
    // L5 reads k<96 of h1 but L4 writes cols<80: zero cols [80,96)
    if (tid < 512) {
        int r = tid >> 4, c = 80 + (tid & 15);
        h1_hi[r * 200 + c] = 0;
        h1_lo[r * 200 + c] = 0;
    }
    __syncthreads();
    mfma_layer<3, 4>(h1_hi, h1_lo, 200, h0_hi, h0_lo, wfh + 184320, wfl + 184320, b5, 64, w, l);
    __syncthreads();
    mfma_layer<2, 2>(h0_hi, h0_lo, 200, h1_hi, h1_lo, wfh + 190464, wfl + 190464, b6, 32, w, l);
    __syncthreads();

    // ---- layer 7 (32->1) + skip ----
    if (tid < 32 && p0 + tid < P_PATHS) {
        float acc = b7[0];
#pragma unroll
        for (int k = 0; k < 32; ++k) {
            float v = bf2f(h1_hi[tid * 200 + k]) + bf2f(h1_lo[tid * 200 + k]);
            acc += v * w7[k];
        }
        outp[p0 + tid] = acc + wx[tid];
    }
}

extern "C" void kernel_launch(void* const* d_in, const int* in_sizes, int n_in,
                              void* d_out, int out_size, void* d_ws, size_t ws_size,
                              hipStream_t stream) {
    const float* x      = (const float*)d_in[0];
    const int*   src    = (const int*)d_in[1];
    const int*   dst    = (const int*)d_in[2];
    const float* fc_w   = (const float*)d_in[3];
    const float* bias   = (const float*)d_in[4];
    const float* attn_l = (const float*)d_in[5];
    const float* attn_r = (const float*)d_in[6];
    const float* w1 = (const float*)d_in[7];  const float* b1 = (const float*)d_in[8];
    const float* w2 = (const float*)d_in[9];  const float* b2 = (const float*)d_in[10];
    const float* w3 = (const float*)d_in[11]; const float* b3 = (const float*)d_in[12];
    const float* w4 = (const float*)d_in[13]; const float* b4 = (const float*)d_in[14];
    const float* w5 = (const float*)d_in[15]; const float* b5 = (const float*)d_in[16];
    const float* w6 = (const float*)d_in[17]; const float* b6 = (const float*)d_in[18];
    const float* w7 = (const float*)d_in[19]; const float* b7 = (const float*)d_in[20];
    const float* wt = (const float*)d_in[21];
    int E = in_sizes[1];

    float* ws     = (float*)d_ws;
    __half* feat  = (__half*)ws;                // 6,400,000 fp16 (dead after k_agg)
    float* el     = ws + 6400000;               //   400,000 f
    float* er     = ws + 6800000;               //   400,000 f
    float* agg    = ws + 7200000;               // 6,400,000 f
    uint2* pair   = (uint2*)(ws + 7200000);     // aliases agg (dead before k_agg)
    int*   deg    = (int*)(ws + 13600000);      //   100,000 i (reused as wptr)
    int*   rowptr = (int*)(ws + 13700000);      //   100,001 i
    int*   csum   = (int*)(ws + 13800004);      //       128 i
    int*   csr    = (int*)(ws + 13800132);      //         E i
    int*   bukptr = csr + E;                    //       196 i
    // weight fragments overlay feat region (written after k_agg, read by k_mlp)
    short* wfh    = (short*)ws;                 //   192,512 bf16
    short* wfl    = wfh + 192512;               //   192,512 bf16

    int nwg = (E + 2047) / 2048;

    hipMemsetAsync(deg, 0, (size_t)N_NODES * 4, stream);

    k_feat<<<(N_NODES + 255) / 256, 256, 0, stream>>>(x, fc_w, attn_l, attn_r, feat, el, er);
    k_hist<<<(E + 1023) / 1024, 256, 0, stream>>>(dst, deg, E);
    k_scan_a<<<NCHUNK, 256, 0, stream>>>(deg, rowptr, csum, N_NODES);
    k_scan_b<<<1, 128, 0, stream>>>(csum, NCHUNK);
    k_scan_c<<<(N_NODES + 255) / 256, 256, 0, stream>>>(rowptr, csum, deg /*wptr*/, bukptr, N_NODES, E);
    k_bucketA<<<nwg, 256, 0, stream>>>(src, dst, bukptr, pair, E);
    k_bucketB<<<nwg, 256, 0, stream>>>(pair, deg /*wptr*/, csr, E, nwg);
    k_agg<<<N_NODES / 4, 256, 0, stream>>>(rowptr, csr, el, er, feat, bias, agg);
    k_wprep<<<376, 64, 0, stream>>>(w1, w2, w3, w4, w5, w6, wfh, wfl);
    k_mlp<<<(P_PATHS + 31) / 32, 512, 0, stream>>>(agg, wfh, wfl, b1, b2, b3, b4, b5, b6,
                                                   w7, b7, wt, (float*)d_out);
}

// Round 11
// 231.670 us; speedup vs baseline: 4.6358x; 1.2653x over previous
//
#include <hip/hip_runtime.h>
#include <hip/hip_bf16.h>
#include <hip/hip_fp16.h>

#define N_NODES 100000
#define P_PATHS 10000
#define NBUK 196    // ceil(100000/512)

typedef __attribute__((ext_vector_type(8))) short s16x8;
typedef __attribute__((ext_vector_type(4))) short s16x4;
typedef __attribute__((ext_vector_type(4))) float f32x4;

__device__ __forceinline__ short f2bf(float v) {
    return __builtin_bit_cast(short, __float2bfloat16(v));
}
__device__ __forceinline__ float bf2f(short s) {
    return __bfloat162float(__builtin_bit_cast(__hip_bfloat16, s));
}

// ---------------- Kernel 1: feat = x@fc_w via MFMA (split-bf16) ------------
// el/er folded in as a 5th N-tile: el = x@(W.al), er = x@(W.ar).
__global__ __launch_bounds__(256) void k_feat(const float* __restrict__ x,
                                              const float* __restrict__ fc_w,
                                              const float* __restrict__ attn_l,
                                              const float* __restrict__ attn_r,
                                              __half* __restrict__ feat,
                                              float* __restrict__ el,
                                              float* __restrict__ er) {
    __shared__ float s_w[64 * 64];
    __shared__ float s_wx[64 * 16];   // cols 0..3: W.al (head), 4..7: W.ar, 8..15: 0
    int tid = threadIdx.x;
    for (int i = tid; i < 4096; i += 256) s_w[i] = fc_w[i];
    __syncthreads();
    for (int i = tid; i < 1024; i += 256) {
        int k = i >> 4, c = i & 15;
        float v = 0.f;
        if (c < 8) {
            int h = c & 3;
            const float* av = (c < 4) ? attn_l : attn_r;
            for (int f = 0; f < 16; ++f) v += s_w[k * 64 + h * 16 + f] * av[h * 16 + f];
        }
        s_wx[i] = v;
    }
    __syncthreads();

    int w = tid >> 6, l = tid & 63;
    int c_lane = l & 15, kg = l >> 4;

    // B fragments (hi/lo split), 5 N-tiles x 2 K-steps
    s16x8 wh[5][2], wlo[5][2];
#pragma unroll
    for (int ct = 0; ct < 5; ++ct)
#pragma unroll
        for (int ks = 0; ks < 2; ++ks) {
            s16x8 h8, l8;
#pragma unroll
            for (int i = 0; i < 8; ++i) {
                int k = ks * 32 + kg * 8 + i;
                float v = (ct < 4) ? s_w[k * 64 + ct * 16 + c_lane]
                                   : s_wx[k * 16 + c_lane];
                short hi = f2bf(v);
                h8[i] = hi;
                l8[i] = f2bf(v - bf2f(hi));
            }
            wh[ct][ks] = h8;
            wlo[ct][ks] = l8;
        }

    int nbase = blockIdx.x * 256 + w * 64;
#pragma unroll 1
    for (int mt = 0; mt < 4; ++mt) {
        int m0 = nbase + mt * 16;
        if (m0 >= N_NODES) break;
        int arow = m0 + c_lane;
        size_t axoff = (size_t)(arow < N_NODES ? arow : N_NODES - 1) * 64;
        s16x8 ah[2], alo[2];
#pragma unroll
        for (int ks = 0; ks < 2; ++ks) {
            const float* xp = x + axoff + ks * 32 + kg * 8;
            float4 v0 = *(const float4*)xp;
            float4 v1 = *(const float4*)(xp + 4);
            float vv[8] = {v0.x, v0.y, v0.z, v0.w, v1.x, v1.y, v1.z, v1.w};
            s16x8 h8, l8;
#pragma unroll
            for (int i = 0; i < 8; ++i) {
                short hi = f2bf(vv[i]);
                h8[i] = hi;
                l8[i] = f2bf(vv[i] - bf2f(hi));
            }
            ah[ks] = h8;
            alo[ks] = l8;
        }
        int r0 = m0 + kg * 4;
#pragma unroll
        for (int ct = 0; ct < 5; ++ct) {
            f32x4 acc = {0.f, 0.f, 0.f, 0.f};
#pragma unroll
            for (int ks = 0; ks < 2; ++ks) {
                acc = __builtin_amdgcn_mfma_f32_16x16x32_bf16(ah[ks], wh[ct][ks], acc, 0, 0, 0);
                acc = __builtin_amdgcn_mfma_f32_16x16x32_bf16(ah[ks], wlo[ct][ks], acc, 0, 0, 0);
                acc = __builtin_amdgcn_mfma_f32_16x16x32_bf16(alo[ks], wh[ct][ks], acc, 0, 0, 0);
            }
            if (ct < 4) {
#pragma unroll
                for (int j = 0; j < 4; ++j) {
                    int r = r0 + j;
                    if (r < N_NODES)
                        feat[(size_t)r * 64 + ct * 16 + c_lane] = __float2half(acc[j]);
                }
            } else {
                if (c_lane < 4) {
#pragma unroll
                    for (int j = 0; j < 4; ++j) {
                        int r = r0 + j;
                        if (r < N_NODES) el[r * 4 + c_lane] = acc[j];
                    }
                } else if (c_lane < 8) {
#pragma unroll
                    for (int j = 0; j < 4; ++j) {
                        int r = r0 + j;
                        if (r < N_NODES) er[r * 4 + (c_lane - 4)] = acc[j];
                    }
                }
            }
        }
    }
}

// ---------------- CSR build: bucket totals -> scan -> pairs -> per-bucket --
__global__ __launch_bounds__(256) void k_histB(const int* __restrict__ dst,
                                               int* __restrict__ buktot, int E) {
    __shared__ int cnt[NBUK];
    int tid = threadIdx.x;
    if (tid < NBUK) cnt[tid] = 0;
    __syncthreads();
    int base = (blockIdx.x * 256 + threadIdx.x) * 4;
    if (base + 3 < E) {
        int4 d4 = *(const int4*)(dst + base);
        atomicAdd(&cnt[d4.x >> 9], 1);
        atomicAdd(&cnt[d4.y >> 9], 1);
        atomicAdd(&cnt[d4.z >> 9], 1);
        atomicAdd(&cnt[d4.w >> 9], 1);
    } else {
        for (int i = base; i < E; ++i) atomicAdd(&cnt[dst[i] >> 9], 1);
    }
    __syncthreads();
    if (tid < NBUK && cnt[tid]) atomicAdd(buktot + tid, cnt[tid]);
}

__global__ __launch_bounds__(256) void k_scan196(const int* __restrict__ buktot,
                                                 int* __restrict__ bukstart,
                                                 int* __restrict__ bukptr,
                                                 int* __restrict__ rowptr, int E) {
    __shared__ int s[256];
    int tid = threadIdx.x;
    int v = (tid < NBUK) ? buktot[tid] : 0;
    s[tid] = v;
    __syncthreads();
    for (int off = 1; off < 256; off <<= 1) {
        int t = (tid >= off) ? s[tid - off] : 0;
        __syncthreads();
        s[tid] += t;
        __syncthreads();
    }
    int excl = s[tid] - v;
    if (tid < NBUK) { bukstart[tid] = excl; bukptr[tid] = excl; }
    if (tid == 0) { bukstart[NBUK] = E; rowptr[N_NODES] = E; }
}

__global__ __launch_bounds__(256) void k_bucketA(const int* __restrict__ src,
                                                 const int* __restrict__ dst,
                                                 int* __restrict__ bukptr,
                                                 uint2* __restrict__ pair, int E) {
    __shared__ int cnt[NBUK];
    __shared__ int base[NBUK];
    int tid = threadIdx.x;
    if (tid < NBUK) cnt[tid] = 0;
    __syncthreads();
    int b0 = blockIdx.x * 2048;
    int s[8], d[8], off[8];
#pragma unroll
    for (int j = 0; j < 8; ++j) {
        int i = b0 + j * 256 + tid;
        if (i < E) {
            s[j] = src[i];
            d[j] = dst[i];
            off[j] = atomicAdd(&cnt[d[j] >> 9], 1);
        } else {
            d[j] = -1; s[j] = 0; off[j] = 0;
        }
    }
    __syncthreads();
    if (tid < NBUK) base[tid] = atomicAdd(bukptr + tid, cnt[tid]);
    __syncthreads();
#pragma unroll
    for (int j = 0; j < 8; ++j) {
        if (d[j] >= 0) {
            int pos = base[d[j] >> 9] + off[j];
            pair[pos] = make_uint2((unsigned)s[j], (unsigned)d[j]);
        }
    }
}

// Per-bucket finalize: LDS histogram + LDS scan -> rowptr; scatter via LDS
// cursors into the bucket's csr window. No per-node global atomics.
__global__ __launch_bounds__(512) void k_bucketC(const uint2* __restrict__ pair,
                                                 const int* __restrict__ bukstart,
                                                 int* __restrict__ rowptr,
                                                 int* __restrict__ csr, int E) {
    __shared__ int cnt[512];
    __shared__ int s[512];
    __shared__ int wofs[512];
    int buk = blockIdx.x, tid = threadIdx.x;
    int p0 = bukstart[buk], p1 = bukstart[buk + 1];
    cnt[tid] = 0;
    __syncthreads();
    for (int i = p0 + tid; i < p1; i += 512)
        atomicAdd(&cnt[pair[i].y & 511], 1);
    __syncthreads();
    int v = cnt[tid];
    s[tid] = v;
    __syncthreads();
    for (int off = 1; off < 512; off <<= 1) {
        int t = (tid >= off) ? s[tid - off] : 0;
        __syncthreads();
        s[tid] += t;
        __syncthreads();
    }
    int r = p0 + s[tid] - v;
    wofs[tid] = r;
    int node = (buk << 9) + tid;
    if (node < N_NODES) rowptr[node] = r;
    __syncthreads();
    for (int i = p0 + tid; i < p1; i += 512) {
        uint2 p = pair[i];
        int pos = atomicAdd(&wofs[(int)p.y & 511], 1);
        csr[pos] = (int)p.x;
    }
}

// ---------------- Aggregation: 4 edges/wave (s16x4 lanes), unroll 2 --------
__global__ __launch_bounds__(256) void k_agg(const int* __restrict__ rowptr,
                                             const int* __restrict__ csr,
                                             const float* __restrict__ el,
                                             const float* __restrict__ er,
                                             const __half* __restrict__ feat,
                                             const float* __restrict__ bias,
                                             float* __restrict__ agg) {
    int tid = threadIdx.x;
    int wave = tid >> 6, lane = tid & 63;
    int slot = lane >> 4;          // edge slot 0..3
    int fl = lane & 15;            // feature quad: features 4fl..4fl+3
    int n = blockIdx.x * 4 + wave;
    if (n >= N_NODES) return;
    int h = fl >> 2;               // head (16 features per head)
    float ern = er[(size_t)n * 4 + h];
    int e0 = rowptr[n], e1 = rowptr[n + 1];
    f32x4 a0 = {0.f, 0.f, 0.f, 0.f}, a1 = {0.f, 0.f, 0.f, 0.f};
    float den0 = 0.f, den1 = 0.f;
    int e = e0 + slot;
    for (; e + 4 < e1; e += 8) {
        int s0 = csr[e], s1 = csr[e + 4];
        s16x4 v0 = *(const s16x4*)(feat + (size_t)s0 * 64 + fl * 4);
        s16x4 v1 = *(const s16x4*)(feat + (size_t)s1 * 64 + fl * 4);
        float ev0 = el[(size_t)s0 * 4 + h] + ern;
        float ev1 = el[(size_t)s1 * 4 + h] + ern;
        ev0 = ev0 > 0.f ? ev0 : 0.2f * ev0;
        ev1 = ev1 > 0.f ? ev1 : 0.2f * ev1;
        float ez0 = __expf(ev0);
        float ez1 = __expf(ev1);
#pragma unroll
        for (int t = 0; t < 4; ++t) {
            a0[t] += ez0 * __half2float(__builtin_bit_cast(__half, (short)v0[t]));
            a1[t] += ez1 * __half2float(__builtin_bit_cast(__half, (short)v1[t]));
        }
        den0 += ez0;
        den1 += ez1;
    }
    for (; e < e1; e += 4) {
        int s0 = csr[e];
        s16x4 v0 = *(const s16x4*)(feat + (size_t)s0 * 64 + fl * 4);
        float ev0 = el[(size_t)s0 * 4 + h] + ern;
        ev0 = ev0 > 0.f ? ev0 : 0.2f * ev0;
        float ez0 = __expf(ev0);
#pragma unroll
        for (int t = 0; t < 4; ++t)
            a0[t] += ez0 * __half2float(__builtin_bit_cast(__half, (short)v0[t]));
        den0 += ez0;
    }
    f32x4 a;
    float den = den0 + den1;
#pragma unroll
    for (int t = 0; t < 4; ++t) a[t] = a0[t] + a1[t];
#pragma unroll
    for (int t = 0; t < 4; ++t) {
        a[t] += __shfl_xor(a[t], 32);
        a[t] += __shfl_xor(a[t], 16);
    }
    den += __shfl_xor(den, 32);
    den += __shfl_xor(den, 16);
    if (slot == 0) {
        float4 o;
        float inv = 1.f / den;
        o.x = a[0] * inv + bias[fl * 4 + 0];
        o.y = a[1] * inv + bias[fl * 4 + 1];
        o.z = a[2] * inv + bias[fl * 4 + 2];
        o.w = a[3] * inv + bias[fl * 4 + 3];
        *(float4*)(agg + (size_t)n * 64 + fl * 4) = o;
    }
}

// ---------------- Weight prep: f32 -> hi/lo bf16 B-fragments ---------------
__global__ __launch_bounds__(64) void k_wprep(const float* __restrict__ w1,
                                              const float* __restrict__ w2,
                                              const float* __restrict__ w3,
                                              const float* __restrict__ w4,
                                              const float* __restrict__ w5,
                                              const float* __restrict__ w6,
                                              short* __restrict__ wfh,
                                              short* __restrict__ wfl) {
    const int nblk[6] = {240, 60, 40, 20, 12, 4};      // CT*KS
    const int din_[6] = {640, 180, 150, 128, 80, 64};
    const int dout_[6] = {180, 150, 128, 80, 64, 32};
    const int ks_[6]  = {20, 6, 5, 4, 3, 2};
    const int off_[6] = {0, 122880, 153600, 174080, 184320, 190464};
    const float* wp[6] = {w1, w2, w3, w4, w5, w6};

    int b = blockIdx.x, layer = 0;
    while (layer < 5 && b >= nblk[layer]) { b -= nblk[layer]; ++layer; }
    int KS = ks_[layer];
    int ct = b / KS, ks = b % KS;
    int l = threadIdx.x;
    int c = ct * 16 + (l & 15);
    int k0 = ks * 32 + ((l >> 4) * 8);
    int din = din_[layer], dout = dout_[layer];
    const float* w = wp[layer];
    s16x8 vh, vl;
#pragma unroll
    for (int i = 0; i < 8; ++i) {
        int k = k0 + i;
        float v = (k < din && c < dout) ? w[k * dout + c] : 0.f;
        short hi = f2bf(v);
        float r = v - bf2f(hi);
        vh[i] = hi;
        vl[i] = f2bf(r);
    }
    size_t o = (size_t)off_[layer] + ((size_t)(ct * KS + ks) * 64 + l) * 8;
    *(s16x8*)(wfh + o) = vh;
    *(s16x8*)(wfl + o) = vl;
}

// ---------------- Kernel 4: MFMA MLP, 32 paths/block, split-bf16 -----------
template <int KS, int CT>
__device__ __forceinline__ void mfma_layer(const short* sh, const short* sl, int sstride,
                                           short* dh, short* dl,
                                           const short* __restrict__ wfh,
                                           const short* __restrict__ wfl,
                                           const float* __restrict__ bias,
                                           int dout, int w, int l) {
    int mtile = w & 1;
    int lrow = mtile * 16 + (l & 15);
    int abase = lrow * sstride + ((l >> 4) * 8);
    int c_lane = l & 15;
    for (int ct = (w >> 1); ct < CT; ct += 4) {
        f32x4 acc = {0.f, 0.f, 0.f, 0.f};
        const s16x8* wph = (const s16x8*)wfh + (size_t)(ct * KS) * 64 + l;
        const s16x8* wpl = (const s16x8*)wfl + (size_t)(ct * KS) * 64 + l;
#pragma unroll 2
        for (int ks = 0; ks < KS; ++ks) {
            s16x8 ah = *(const s16x8*)(sh + abase + ks * 32);
            s16x8 al = *(const s16x8*)(sl + abase + ks * 32);
            s16x8 wh = wph[ks * 64];
            s16x8 wl = wpl[ks * 64];
            acc = __builtin_amdgcn_mfma_f32_16x16x32_bf16(ah, wh, acc, 0, 0, 0);
            acc = __builtin_amdgcn_mfma_f32_16x16x32_bf16(ah, wl, acc, 0, 0, 0);
            acc = __builtin_amdgcn_mfma_f32_16x16x32_bf16(al, wh, acc, 0, 0, 0);
        }
        int c = ct * 16 + c_lane;
        float bb = (c < dout) ? bias[c] : 0.f;
        int row0 = mtile * 16 + ((l >> 4) * 4);
#pragma unroll
        for (int j = 0; j < 4; ++j) {
            float v = acc[j] + bb;
            v = v > 0.f ? v : 0.f;   // relu (pad cols write 0)
            short hi = f2bf(v);
            float r = v - bf2f(hi);
            dh[(row0 + j) * 200 + c] = hi;
            dl[(row0 + j) * 200 + c] = f2bf(r);
        }
    }
}

__global__ __launch_bounds__(512) void k_mlp(const float* __restrict__ agg,
                                             const short* __restrict__ wfh,
                                             const short* __restrict__ wfl,
                                             const float* __restrict__ b1,
                                             const float* __restrict__ b2,
                                             const float* __restrict__ b3,
                                             const float* __restrict__ b4,
                                             const float* __restrict__ b5,
                                             const float* __restrict__ b6,
                                             const float* __restrict__ w7,
                                             const float* __restrict__ b7,
                                             const float* __restrict__ wt,
                                             float* __restrict__ outp) {
    __shared__ __align__(16) short smem[54272];   // 106KB
    __shared__ float wx[32];
    short* g_hi  = smem;           // 32 x 648
    short* g_lo  = smem + 20736;
    short* h0_hi = smem + 41472;   // 32 x 200
    short* h0_lo = smem + 47872;
    short* h1_hi = smem;           // overlays g (dead after L1)
    short* h1_lo = smem + 6400;

    int tid = threadIdx.x;
    int w = tid >> 6, l = tid & 63;
    int p0 = blockIdx.x * 32;

    // ---- stage g tile (32x640) as hi/lo bf16 into LDS ----
    const float4* a4 = (const float4*)(agg + (size_t)p0 * 640);
    for (int i = tid; i < 32 * 160; i += 512) {
        int r = i / 160, c4 = (i % 160) * 4;
        float4 v = (p0 + r < P_PATHS) ? a4[i] : make_float4(0.f, 0.f, 0.f, 0.f);
        float vs[4] = {v.x, v.y, v.z, v.w};
        s16x4 vh, vl;
#pragma unroll
        for (int t = 0; t < 4; ++t) {
            short hi = f2bf(vs[t]);
            vh[t] = hi;
            vl[t] = f2bf(vs[t] - bf2f(hi));
        }
        *(s16x4*)(g_hi + r * 648 + c4) = vh;
        *(s16x4*)(g_lo + r * 648 + c4) = vl;
    }

    // ---- skip linear wx = g . wt (f32 from global, 8 lanes/path) ----
    if (tid < 256) {
        int path = tid >> 3, sub = tid & 7;
        float acc = 0.f;
        if (p0 + path < P_PATHS) {
            const float* gr = agg + (size_t)(p0 + path) * 640;
            for (int k = sub * 4; k < 640; k += 32) {
                float4 gv = *(const float4*)(gr + k);
                float4 wv = *(const float4*)(wt + k);
                acc += gv.x * wv.x + gv.y * wv.y + gv.z * wv.z + gv.w * wv.w;
            }
        }
        acc += __shfl_xor(acc, 1);
        acc += __shfl_xor(acc, 2);
        acc += __shfl_xor(acc, 4);
        if (sub == 0) wx[path] = acc;
    }
    __syncthreads();

    mfma_layer<20, 12>(g_hi, g_lo, 648, h0_hi, h0_lo, wfh + 0,      wfl + 0,      b1, 180, w, l);
    __syncthreads();
    mfma_layer<6, 10>(h0_hi, h0_lo, 200, h1_hi, h1_lo, wfh + 122880, wfl + 122880, b2, 150, w, l);
    __syncthreads();
    mfma_layer<5, 8>(h1_hi, h1_lo, 200, h0_hi, h0_lo, wfh + 153600, wfl + 153600, b3, 128, w, l);
    __syncthreads();
    mfma_layer<4, 5>(h0_hi, h0_lo, 200, h1_hi, h1_lo, wfh + 174080, wfl + 174080, b4, 80, w, l);
    // L5 reads k<96 of h1 but L4 writes cols<80: zero cols [80,96)
    if (tid < 512) {
        int r = tid >> 4, c = 80 + (tid & 15);
        h1_hi[r * 200 + c] = 0;
        h1_lo[r * 200 + c] = 0;
    }
    __syncthreads();
    mfma_layer<3, 4>(h1_hi, h1_lo, 200, h0_hi, h0_lo, wfh + 184320, wfl + 184320, b5, 64, w, l);
    __syncthreads();
    mfma_layer<2, 2>(h0_hi, h0_lo, 200, h1_hi, h1_lo, wfh + 190464, wfl + 190464, b6, 32, w, l);
    __syncthreads();

    // ---- layer 7 (32->1) + skip ----
    if (tid < 32 && p0 + tid < P_PATHS) {
        float acc = b7[0];
#pragma unroll
        for (int k = 0; k < 32; ++k) {
            float v = bf2f(h1_hi[tid * 200 + k]) + bf2f(h1_lo[tid * 200 + k]);
            acc += v * w7[k];
        }
        outp[p0 + tid] = acc + wx[tid];
    }
}

extern "C" void kernel_launch(void* const* d_in, const int* in_sizes, int n_in,
                              void* d_out, int out_size, void* d_ws, size_t ws_size,
                              hipStream_t stream) {
    const float* x      = (const float*)d_in[0];
    const int*   src    = (const int*)d_in[1];
    const int*   dst    = (const int*)d_in[2];
    const float* fc_w   = (const float*)d_in[3];
    const float* bias   = (const float*)d_in[4];
    const float* attn_l = (const float*)d_in[5];
    const float* attn_r = (const float*)d_in[6];
    const float* w1 = (const float*)d_in[7];  const float* b1 = (const float*)d_in[8];
    const float* w2 = (const float*)d_in[9];  const float* b2 = (const float*)d_in[10];
    const float* w3 = (const float*)d_in[11]; const float* b3 = (const float*)d_in[12];
    const float* w4 = (const float*)d_in[13]; const float* b4 = (const float*)d_in[14];
    const float* w5 = (const float*)d_in[15]; const float* b5 = (const float*)d_in[16];
    const float* w6 = (const float*)d_in[17]; const float* b6 = (const float*)d_in[18];
    const float* w7 = (const float*)d_in[19]; const float* b7 = (const float*)d_in[20];
    const float* wt = (const float*)d_in[21];
    int E = in_sizes[1];

    float* ws      = (float*)d_ws;
    __half* feat   = (__half*)ws;               // 6,400,000 fp16 (dead after k_agg)
    float* el      = ws + 6400000;              //   400,000 f
    float* er      = ws + 6800000;              //   400,000 f
    float* agg     = ws + 7200000;              // 6,400,000 f
    uint2* pair    = (uint2*)(ws + 7200000);    // aliases agg (dead before k_agg)
    int*   rowptr  = (int*)(ws + 13600000);     //   100,001 i (pad 100,004)
    int*   buktot  = (int*)(ws + 13700004);     //       196 i
    int*   bukstart= (int*)(ws + 13700200);     //       197 i
    int*   bukptr  = (int*)(ws + 13700400);     //       196 i
    int*   csr     = (int*)(ws + 13700600);     //         E i
    // weight fragments overlay feat region (written after k_agg, read by k_mlp)
    short* wfh     = (short*)ws;                //   192,512 bf16
    short* wfl     = wfh + 192512;              //   192,512 bf16

    int nwg = (E + 2047) / 2048;

    hipMemsetAsync(buktot, 0, NBUK * 4, stream);

    k_feat<<<(N_NODES + 255) / 256, 256, 0, stream>>>(x, fc_w, attn_l, attn_r, feat, el, er);
    k_histB<<<(E + 1023) / 1024, 256, 0, stream>>>(dst, buktot, E);
    k_scan196<<<1, 256, 0, stream>>>(buktot, bukstart, bukptr, rowptr, E);
    k_bucketA<<<nwg, 256, 0, stream>>>(src, dst, bukptr, pair, E);
    k_bucketC<<<NBUK, 512, 0, stream>>>(pair, bukstart, rowptr, csr, E);
    k_agg<<<N_NODES / 4, 256, 0, stream>>>(rowptr, csr, el, er, feat, bias, agg);
    k_wprep<<<376, 64, 0, stream>>>(w1, w2, w3, w4, w5, w6, wfh, wfl);
    k_mlp<<<(P_PATHS + 31) / 32, 512, 0, stream>>>(agg, wfh, wfl, b1, b2, b3, b4, b5, b6,
                                                   w7, b7, wt, (float*)d_out);
}